// Round 1
// 594.630 us; speedup vs baseline: 1.0040x; 1.0040x over previous
//
#include <hip/hip_runtime.h>
#include <math.h>

#define NN 16384
#define KNB 30
#define NE (NN*KNB)   // 491520

typedef __attribute__((ext_vector_type(8))) __bf16 bf16x8;
typedef __attribute__((ext_vector_type(4))) float f32x4;
typedef unsigned short ushortT;
typedef __attribute__((ext_vector_type(8))) unsigned short ushort8v;

#define SWZ(r) (((r)&7)<<4)

__device__ __forceinline__ ushortT f2bf(float x){
  __bf16 b = (__bf16)x;
  union { __bf16 b; ushortT u; } v; v.b = b; return v.u;
}
__device__ __forceinline__ float bf2f(ushortT u){
  union { unsigned int u32; float f; } v; v.u32 = ((unsigned int)u) << 16;
  return v.f;
}
// A&S 7.1.26 erf (|err| <= 1.5e-7), exact-GELU compatible at bf16 tolerance
__device__ __forceinline__ float gelu_f(float x){
  float ax = fabsf(x) * 0.7071067811865476f;
  float t = 1.0f / (1.0f + 0.3275911f * ax);
  float poly = t*(0.254829592f + t*(-0.284496736f + t*(1.421413741f +
               t*(-1.453152027f + t*1.061405429f))));
  float er = 1.0f - poly * __expf(-ax*ax);
  er = copysignf(er, x);
  return 0.5f * x * (1.0f + er);
}

// ---------------- prep: weights -> bf16 in MFMA-fragment order ----------------
// Fragment unit = 64 lanes x 8 bf16 (one B-operand wave-load = 1KB contiguous).
// WF1: 128 tiles = ((half*8+nt)*8+kt), k over [e|hj] (att: aw1 rows 128..383)
// WF2: 64 tiles  = ((half*8+nt)*4+kt)
// WF3: 32 tiles  = (nt*4+kt), nw3^T
__global__ void pack_kernel(const float* __restrict__ aw1, const float* __restrict__ nw1,
                            const float* __restrict__ aw2, const float* __restrict__ nw2,
                            const float* __restrict__ nw3,
                            const float* __restrict__ ab1, const float* __restrict__ nb1,
                            const float* __restrict__ ab2, const float* __restrict__ nb2,
                            const float* __restrict__ nb3,
                            ushortT* __restrict__ WF1, ushortT* __restrict__ WF2,
                            ushortT* __restrict__ WF3,
                            float* __restrict__ bias1, float* __restrict__ bias2,
                            float* __restrict__ bias3)
{
  int u = blockIdx.x * blockDim.x + threadIdx.x;
  if (u < 8192) {
    int lane = u & 63, tile = u >> 6;
    int half = tile >> 6, nt = (tile >> 3) & 7, kt = tile & 7;
    int mrow = lane & 15, krow = lane >> 4;
    int n = half*128 + nt*16 + mrow, k0 = kt*32 + krow*8;
    ushort8v o;
    #pragma unroll
    for (int j = 0; j < 8; ++j) {
      int k = k0 + j;
      float v = (half == 0) ? aw1[(128 + k)*128 + n] : nw1[k*128 + (n - 128)];
      o[j] = f2bf(v);
    }
    *(ushort8v*)(WF1 + (size_t)u*8) = o;
    return;
  }
  u -= 8192;
  if (u < 4096) {
    int lane = u & 63, tile = u >> 6;
    int half = tile >> 5, nt = (tile >> 2) & 7, kt = tile & 3;
    int mrow = lane & 15, krow = lane >> 4;
    int n = half*128 + nt*16 + mrow, k0 = kt*32 + krow*8;
    ushort8v o;
    #pragma unroll
    for (int j = 0; j < 8; ++j) {
      int k = k0 + j;
      float v = (half == 0) ? aw2[k*128 + n] : nw2[k*128 + (n - 128)];
      o[j] = f2bf(v);
    }
    *(ushort8v*)(WF2 + (size_t)u*8) = o;
    return;
  }
  u -= 4096;
  if (u < 2048) {
    int lane = u & 63, tile = u >> 6;
    int nt = tile >> 2, kt = tile & 3;
    int mrow = lane & 15, krow = lane >> 4;
    int n = nt*16 + mrow, k0 = kt*32 + krow*8;
    ushort8v o;
    #pragma unroll
    for (int j = 0; j < 8; ++j) o[j] = f2bf(nw3[(k0 + j)*128 + n]);
    *(ushort8v*)(WF3 + (size_t)u*8) = o;
    return;
  }
  u -= 2048;
  if (u < 256) { bias1[u] = (u < 128) ? ab1[u] : nb1[u - 128]; return; }
  u -= 256;
  if (u < 256) { bias2[u] = (u < 128) ? ab2[u] : nb2[u - 128]; return; }
  u -= 128 + 128;
  if (u >= 0 && u < 128) { bias3[u] = nb3[u]; return; }
}

// ---------------- U = h @ aw1[0:128,:]  (per-node att first-layer part) -------
// Written into the hh/output buffer; edge_kernel consumes its own 4 rows before
// overwriting them with hh0. 16 nodes/block, 256 threads, 8 rows/thread.
__global__ void ub_kernel(const float* __restrict__ h, const float* __restrict__ aw1,
                          float* __restrict__ U)
{
  __shared__ float hs[16][128];
  int tid = threadIdx.x;
  size_t n0 = (size_t)blockIdx.x * 16;
  {
    int r = tid >> 4, c = (tid & 15) * 8;
    const float* src = h + (n0 + r)*128 + c;
    *(float4*)&hs[r][c]     = *(const float4*)src;
    *(float4*)&hs[r][c + 4] = *(const float4*)(src + 4);
  }
  __syncthreads();
  int d = tid & 127, gq = tid >> 7;
  float s[8] = {0.f,0.f,0.f,0.f,0.f,0.f,0.f,0.f};
  for (int c = 0; c < 128; ++c) {
    float w = aw1[c*128 + d];
    #pragma unroll
    for (int r = 0; r < 8; ++r) s[r] += hs[gq*8 + r][c] * w;
  }
  #pragma unroll
  for (int r = 0; r < 8; ++r) U[(n0 + gq*8 + r)*128 + d] = s[r];
}

// ---------------- fused edge pipeline: 4 nodes (120 edges), 512 threads --------
// LDS: Xb [128 rows][512B] XOR-swizzled bf16 | Ubs[512]f32 | lg[128]
// V3f [128][132] f32 overlays Xb+Ubs after stage3. Total 68096 B -> 2 blocks/CU.
__global__ __launch_bounds__(512, 4) void edge_kernel(
    const float* __restrict__ h, const float* __restrict__ e,
    const int* __restrict__ edge_idx,
    const ushortT* __restrict__ WF1, const ushortT* __restrict__ WF2,
    const ushortT* __restrict__ WF3,
    const float* __restrict__ bias1, const float* __restrict__ bias2,
    const float* __restrict__ bias3,
    const float* __restrict__ aw3, const float* __restrict__ ab3,
    float* __restrict__ hh)
{
  extern __shared__ char smem[];
  char*  Xb   = smem;                       // [128][512B] swizzled bf16
  float* Ubs  = (float*)(smem + 65536);     // [4][128]
  float* lg   = (float*)(smem + 67584);     // [128]
  float* V3f  = (float*)smem;               // [128][132] overlays Xb+Ubs

  const int tid  = threadIdx.x;
  const int lane = tid & 63;
  const int wid  = tid >> 6;
  const int node0 = blockIdx.x * 4;
  const long e0 = (long)node0 * KNB;

  // U for this block's 4 nodes (precomputed by ub_kernel into hh rows);
  // issue the load early so it's in flight during staging.
  float uval = hh[(size_t)node0*128 + tid];

  // ---- Phase 0: stage X = [e | hj] bf16, swizzled; rows 120..127 zeroed ----
  #pragma unroll
  for (int it = 0; it < 8; ++it) {
    int idx = it*512 + tid;
    int r = idx >> 5, c8 = idx & 31;
    ushort8v u = {0,0,0,0,0,0,0,0};
    if (r < 120) {
      long edge = e0 + r;
      const float* src;
      if (c8 < 16) src = e + (size_t)edge*128 + c8*8;
      else {
        int dst = edge_idx[NE + edge];
        src = h + (size_t)dst*128 + (c8 - 16)*8;
      }
      float4 v0 = *(const float4*)src;
      float4 v1 = *(const float4*)(src + 4);
      u[0]=f2bf(v0.x); u[1]=f2bf(v0.y); u[2]=f2bf(v0.z); u[3]=f2bf(v0.w);
      u[4]=f2bf(v1.x); u[5]=f2bf(v1.y); u[6]=f2bf(v1.z); u[7]=f2bf(v1.w);
    }
    *(ushort8v*)(Xb + r*512 + ((c8*16) ^ SWZ(r))) = u;
  }
  Ubs[tid] = uval;
  __syncthreads();

  const int mrow = lane & 15, krow = lane >> 4;
  const int wr = wid >> 1;   // row strip (32 rows)
  const int wc = wid & 1;    // col half

  f32x4 acc[2][8];
  #pragma unroll
  for (int mt = 0; mt < 2; ++mt)
    #pragma unroll
    for (int nt = 0; nt < 8; ++nt) acc[mt][nt] = (f32x4){0.f,0.f,0.f,0.f};

  // ---- GEMM1: X[128x256] @ WF1 -> (W1|V1)[128x256] ----
  for (int kt = 0; kt < 8; ++kt) {
    bf16x8 a[2];
    #pragma unroll
    for (int mt = 0; mt < 2; ++mt) {
      int row = wr*32 + mt*16 + mrow;
      a[mt] = *(const bf16x8*)(Xb + row*512 + ((kt*64 + krow*16) ^ SWZ(row)));
    }
    const ushortT* Bp = WF1 + ((size_t)(wc*8)*8 + kt)*512 + lane*8;
    #pragma unroll
    for (int nt = 0; nt < 8; ++nt) {
      bf16x8 b = *(const bf16x8*)(Bp + (size_t)nt*8*512);
      acc[0][nt] = __builtin_amdgcn_mfma_f32_16x16x32_bf16(a[0], b, acc[0][nt], 0, 0, 0);
      acc[1][nt] = __builtin_amdgcn_mfma_f32_16x16x32_bf16(a[1], b, acc[1][nt], 0, 0, 0);
    }
  }
  __syncthreads();
  // epilogue 1: +bias (+Ub on att half), relu/gelu, store bf16 in place
  {
    float bia[8];
    #pragma unroll
    for (int nt = 0; nt < 8; ++nt) bia[nt] = bias1[wc*128 + nt*16 + mrow];
    #pragma unroll
    for (int mt = 0; mt < 2; ++mt)
      #pragma unroll
      for (int rr = 0; rr < 4; ++rr) {
        int row = wr*32 + mt*16 + krow*4 + rr;
        int nq = (row >= 120) ? 3 : (row / KNB);
        const float* ubr = Ubs + nq*128;
        #pragma unroll
        for (int nt = 0; nt < 8; ++nt) {
          int col = wc*128 + nt*16 + mrow;
          float x = acc[mt][nt][rr] + bia[nt];
          x = (wc == 0) ? fmaxf(x + ubr[col], 0.f) : gelu_f(x);
          *(ushortT*)(Xb + row*512 + ((2*col) ^ SWZ(row))) = f2bf(x);
        }
      }
  }
  __syncthreads();

  // ---- GEMM2: W2 = relu(W1@aw2), V2 = gelu(V1@nw2) ----
  #pragma unroll
  for (int mt = 0; mt < 2; ++mt)
    #pragma unroll
    for (int nt = 0; nt < 8; ++nt) acc[mt][nt] = (f32x4){0.f,0.f,0.f,0.f};
  for (int kt = 0; kt < 4; ++kt) {
    bf16x8 a[2];
    #pragma unroll
    for (int mt = 0; mt < 2; ++mt) {
      int row = wr*32 + mt*16 + mrow;
      a[mt] = *(const bf16x8*)(Xb + row*512 + ((wc*256 + kt*64 + krow*16) ^ SWZ(row)));
    }
    const ushortT* Bp = WF2 + ((size_t)(wc*8)*4 + kt)*512 + lane*8;
    #pragma unroll
    for (int nt = 0; nt < 8; ++nt) {
      bf16x8 b = *(const bf16x8*)(Bp + (size_t)nt*4*512);
      acc[0][nt] = __builtin_amdgcn_mfma_f32_16x16x32_bf16(a[0], b, acc[0][nt], 0, 0, 0);
      acc[1][nt] = __builtin_amdgcn_mfma_f32_16x16x32_bf16(a[1], b, acc[1][nt], 0, 0, 0);
    }
  }
  __syncthreads();
  // epilogue 2: store swapped [V2 | W2] (V2 -> cols 0..127)
  {
    float bia[8];
    #pragma unroll
    for (int nt = 0; nt < 8; ++nt) bia[nt] = bias2[wc*128 + nt*16 + mrow];
    #pragma unroll
    for (int mt = 0; mt < 2; ++mt)
      #pragma unroll
      for (int rr = 0; rr < 4; ++rr) {
        int row = wr*32 + mt*16 + krow*4 + rr;
        #pragma unroll
        for (int nt = 0; nt < 8; ++nt) {
          int col = wc*128 + nt*16 + mrow;
          float x = acc[mt][nt][rr] + bia[nt];
          x = (wc == 0) ? fmaxf(x, 0.f) : gelu_f(x);
          *(ushortT*)(Xb + row*512 + ((2*(col ^ 128)) ^ SWZ(row))) = f2bf(x);
        }
      }
  }
  __syncthreads();

  // ---- logits = W2 . aw3 + ab3 (4 threads/row), cols 128..255 ----
  {
    int row = tid >> 2, q = tid & 3;
    const char* wp = Xb + row*512;
    float s = 0.f;
    #pragma unroll
    for (int j = 0; j < 4; ++j) {
      ushort8v wv = *(const ushort8v*)(wp + ((256 + q*64 + j*16) ^ SWZ(row)));
      #pragma unroll
      for (int t = 0; t < 8; ++t) s += bf2f(wv[t]) * aw3[q*32 + j*8 + t];
    }
    s += __shfl_xor(s, 1);
    s += __shfl_xor(s, 2);
    if (q == 0) lg[row] = (s + ab3[0]) * 0.08838834764831845f;
  }

  // ---- GEMM3: V3 = V2 @ nw3 (A = cols 0..127) ----
  f32x4 acc3[2][4];
  #pragma unroll
  for (int mt = 0; mt < 2; ++mt)
    #pragma unroll
    for (int nt = 0; nt < 4; ++nt) acc3[mt][nt] = (f32x4){0.f,0.f,0.f,0.f};
  for (int kt = 0; kt < 4; ++kt) {
    bf16x8 a[2];
    #pragma unroll
    for (int mt = 0; mt < 2; ++mt) {
      int row = wr*32 + mt*16 + mrow;
      a[mt] = *(const bf16x8*)(Xb + row*512 + ((kt*64 + krow*16) ^ SWZ(row)));
    }
    const ushortT* Bp = WF3 + ((size_t)(wc*4)*4 + kt)*512 + lane*8;
    #pragma unroll
    for (int nt = 0; nt < 4; ++nt) {
      bf16x8 b = *(const bf16x8*)(Bp + (size_t)nt*4*512);
      acc3[0][nt] = __builtin_amdgcn_mfma_f32_16x16x32_bf16(a[0], b, acc3[0][nt], 0, 0, 0);
      acc3[1][nt] = __builtin_amdgcn_mfma_f32_16x16x32_bf16(a[1], b, acc3[1][nt], 0, 0, 0);
    }
  }
  __syncthreads();   // all Xs reads (logits + GEMM3) complete before overlay
  // V3 dump f32 over Xb region
  {
    float bia[4];
    #pragma unroll
    for (int nt = 0; nt < 4; ++nt) bia[nt] = bias3[wc*64 + nt*16 + mrow];
    #pragma unroll
    for (int mt = 0; mt < 2; ++mt)
      #pragma unroll
      for (int nt = 0; nt < 4; ++nt)
        #pragma unroll
        for (int rr = 0; rr < 4; ++rr) {
          int row = wr*32 + mt*16 + krow*4 + rr;
          int col = wc*64 + nt*16 + mrow;
          V3f[row*132 + col] = acc3[mt][nt][rr] + bia[nt];
        }
  }
  __syncthreads();

  // ---- softmax over 30 neighbors (wave pair per node) + PV -> hh0 global ----
  {
    int n = wid >> 1, dh = (wid & 1) * 64;
    float x = (lane < KNB) ? lg[n*KNB + lane] : -INFINITY;
    float m = x;
    #pragma unroll
    for (int off = 32; off >= 1; off >>= 1) m = fmaxf(m, __shfl_xor(m, off));
    float p = (lane < KNB) ? __expf(x - m) : 0.f;
    float ssum = p;
    #pragma unroll
    for (int off = 32; off >= 1; off >>= 1) ssum += __shfl_xor(ssum, off);
    float attv = p / ssum;
    float s = 0.f;
    #pragma unroll
    for (int k2 = 0; k2 < KNB; ++k2) {
      float a = __shfl(attv, k2);
      s += a * V3f[(size_t)(n*KNB + k2)*132 + dh + lane];
    }
    hh[(size_t)(node0 + n)*128 + dh + lane] = s;
  }
}

// ---------------- deterministic column reduction over nodes (on hh0) ----------
__global__ void reduce1_kernel(const float* __restrict__ hh, float* __restrict__ p2) {
  int b = blockIdx.x, tid = threadIdx.x;
  int d = tid & 127, half = tid >> 7;
  float s = 0.f;
  const float* base = hh + (size_t)(b*64 + half*32)*128 + d;
  #pragma unroll 4
  for (int i = 0; i < 32; ++i) s += base[(size_t)i*128];
  __shared__ float ps[256];
  ps[tid] = s; __syncthreads();
  if (tid < 128) p2[b*128 + tid] = ps[tid] + ps[tid + 128];
}

// gate: c0 = mean(hh0); c = c0 @ thw; g = sigmoid(MLP(c))
__global__ void gate_kernel(const float* __restrict__ p2, const float* __restrict__ thw,
                            const float* __restrict__ gw1, const float* __restrict__ gb1,
                            const float* __restrict__ gw2, const float* __restrict__ gb2,
                            const float* __restrict__ gw3, const float* __restrict__ gb3,
                            float* __restrict__ gout) {
  int tid = threadIdx.x;
  int d = tid & 127, half = tid >> 7;
  float s = 0.f;
  for (int i = 0; i < 128; ++i) s += p2[(half*128 + i)*128 + d];
  __shared__ float ps[256];
  __shared__ float cv[128], cv2[128], y1[128], y2[128];
  ps[tid] = s; __syncthreads();
  if (tid < 128) cv[tid] = (ps[tid] + ps[tid+128]) * (1.f / (float)NN);
  __syncthreads();
  if (tid < 128) {
    float a = 0.f;
    for (int c = 0; c < 128; ++c) a += cv[c] * thw[c*128 + tid];
    cv2[tid] = a;
  }
  __syncthreads();
  if (tid < 128) {
    float a = gb1[tid];
    for (int c = 0; c < 128; ++c) a += cv2[c] * gw1[c*128 + tid];
    y1[tid] = fmaxf(a, 0.f);
  }
  __syncthreads();
  if (tid < 128) {
    float a = gb2[tid];
    for (int c = 0; c < 128; ++c) a += y1[c] * gw2[c*128 + tid];
    y2[tid] = fmaxf(a, 0.f);
  }
  __syncthreads();
  if (tid < 128) {
    float a = gb3[tid];
    for (int c = 0; c < 128; ++c) a += y2[c] * gw3[c*128 + tid];
    gout[tid] = 1.f / (1.f + __expf(-a));
  }
}

// ---------------- fused to_h + gate scale: out = (hh0 @ thw) * g, in place ----
__global__ void toh_scale_kernel(float* __restrict__ hh, const float* __restrict__ thw,
                                 const float* __restrict__ gv)
{
  __shared__ float hs[16][128];
  int tid = threadIdx.x;
  size_t n0 = (size_t)blockIdx.x * 16;
  {
    int r = tid >> 4, c = (tid & 15) * 8;
    const float* src = hh + (n0 + r)*128 + c;
    *(float4*)&hs[r][c]     = *(const float4*)src;
    *(float4*)&hs[r][c + 4] = *(const float4*)(src + 4);
  }
  __syncthreads();
  int d = tid & 127, gq = tid >> 7;
  float s[8] = {0.f,0.f,0.f,0.f,0.f,0.f,0.f,0.f};
  for (int c = 0; c < 128; ++c) {
    float w = thw[c*128 + d];
    #pragma unroll
    for (int r = 0; r < 8; ++r) s[r] += hs[gq*8 + r][c] * w;
  }
  float gd = gv[d];
  #pragma unroll
  for (int r = 0; r < 8; ++r) hh[(n0 + gq*8 + r)*128 + d] = s[r] * gd;
}

extern "C" void kernel_launch(void* const* d_in, const int* in_sizes, int n_in,
                              void* d_out, int out_size, void* d_ws, size_t ws_size,
                              hipStream_t stream) {
  const float* h   = (const float*)d_in[0];
  const float* e   = (const float*)d_in[1];
  const float* aw1 = (const float*)d_in[2];
  const float* ab1 = (const float*)d_in[3];
  const float* aw2 = (const float*)d_in[4];
  const float* ab2 = (const float*)d_in[5];
  const float* aw3 = (const float*)d_in[6];
  const float* ab3 = (const float*)d_in[7];
  const float* nw1 = (const float*)d_in[8];
  const float* nb1 = (const float*)d_in[9];
  const float* nw2 = (const float*)d_in[10];
  const float* nb2 = (const float*)d_in[11];
  const float* nw3 = (const float*)d_in[12];
  const float* nb3 = (const float*)d_in[13];
  const float* thw = (const float*)d_in[14];
  const float* gw1 = (const float*)d_in[15];
  const float* gb1 = (const float*)d_in[16];
  const float* gw2 = (const float*)d_in[17];
  const float* gb2 = (const float*)d_in[18];
  const float* gw3 = (const float*)d_in[19];
  const float* gb3 = (const float*)d_in[20];
  const int* edge_idx = (const int*)d_in[21];

  char* ws = (char*)d_ws;
  ushortT* WF1 = (ushortT*)(ws + 0);        // 131072 B
  ushortT* WF2 = (ushortT*)(ws + 131072);   // 65536 B
  ushortT* WF3 = (ushortT*)(ws + 196608);   // 32768 B
  float* bias1 = (float*)(ws + 229376);     // 1024 B
  float* bias2 = (float*)(ws + 230400);     // 1024 B
  float* bias3 = (float*)(ws + 231424);     // 512 B
  float* p2    = (float*)(ws + 231936);     // 131072 B
  float* gout  = (float*)(ws + 363008);     // 512 B
  float* hh    = (float*)d_out;

  pack_kernel<<<59, 256, 0, stream>>>(aw1, nw1, aw2, nw2, nw3,
                                      ab1, nb1, ab2, nb2, nb3,
                                      WF1, WF2, WF3, bias1, bias2, bias3);

  // U = h @ aw1[0:128,:] into the output buffer (consumed in-place by edge_kernel)
  ub_kernel<<<NN/16, 256, 0, stream>>>(h, aw1, hh);

  const int SMEM = 68096;
  hipFuncSetAttribute((const void*)edge_kernel,
                      hipFuncAttributeMaxDynamicSharedMemorySize, SMEM);
  edge_kernel<<<NN/4, 512, SMEM, stream>>>(h, e, edge_idx, WF1, WF2, WF3,
                                           bias1, bias2, bias3, aw3, ab3, hh);

  reduce1_kernel<<<256, 256, 0, stream>>>(hh, p2);
  gate_kernel<<<1, 256, 0, stream>>>(p2, thw, gw1, gb1, gw2, gb2, gw3, gb3, gout);
  toh_scale_kernel<<<NN/16, 256, 0, stream>>>(hh, thw, gout);
}

// Round 2
// 548.751 us; speedup vs baseline: 1.0879x; 1.0836x over previous
//
#include <hip/hip_runtime.h>
#include <math.h>

#define NN 16384
#define KNB 30
#define NE (NN*KNB)   // 491520

typedef __attribute__((ext_vector_type(8))) __bf16 bf16x8;
typedef __attribute__((ext_vector_type(4))) float f32x4;
typedef unsigned short ushortT;
typedef __attribute__((ext_vector_type(8))) unsigned short ushort8v;

#define SWZ(r) (((r)&7)<<4)

__device__ __forceinline__ ushortT f2bf(float x){
  __bf16 b = (__bf16)x;
  union { __bf16 b; ushortT u; } v; v.b = b; return v.u;
}
__device__ __forceinline__ float bf2f(ushortT u){
  union { unsigned int u32; float f; } v; v.u32 = ((unsigned int)u) << 16;
  return v.f;
}
// A&S 7.1.26 erf (|err| <= 1.5e-7), exact-GELU compatible at bf16 tolerance
__device__ __forceinline__ float gelu_f(float x){
  float ax = fabsf(x) * 0.7071067811865476f;
  float t = 1.0f / (1.0f + 0.3275911f * ax);
  float poly = t*(0.254829592f + t*(-0.284496736f + t*(1.421413741f +
               t*(-1.453152027f + t*1.061405429f))));
  float er = 1.0f - poly * __expf(-ax*ax);
  er = copysignf(er, x);
  return 0.5f * x * (1.0f + er);
}

// ---------------- prep: weights -> bf16 in MFMA-fragment order ----------------
// Fragment unit = 64 lanes x 8 bf16 (one B-operand wave-load = 1KB contiguous).
// WF1: 128 tiles = ((half*8+nt)*8+kt), k over [e|hj] (att: aw1 rows 128..383)
// WF2: 64 tiles  = ((half*8+nt)*4+kt)
// WF3: 32 tiles  = (nt*4+kt), nw3^T
__global__ void pack_kernel(const float* __restrict__ aw1, const float* __restrict__ nw1,
                            const float* __restrict__ aw2, const float* __restrict__ nw2,
                            const float* __restrict__ nw3,
                            const float* __restrict__ ab1, const float* __restrict__ nb1,
                            const float* __restrict__ ab2, const float* __restrict__ nb2,
                            const float* __restrict__ nb3,
                            ushortT* __restrict__ WF1, ushortT* __restrict__ WF2,
                            ushortT* __restrict__ WF3,
                            float* __restrict__ bias1, float* __restrict__ bias2,
                            float* __restrict__ bias3)
{
  int u = blockIdx.x * blockDim.x + threadIdx.x;
  if (u < 8192) {
    int lane = u & 63, tile = u >> 6;
    int half = tile >> 6, nt = (tile >> 3) & 7, kt = tile & 7;
    int mrow = lane & 15, krow = lane >> 4;
    int n = half*128 + nt*16 + mrow, k0 = kt*32 + krow*8;
    ushort8v o;
    #pragma unroll
    for (int j = 0; j < 8; ++j) {
      int k = k0 + j;
      float v = (half == 0) ? aw1[(128 + k)*128 + n] : nw1[k*128 + (n - 128)];
      o[j] = f2bf(v);
    }
    *(ushort8v*)(WF1 + (size_t)u*8) = o;
    return;
  }
  u -= 8192;
  if (u < 4096) {
    int lane = u & 63, tile = u >> 6;
    int half = tile >> 5, nt = (tile >> 2) & 7, kt = tile & 3;
    int mrow = lane & 15, krow = lane >> 4;
    int n = half*128 + nt*16 + mrow, k0 = kt*32 + krow*8;
    ushort8v o;
    #pragma unroll
    for (int j = 0; j < 8; ++j) {
      int k = k0 + j;
      float v = (half == 0) ? aw2[k*128 + n] : nw2[k*128 + (n - 128)];
      o[j] = f2bf(v);
    }
    *(ushort8v*)(WF2 + (size_t)u*8) = o;
    return;
  }
  u -= 4096;
  if (u < 2048) {
    int lane = u & 63, tile = u >> 6;
    int nt = tile >> 2, kt = tile & 3;
    int mrow = lane & 15, krow = lane >> 4;
    int n = nt*16 + mrow, k0 = kt*32 + krow*8;
    ushort8v o;
    #pragma unroll
    for (int j = 0; j < 8; ++j) o[j] = f2bf(nw3[(k0 + j)*128 + n]);
    *(ushort8v*)(WF3 + (size_t)u*8) = o;
    return;
  }
  u -= 2048;
  if (u < 256) { bias1[u] = (u < 128) ? ab1[u] : nb1[u - 128]; return; }
  u -= 256;
  if (u < 256) { bias2[u] = (u < 128) ? ab2[u] : nb2[u - 128]; return; }
  u -= 128 + 128;
  if (u >= 0 && u < 128) { bias3[u] = nb3[u]; return; }
}

// ---------------- U = h @ aw1[0:128,:]  (per-node att first-layer part) -------
// Written into the hh/output buffer; edge_kernel consumes its own 2 rows before
// overwriting them with hh0. 16 nodes/block, 256 threads, 8 rows/thread.
__global__ void ub_kernel(const float* __restrict__ h, const float* __restrict__ aw1,
                          float* __restrict__ U)
{
  __shared__ float hs[16][128];
  int tid = threadIdx.x;
  size_t n0 = (size_t)blockIdx.x * 16;
  {
    int r = tid >> 4, c = (tid & 15) * 8;
    const float* src = h + (n0 + r)*128 + c;
    *(float4*)&hs[r][c]     = *(const float4*)src;
    *(float4*)&hs[r][c + 4] = *(const float4*)(src + 4);
  }
  __syncthreads();
  int d = tid & 127, gq = tid >> 7;
  float s[8] = {0.f,0.f,0.f,0.f,0.f,0.f,0.f,0.f};
  for (int c = 0; c < 128; ++c) {
    float w = aw1[c*128 + d];
    #pragma unroll
    for (int r = 0; r < 8; ++r) s[r] += hs[gq*8 + r][c] * w;
  }
  #pragma unroll
  for (int r = 0; r < 8; ++r) U[(n0 + gq*8 + r)*128 + d] = s[r];
}

// ---------------- fused edge pipeline: 2 nodes (60 edges), 512 threads --------
// LDS: Xb [64 rows][512B] XOR-swizzled bf16 (32 KiB); V3f [64][132] f32 overlays
// Xb; lg[64]; Ubs[2][128]. Total 35072 B -> 4 blocks/CU by LDS.
// Wave tile 16 rows x 128 cols -> acc[8] = 32 AGPRs (half of prior round).
__global__ __launch_bounds__(512, 6) void edge_kernel(
    const float* __restrict__ h, const float* __restrict__ e,
    const int* __restrict__ edge_idx,
    const ushortT* __restrict__ WF1, const ushortT* __restrict__ WF2,
    const ushortT* __restrict__ WF3,
    const float* __restrict__ bias1, const float* __restrict__ bias2,
    const float* __restrict__ bias3,
    const float* __restrict__ aw3, const float* __restrict__ ab3,
    float* __restrict__ hh)
{
  extern __shared__ char smem[];
  char*  Xb   = smem;                       // [64][512B] swizzled bf16 (32768 B)
  float* V3f  = (float*)smem;               // [64][132] f32 overlay (33792 B)
  float* lg   = (float*)(smem + 33792);     // [64]
  float* Ubs  = (float*)(smem + 34048);     // [2][128]

  const int tid  = threadIdx.x;
  const int lane = tid & 63;
  const int wid  = tid >> 6;
  const int node0 = blockIdx.x * 2;
  const long e0 = (long)node0 * KNB;

  // U for this block's 2 nodes (precomputed by ub_kernel into hh rows);
  // issue the load early so it's in flight during staging.
  float uval = 0.f;
  if (tid < 256) uval = hh[(size_t)node0*128 + tid];

  // ---- Phase 0: stage X = [e | hj] bf16, swizzled; rows 60..63 zeroed ----
  #pragma unroll
  for (int it = 0; it < 4; ++it) {
    int idx = it*512 + tid;
    int r = idx >> 5, c8 = idx & 31;
    ushort8v u = {0,0,0,0,0,0,0,0};
    if (r < 60) {
      long edge = e0 + r;
      const float* src;
      if (c8 < 16) src = e + (size_t)edge*128 + c8*8;
      else {
        int dst = edge_idx[NE + edge];
        src = h + (size_t)dst*128 + (c8 - 16)*8;
      }
      float4 v0 = *(const float4*)src;
      float4 v1 = *(const float4*)(src + 4);
      u[0]=f2bf(v0.x); u[1]=f2bf(v0.y); u[2]=f2bf(v0.z); u[3]=f2bf(v0.w);
      u[4]=f2bf(v1.x); u[5]=f2bf(v1.y); u[6]=f2bf(v1.z); u[7]=f2bf(v1.w);
    }
    *(ushort8v*)(Xb + r*512 + ((c8*16) ^ SWZ(r))) = u;
  }
  if (tid < 256) Ubs[tid] = uval;
  __syncthreads();

  const int mrow = lane & 15, krow = lane >> 4;
  const int wr = wid >> 1;   // row strip (16 rows)
  const int wc = wid & 1;    // col half

  f32x4 acc[8];
  #pragma unroll
  for (int nt = 0; nt < 8; ++nt) acc[nt] = (f32x4){0.f,0.f,0.f,0.f};

  // ---- GEMM1: X[64x256] @ WF1 -> (W1|V1)[64x256] ----
  for (int kt = 0; kt < 8; ++kt) {
    int row = wr*16 + mrow;
    bf16x8 a = *(const bf16x8*)(Xb + row*512 + ((kt*64 + krow*16) ^ SWZ(row)));
    const ushortT* Bp = WF1 + ((size_t)(wc*8)*8 + kt)*512 + lane*8;
    #pragma unroll
    for (int nt = 0; nt < 8; ++nt) {
      bf16x8 b = *(const bf16x8*)(Bp + (size_t)nt*8*512);
      acc[nt] = __builtin_amdgcn_mfma_f32_16x16x32_bf16(a, b, acc[nt], 0, 0, 0);
    }
  }
  __syncthreads();
  // epilogue 1: +bias (+Ub on att half), relu/gelu, store bf16 in place
  {
    float bia[8];
    #pragma unroll
    for (int nt = 0; nt < 8; ++nt) bia[nt] = bias1[wc*128 + nt*16 + mrow];
    #pragma unroll
    for (int rr = 0; rr < 4; ++rr) {
      int row = wr*16 + krow*4 + rr;
      int nq = (row >= 60) ? 1 : (row / KNB);
      const float* ubr = Ubs + nq*128;
      #pragma unroll
      for (int nt = 0; nt < 8; ++nt) {
        int col = wc*128 + nt*16 + mrow;
        float x = acc[nt][rr] + bia[nt];
        x = (wc == 0) ? fmaxf(x + ubr[col], 0.f) : gelu_f(x);
        *(ushortT*)(Xb + row*512 + ((2*col) ^ SWZ(row))) = f2bf(x);
      }
    }
  }
  __syncthreads();

  // ---- GEMM2: W2 = relu(W1@aw2), V2 = gelu(V1@nw2) ----
  #pragma unroll
  for (int nt = 0; nt < 8; ++nt) acc[nt] = (f32x4){0.f,0.f,0.f,0.f};
  for (int kt = 0; kt < 4; ++kt) {
    int row = wr*16 + mrow;
    bf16x8 a = *(const bf16x8*)(Xb + row*512 + ((wc*256 + kt*64 + krow*16) ^ SWZ(row)));
    const ushortT* Bp = WF2 + ((size_t)(wc*8)*4 + kt)*512 + lane*8;
    #pragma unroll
    for (int nt = 0; nt < 8; ++nt) {
      bf16x8 b = *(const bf16x8*)(Bp + (size_t)nt*4*512);
      acc[nt] = __builtin_amdgcn_mfma_f32_16x16x32_bf16(a, b, acc[nt], 0, 0, 0);
    }
  }
  __syncthreads();
  // epilogue 2: store swapped [V2 | W2] (V2 -> cols 0..127)
  {
    float bia[8];
    #pragma unroll
    for (int nt = 0; nt < 8; ++nt) bia[nt] = bias2[wc*128 + nt*16 + mrow];
    #pragma unroll
    for (int rr = 0; rr < 4; ++rr) {
      int row = wr*16 + krow*4 + rr;
      #pragma unroll
      for (int nt = 0; nt < 8; ++nt) {
        int col = wc*128 + nt*16 + mrow;
        float x = acc[nt][rr] + bia[nt];
        x = (wc == 0) ? fmaxf(x, 0.f) : gelu_f(x);
        *(ushortT*)(Xb + row*512 + ((2*(col ^ 128)) ^ SWZ(row))) = f2bf(x);
      }
    }
  }
  __syncthreads();

  // ---- logits = W2 . aw3 + ab3 (8 threads/row), cols 128..255 ----
  {
    int row = tid >> 3, q = tid & 7;
    const char* wp = Xb + row*512;
    float s = 0.f;
    #pragma unroll
    for (int j = 0; j < 2; ++j) {
      ushort8v wv = *(const ushort8v*)(wp + ((256 + q*32 + j*16) ^ SWZ(row)));
      #pragma unroll
      for (int t = 0; t < 8; ++t) s += bf2f(wv[t]) * aw3[q*16 + j*8 + t];
    }
    s += __shfl_xor(s, 1);
    s += __shfl_xor(s, 2);
    s += __shfl_xor(s, 4);
    if (q == 0) lg[row] = (s + ab3[0]) * 0.08838834764831845f;
  }

  // ---- GEMM3: V3 = V2 @ nw3 (A = cols 0..127) ----
  f32x4 acc3[4];
  #pragma unroll
  for (int nt = 0; nt < 4; ++nt) acc3[nt] = (f32x4){0.f,0.f,0.f,0.f};
  for (int kt = 0; kt < 4; ++kt) {
    int row = wr*16 + mrow;
    bf16x8 a = *(const bf16x8*)(Xb + row*512 + ((kt*64 + krow*16) ^ SWZ(row)));
    const ushortT* Bp = WF3 + ((size_t)(wc*4)*4 + kt)*512 + lane*8;
    #pragma unroll
    for (int nt = 0; nt < 4; ++nt) {
      bf16x8 b = *(const bf16x8*)(Bp + (size_t)nt*4*512);
      acc3[nt] = __builtin_amdgcn_mfma_f32_16x16x32_bf16(a, b, acc3[nt], 0, 0, 0);
    }
  }
  __syncthreads();   // all Xb reads (logits + GEMM3) complete before overlay
  // V3 dump f32 over Xb region
  {
    float bia[4];
    #pragma unroll
    for (int nt = 0; nt < 4; ++nt) bia[nt] = bias3[wc*64 + nt*16 + mrow];
    #pragma unroll
    for (int nt = 0; nt < 4; ++nt)
      #pragma unroll
      for (int rr = 0; rr < 4; ++rr) {
        int row = wr*16 + krow*4 + rr;
        int col = wc*64 + nt*16 + mrow;
        V3f[row*132 + col] = acc3[nt][rr] + bia[nt];
      }
  }
  __syncthreads();

  // ---- softmax over 30 neighbors (4 waves per node, 32 cols each) + PV ----
  {
    int n = wid >> 2, dh = (wid & 3) * 32;
    int cl = lane & 31;
    float x = (lane < KNB) ? lg[n*KNB + lane] : -INFINITY;
    float m = x;
    #pragma unroll
    for (int off = 32; off >= 1; off >>= 1) m = fmaxf(m, __shfl_xor(m, off));
    float p = (lane < KNB) ? __expf(x - m) : 0.f;
    float ssum = p;
    #pragma unroll
    for (int off = 32; off >= 1; off >>= 1) ssum += __shfl_xor(ssum, off);
    float attv = p / ssum;
    float s = 0.f;
    #pragma unroll
    for (int k2 = 0; k2 < KNB; ++k2) {
      float a = __shfl(attv, k2);
      s += a * V3f[(size_t)(n*KNB + k2)*132 + dh + cl];
    }
    if (lane < 32) hh[(size_t)(node0 + n)*128 + dh + cl] = s;
  }
}

// ---------------- deterministic column reduction over nodes (on hh0) ----------
__global__ void reduce1_kernel(const float* __restrict__ hh, float* __restrict__ p2) {
  int b = blockIdx.x, tid = threadIdx.x;
  int d = tid & 127, half = tid >> 7;
  float s = 0.f;
  const float* base = hh + (size_t)(b*64 + half*32)*128 + d;
  #pragma unroll 4
  for (int i = 0; i < 32; ++i) s += base[(size_t)i*128];
  __shared__ float ps[256];
  ps[tid] = s; __syncthreads();
  if (tid < 128) p2[b*128 + tid] = ps[tid] + ps[tid + 128];
}

// gate: c0 = mean(hh0); c = c0 @ thw; g = sigmoid(MLP(c))
__global__ void gate_kernel(const float* __restrict__ p2, const float* __restrict__ thw,
                            const float* __restrict__ gw1, const float* __restrict__ gb1,
                            const float* __restrict__ gw2, const float* __restrict__ gb2,
                            const float* __restrict__ gw3, const float* __restrict__ gb3,
                            float* __restrict__ gout) {
  int tid = threadIdx.x;
  int d = tid & 127, half = tid >> 7;
  float s = 0.f;
  for (int i = 0; i < 128; ++i) s += p2[(half*128 + i)*128 + d];
  __shared__ float ps[256];
  __shared__ float cv[128], cv2[128], y1[128], y2[128];
  ps[tid] = s; __syncthreads();
  if (tid < 128) cv[tid] = (ps[tid] + ps[tid+128]) * (1.f / (float)NN);
  __syncthreads();
  if (tid < 128) {
    float a = 0.f;
    for (int c = 0; c < 128; ++c) a += cv[c] * thw[c*128 + tid];
    cv2[tid] = a;
  }
  __syncthreads();
  if (tid < 128) {
    float a = gb1[tid];
    for (int c = 0; c < 128; ++c) a += cv2[c] * gw1[c*128 + tid];
    y1[tid] = fmaxf(a, 0.f);
  }
  __syncthreads();
  if (tid < 128) {
    float a = gb2[tid];
    for (int c = 0; c < 128; ++c) a += y1[c] * gw2[c*128 + tid];
    y2[tid] = fmaxf(a, 0.f);
  }
  __syncthreads();
  if (tid < 128) {
    float a = gb3[tid];
    for (int c = 0; c < 128; ++c) a += y2[c] * gw3[c*128 + tid];
    gout[tid] = 1.f / (1.f + __expf(-a));
  }
}

// ---------------- fused to_h + gate scale: out = (hh0 @ thw) * g, in place ----
__global__ void toh_scale_kernel(float* __restrict__ hh, const float* __restrict__ thw,
                                 const float* __restrict__ gv)
{
  __shared__ float hs[16][128];
  int tid = threadIdx.x;
  size_t n0 = (size_t)blockIdx.x * 16;
  {
    int r = tid >> 4, c = (tid & 15) * 8;
    const float* src = hh + (n0 + r)*128 + c;
    *(float4*)&hs[r][c]     = *(const float4*)src;
    *(float4*)&hs[r][c + 4] = *(const float4*)(src + 4);
  }
  __syncthreads();
  int d = tid & 127, gq = tid >> 7;
  float s[8] = {0.f,0.f,0.f,0.f,0.f,0.f,0.f,0.f};
  for (int c = 0; c < 128; ++c) {
    float w = thw[c*128 + d];
    #pragma unroll
    for (int r = 0; r < 8; ++r) s[r] += hs[gq*8 + r][c] * w;
  }
  float gd = gv[d];
  #pragma unroll
  for (int r = 0; r < 8; ++r) hh[(n0 + gq*8 + r)*128 + d] = s[r] * gd;
}

extern "C" void kernel_launch(void* const* d_in, const int* in_sizes, int n_in,
                              void* d_out, int out_size, void* d_ws, size_t ws_size,
                              hipStream_t stream) {
  const float* h   = (const float*)d_in[0];
  const float* e   = (const float*)d_in[1];
  const float* aw1 = (const float*)d_in[2];
  const float* ab1 = (const float*)d_in[3];
  const float* aw2 = (const float*)d_in[4];
  const float* ab2 = (const float*)d_in[5];
  const float* aw3 = (const float*)d_in[6];
  const float* ab3 = (const float*)d_in[7];
  const float* nw1 = (const float*)d_in[8];
  const float* nb1 = (const float*)d_in[9];
  const float* nw2 = (const float*)d_in[10];
  const float* nb2 = (const float*)d_in[11];
  const float* nw3 = (const float*)d_in[12];
  const float* nb3 = (const float*)d_in[13];
  const float* thw = (const float*)d_in[14];
  const float* gw1 = (const float*)d_in[15];
  const float* gb1 = (const float*)d_in[16];
  const float* gw2 = (const float*)d_in[17];
  const float* gb2 = (const float*)d_in[18];
  const float* gw3 = (const float*)d_in[19];
  const float* gb3 = (const float*)d_in[20];
  const int* edge_idx = (const int*)d_in[21];

  char* ws = (char*)d_ws;
  ushortT* WF1 = (ushortT*)(ws + 0);        // 131072 B
  ushortT* WF2 = (ushortT*)(ws + 131072);   // 65536 B
  ushortT* WF3 = (ushortT*)(ws + 196608);   // 32768 B
  float* bias1 = (float*)(ws + 229376);     // 1024 B
  float* bias2 = (float*)(ws + 230400);     // 1024 B
  float* bias3 = (float*)(ws + 231424);     // 512 B
  float* p2    = (float*)(ws + 231936);     // 131072 B
  float* gout  = (float*)(ws + 363008);     // 512 B
  float* hh    = (float*)d_out;

  pack_kernel<<<59, 256, 0, stream>>>(aw1, nw1, aw2, nw2, nw3,
                                      ab1, nb1, ab2, nb2, nb3,
                                      WF1, WF2, WF3, bias1, bias2, bias3);

  // U = h @ aw1[0:128,:] into the output buffer (consumed in-place by edge_kernel)
  ub_kernel<<<NN/16, 256, 0, stream>>>(h, aw1, hh);

  const int SMEM = 35072;
  hipFuncSetAttribute((const void*)edge_kernel,
                      hipFuncAttributeMaxDynamicSharedMemorySize, SMEM);
  edge_kernel<<<NN/2, 512, SMEM, stream>>>(h, e, edge_idx, WF1, WF2, WF3,
                                           bias1, bias2, bias3, aw3, ab3, hh);

  reduce1_kernel<<<256, 256, 0, stream>>>(hh, p2);
  gate_kernel<<<1, 256, 0, stream>>>(p2, thw, gw1, gb1, gw2, gb2, gw3, gb3, gout);
  toh_scale_kernel<<<NN/16, 256, 0, stream>>>(hh, thw, gout);
}

// Round 3
// 536.290 us; speedup vs baseline: 1.1132x; 1.0232x over previous
//
#include <hip/hip_runtime.h>
#include <math.h>

#define NN 16384
#define KNB 30
#define NE (NN*KNB)   // 491520

typedef __attribute__((ext_vector_type(8))) __bf16 bf16x8;
typedef __attribute__((ext_vector_type(4))) float f32x4;
typedef unsigned short ushortT;
typedef __attribute__((ext_vector_type(8))) unsigned short ushort8v;

#define SWZ(r) (((r)&7)<<4)

__device__ __forceinline__ ushortT f2bf(float x){
  __bf16 b = (__bf16)x;
  union { __bf16 b; ushortT u; } v; v.b = b; return v.u;
}
__device__ __forceinline__ float bf2f(ushortT u){
  union { unsigned int u32; float f; } v; v.u32 = ((unsigned int)u) << 16;
  return v.f;
}
// A&S 7.1.26 erf (|err| <= 1.5e-7), exact-GELU compatible at bf16 tolerance
__device__ __forceinline__ float gelu_f(float x){
  float ax = fabsf(x) * 0.7071067811865476f;
  float t = 1.0f / (1.0f + 0.3275911f * ax);
  float poly = t*(0.254829592f + t*(-0.284496736f + t*(1.421413741f +
               t*(-1.453152027f + t*1.061405429f))));
  float er = 1.0f - poly * __expf(-ax*ax);
  er = copysignf(er, x);
  return 0.5f * x * (1.0f + er);
}

// ---------------- prep: weights -> bf16 in MFMA-fragment order ----------------
// Fragment unit = 64 lanes x 8 bf16 (one B-operand wave-load = 1KB contiguous).
// WF1: 128 tiles = ((half*8+nt)*8+kt), k over [e|hj] (att: aw1 rows 128..383)
// WF2: 64 tiles  = ((half*8+nt)*4+kt)
// WF3: 32 tiles  = (nt*4+kt), nw3^T
__global__ void pack_kernel(const float* __restrict__ aw1, const float* __restrict__ nw1,
                            const float* __restrict__ aw2, const float* __restrict__ nw2,
                            const float* __restrict__ nw3,
                            const float* __restrict__ ab1, const float* __restrict__ nb1,
                            const float* __restrict__ ab2, const float* __restrict__ nb2,
                            const float* __restrict__ nb3,
                            ushortT* __restrict__ WF1, ushortT* __restrict__ WF2,
                            ushortT* __restrict__ WF3,
                            float* __restrict__ bias1, float* __restrict__ bias2,
                            float* __restrict__ bias3)
{
  int u = blockIdx.x * blockDim.x + threadIdx.x;
  if (u < 8192) {
    int lane = u & 63, tile = u >> 6;
    int half = tile >> 6, nt = (tile >> 3) & 7, kt = tile & 7;
    int mrow = lane & 15, krow = lane >> 4;
    int n = half*128 + nt*16 + mrow, k0 = kt*32 + krow*8;
    ushort8v o;
    #pragma unroll
    for (int j = 0; j < 8; ++j) {
      int k = k0 + j;
      float v = (half == 0) ? aw1[(128 + k)*128 + n] : nw1[k*128 + (n - 128)];
      o[j] = f2bf(v);
    }
    *(ushort8v*)(WF1 + (size_t)u*8) = o;
    return;
  }
  u -= 8192;
  if (u < 4096) {
    int lane = u & 63, tile = u >> 6;
    int half = tile >> 5, nt = (tile >> 2) & 7, kt = tile & 3;
    int mrow = lane & 15, krow = lane >> 4;
    int n = half*128 + nt*16 + mrow, k0 = kt*32 + krow*8;
    ushort8v o;
    #pragma unroll
    for (int j = 0; j < 8; ++j) {
      int k = k0 + j;
      float v = (half == 0) ? aw2[k*128 + n] : nw2[k*128 + (n - 128)];
      o[j] = f2bf(v);
    }
    *(ushort8v*)(WF2 + (size_t)u*8) = o;
    return;
  }
  u -= 4096;
  if (u < 2048) {
    int lane = u & 63, tile = u >> 6;
    int nt = tile >> 2, kt = tile & 3;
    int mrow = lane & 15, krow = lane >> 4;
    int n = nt*16 + mrow, k0 = kt*32 + krow*8;
    ushort8v o;
    #pragma unroll
    for (int j = 0; j < 8; ++j) o[j] = f2bf(nw3[(k0 + j)*128 + n]);
    *(ushort8v*)(WF3 + (size_t)u*8) = o;
    return;
  }
  u -= 2048;
  if (u < 256) { bias1[u] = (u < 128) ? ab1[u] : nb1[u - 128]; return; }
  u -= 256;
  if (u < 256) { bias2[u] = (u < 128) ? ab2[u] : nb2[u - 128]; return; }
  u -= 128 + 128;
  if (u >= 0 && u < 128) { bias3[u] = nb3[u]; return; }
}

// ---------------- U = h @ aw1[0:128,:]  (per-node att first-layer part) -------
// Written into the hh/output buffer; edge_kernel consumes its own row before
// overwriting it with hh0. 16 nodes/block, 256 threads, 8 rows/thread.
__global__ void ub_kernel(const float* __restrict__ h, const float* __restrict__ aw1,
                          float* __restrict__ U)
{
  __shared__ float hs[16][128];
  int tid = threadIdx.x;
  size_t n0 = (size_t)blockIdx.x * 16;
  {
    int r = tid >> 4, c = (tid & 15) * 8;
    const float* src = h + (n0 + r)*128 + c;
    *(float4*)&hs[r][c]     = *(const float4*)src;
    *(float4*)&hs[r][c + 4] = *(const float4*)(src + 4);
  }
  __syncthreads();
  int d = tid & 127, gq = tid >> 7;
  float s[8] = {0.f,0.f,0.f,0.f,0.f,0.f,0.f,0.f};
  for (int c = 0; c < 128; ++c) {
    float w = aw1[c*128 + d];
    #pragma unroll
    for (int r = 0; r < 8; ++r) s[r] += hs[gq*8 + r][c] * w;
  }
  #pragma unroll
  for (int r = 0; r < 8; ++r) U[(n0 + gq*8 + r)*128 + d] = s[r];
}

// ---------------- fused edge pipeline: 1 node (30 edges), 256 threads ---------
// LDS: Xb [32 rows][512B] XOR-swizzled bf16 (16 KiB); V3f [30][132] f32 overlays
// Xb; lg[32]; Ubs[128]. Total 17024 B. 4 waves/block -> fine-grained occupancy:
// reg limit 72 (40 arch + 32 acc) -> 7 waves/SIMD = 28 waves/CU (~87%).
__global__ __launch_bounds__(256, 6) void edge_kernel(
    const float* __restrict__ h, const float* __restrict__ e,
    const int* __restrict__ edge_idx,
    const ushortT* __restrict__ WF1, const ushortT* __restrict__ WF2,
    const ushortT* __restrict__ WF3,
    const float* __restrict__ bias1, const float* __restrict__ bias2,
    const float* __restrict__ bias3,
    const float* __restrict__ aw3, const float* __restrict__ ab3,
    float* __restrict__ hh)
{
  extern __shared__ char smem[];
  char*  Xb   = smem;                       // [32][512B] swizzled bf16 (16384 B)
  float* V3f  = (float*)smem;               // [30][132] f32 overlay (15840 B)
  float* lg   = (float*)(smem + 16384);     // [32]
  float* Ubs  = (float*)(smem + 16512);     // [128]

  const int tid  = threadIdx.x;
  const int lane = tid & 63;
  const int wid  = tid >> 6;
  const int node = blockIdx.x;
  const long e0 = (long)node * KNB;

  // U for this block's node (precomputed by ub_kernel into hh row);
  // issue the load early so it's in flight during staging.
  float uval = 0.f;
  if (tid < 128) uval = hh[(size_t)node*128 + tid];

  // ---- Phase 0: stage X = [e | hj] bf16, swizzled; rows 30..31 zeroed ----
  #pragma unroll
  for (int it = 0; it < 4; ++it) {
    int idx = it*256 + tid;
    int r = idx >> 5, c8 = idx & 31;
    ushort8v u = {0,0,0,0,0,0,0,0};
    if (r < KNB) {
      long edge = e0 + r;
      const float* src;
      if (c8 < 16) src = e + (size_t)edge*128 + c8*8;
      else {
        int dst = edge_idx[NE + edge];
        src = h + (size_t)dst*128 + (c8 - 16)*8;
      }
      float4 v0 = *(const float4*)src;
      float4 v1 = *(const float4*)(src + 4);
      u[0]=f2bf(v0.x); u[1]=f2bf(v0.y); u[2]=f2bf(v0.z); u[3]=f2bf(v0.w);
      u[4]=f2bf(v1.x); u[5]=f2bf(v1.y); u[6]=f2bf(v1.z); u[7]=f2bf(v1.w);
    }
    *(ushort8v*)(Xb + r*512 + ((c8*16) ^ SWZ(r))) = u;
  }
  if (tid < 128) Ubs[tid] = uval;
  __syncthreads();

  const int mrow = lane & 15, krow = lane >> 4;
  const int wr = wid >> 1;   // row strip (16 rows)
  const int wc = wid & 1;    // col half

  f32x4 acc[8];
  #pragma unroll
  for (int nt = 0; nt < 8; ++nt) acc[nt] = (f32x4){0.f,0.f,0.f,0.f};

  // ---- GEMM1: X[32x256] @ WF1 -> (W1|V1)[32x256] ----
  for (int kt = 0; kt < 8; ++kt) {
    int row = wr*16 + mrow;
    bf16x8 a = *(const bf16x8*)(Xb + row*512 + ((kt*64 + krow*16) ^ SWZ(row)));
    const ushortT* Bp = WF1 + ((size_t)(wc*8)*8 + kt)*512 + lane*8;
    #pragma unroll
    for (int nt = 0; nt < 8; ++nt) {
      bf16x8 b = *(const bf16x8*)(Bp + (size_t)nt*8*512);
      acc[nt] = __builtin_amdgcn_mfma_f32_16x16x32_bf16(a, b, acc[nt], 0, 0, 0);
    }
  }
  __syncthreads();
  // epilogue 1: +bias (+Ub on att half), relu/gelu, store bf16 in place
  {
    float bia[8];
    #pragma unroll
    for (int nt = 0; nt < 8; ++nt) bia[nt] = bias1[wc*128 + nt*16 + mrow];
    #pragma unroll
    for (int rr = 0; rr < 4; ++rr) {
      int row = wr*16 + krow*4 + rr;
      #pragma unroll
      for (int nt = 0; nt < 8; ++nt) {
        int col = wc*128 + nt*16 + mrow;
        float x = acc[nt][rr] + bia[nt];
        x = (wc == 0) ? fmaxf(x + Ubs[col], 0.f) : gelu_f(x);
        *(ushortT*)(Xb + row*512 + ((2*col) ^ SWZ(row))) = f2bf(x);
      }
    }
  }
  __syncthreads();

  // ---- GEMM2: W2 = relu(W1@aw2), V2 = gelu(V1@nw2) ----
  #pragma unroll
  for (int nt = 0; nt < 8; ++nt) acc[nt] = (f32x4){0.f,0.f,0.f,0.f};
  for (int kt = 0; kt < 4; ++kt) {
    int row = wr*16 + mrow;
    bf16x8 a = *(const bf16x8*)(Xb + row*512 + ((wc*256 + kt*64 + krow*16) ^ SWZ(row)));
    const ushortT* Bp = WF2 + ((size_t)(wc*8)*4 + kt)*512 + lane*8;
    #pragma unroll
    for (int nt = 0; nt < 8; ++nt) {
      bf16x8 b = *(const bf16x8*)(Bp + (size_t)nt*4*512);
      acc[nt] = __builtin_amdgcn_mfma_f32_16x16x32_bf16(a, b, acc[nt], 0, 0, 0);
    }
  }
  __syncthreads();
  // epilogue 2: store swapped [V2 | W2] (V2 -> cols 0..127);
  // wc==0 waves hold W2 in-register -> fuse the logits dot (W2 . aw3) here.
  {
    float bia[8];
    #pragma unroll
    for (int nt = 0; nt < 8; ++nt) bia[nt] = bias2[wc*128 + nt*16 + mrow];
    float aw3c[8];
    if (wc == 0) {
      #pragma unroll
      for (int nt = 0; nt < 8; ++nt) aw3c[nt] = aw3[nt*16 + mrow];
    }
    float ab3v = ab3[0];
    #pragma unroll
    for (int rr = 0; rr < 4; ++rr) {
      int row = wr*16 + krow*4 + rr;
      float lsum = 0.f;
      #pragma unroll
      for (int nt = 0; nt < 8; ++nt) {
        int col = wc*128 + nt*16 + mrow;
        float x = acc[nt][rr] + bia[nt];
        x = (wc == 0) ? fmaxf(x, 0.f) : gelu_f(x);
        if (wc == 0) lsum += x * aw3c[nt];
        *(ushortT*)(Xb + row*512 + ((2*(col ^ 128)) ^ SWZ(row))) = f2bf(x);
      }
      if (wc == 0) {
        lsum += __shfl_xor(lsum, 1);
        lsum += __shfl_xor(lsum, 2);
        lsum += __shfl_xor(lsum, 4);
        lsum += __shfl_xor(lsum, 8);
        if (mrow == 0) lg[row] = (lsum + ab3v) * 0.08838834764831845f;
      }
    }
  }
  __syncthreads();

  // ---- GEMM3: V3 = V2 @ nw3 (A = cols 0..127) ----
  f32x4 acc3[4];
  #pragma unroll
  for (int nt = 0; nt < 4; ++nt) acc3[nt] = (f32x4){0.f,0.f,0.f,0.f};
  for (int kt = 0; kt < 4; ++kt) {
    int row = wr*16 + mrow;
    bf16x8 a = *(const bf16x8*)(Xb + row*512 + ((kt*64 + krow*16) ^ SWZ(row)));
    const ushortT* Bp = WF3 + ((size_t)(wc*4)*4 + kt)*512 + lane*8;
    #pragma unroll
    for (int nt = 0; nt < 4; ++nt) {
      bf16x8 b = *(const bf16x8*)(Bp + (size_t)nt*4*512);
      acc3[nt] = __builtin_amdgcn_mfma_f32_16x16x32_bf16(a, b, acc3[nt], 0, 0, 0);
    }
  }
  __syncthreads();   // all Xb reads complete before f32 overlay
  // V3 dump f32 over Xb region (rows < 30 only)
  {
    float bia[4];
    #pragma unroll
    for (int nt = 0; nt < 4; ++nt) bia[nt] = bias3[wc*64 + nt*16 + mrow];
    #pragma unroll
    for (int nt = 0; nt < 4; ++nt)
      #pragma unroll
      for (int rr = 0; rr < 4; ++rr) {
        int row = wr*16 + krow*4 + rr;
        int col = wc*64 + nt*16 + mrow;
        if (row < KNB) V3f[row*132 + col] = acc3[nt][rr] + bia[nt];
      }
  }
  __syncthreads();

  // ---- softmax over 30 neighbors (each wave: full softmax + 32 cols of PV) ----
  {
    int dh = wid * 32;
    int cl = lane & 31;
    float x = (lane < KNB) ? lg[lane] : -INFINITY;
    float m = x;
    #pragma unroll
    for (int off = 32; off >= 1; off >>= 1) m = fmaxf(m, __shfl_xor(m, off));
    float p = (lane < KNB) ? __expf(x - m) : 0.f;
    float ssum = p;
    #pragma unroll
    for (int off = 32; off >= 1; off >>= 1) ssum += __shfl_xor(ssum, off);
    float attv = p / ssum;
    float s = 0.f;
    #pragma unroll
    for (int k2 = 0; k2 < KNB; ++k2) {
      float a = __shfl(attv, k2);
      s += a * V3f[(size_t)k2*132 + dh + cl];
    }
    if (lane < 32) hh[(size_t)node*128 + dh + cl] = s;
  }
}

// ---------------- deterministic column reduction over nodes (on hh0) ----------
__global__ void reduce1_kernel(const float* __restrict__ hh, float* __restrict__ p2) {
  int b = blockIdx.x, tid = threadIdx.x;
  int d = tid & 127, half = tid >> 7;
  float s = 0.f;
  const float* base = hh + (size_t)(b*64 + half*32)*128 + d;
  #pragma unroll 4
  for (int i = 0; i < 32; ++i) s += base[(size_t)i*128];
  __shared__ float ps[256];
  ps[tid] = s; __syncthreads();
  if (tid < 128) p2[b*128 + tid] = ps[tid] + ps[tid + 128];
}

// gate: c0 = mean(hh0); c = c0 @ thw; g = sigmoid(MLP(c))
__global__ void gate_kernel(const float* __restrict__ p2, const float* __restrict__ thw,
                            const float* __restrict__ gw1, const float* __restrict__ gb1,
                            const float* __restrict__ gw2, const float* __restrict__ gb2,
                            const float* __restrict__ gw3, const float* __restrict__ gb3,
                            float* __restrict__ gout) {
  int tid = threadIdx.x;
  int d = tid & 127, half = tid >> 7;
  float s = 0.f;
  for (int i = 0; i < 128; ++i) s += p2[(half*128 + i)*128 + d];
  __shared__ float ps[256];
  __shared__ float cv[128], cv2[128], y1[128], y2[128];
  ps[tid] = s; __syncthreads();
  if (tid < 128) cv[tid] = (ps[tid] + ps[tid+128]) * (1.f / (float)NN);
  __syncthreads();
  if (tid < 128) {
    float a = 0.f;
    for (int c = 0; c < 128; ++c) a += cv[c] * thw[c*128 + tid];
    cv2[tid] = a;
  }
  __syncthreads();
  if (tid < 128) {
    float a = gb1[tid];
    for (int c = 0; c < 128; ++c) a += cv2[c] * gw1[c*128 + tid];
    y1[tid] = fmaxf(a, 0.f);
  }
  __syncthreads();
  if (tid < 128) {
    float a = gb2[tid];
    for (int c = 0; c < 128; ++c) a += y1[c] * gw2[c*128 + tid];
    y2[tid] = fmaxf(a, 0.f);
  }
  __syncthreads();
  if (tid < 128) {
    float a = gb3[tid];
    for (int c = 0; c < 128; ++c) a += y2[c] * gw3[c*128 + tid];
    gout[tid] = 1.f / (1.f + __expf(-a));
  }
}

// ---------------- fused to_h + gate scale: out = (hh0 @ thw) * g, in place ----
__global__ void toh_scale_kernel(float* __restrict__ hh, const float* __restrict__ thw,
                                 const float* __restrict__ gv)
{
  __shared__ float hs[16][128];
  int tid = threadIdx.x;
  size_t n0 = (size_t)blockIdx.x * 16;
  {
    int r = tid >> 4, c = (tid & 15) * 8;
    const float* src = hh + (n0 + r)*128 + c;
    *(float4*)&hs[r][c]     = *(const float4*)src;
    *(float4*)&hs[r][c + 4] = *(const float4*)(src + 4);
  }
  __syncthreads();
  int d = tid & 127, gq = tid >> 7;
  float s[8] = {0.f,0.f,0.f,0.f,0.f,0.f,0.f,0.f};
  for (int c = 0; c < 128; ++c) {
    float w = thw[c*128 + d];
    #pragma unroll
    for (int r = 0; r < 8; ++r) s[r] += hs[gq*8 + r][c] * w;
  }
  float gd = gv[d];
  #pragma unroll
  for (int r = 0; r < 8; ++r) hh[(n0 + gq*8 + r)*128 + d] = s[r] * gd;
}

extern "C" void kernel_launch(void* const* d_in, const int* in_sizes, int n_in,
                              void* d_out, int out_size, void* d_ws, size_t ws_size,
                              hipStream_t stream) {
  const float* h   = (const float*)d_in[0];
  const float* e   = (const float*)d_in[1];
  const float* aw1 = (const float*)d_in[2];
  const float* ab1 = (const float*)d_in[3];
  const float* aw2 = (const float*)d_in[4];
  const float* ab2 = (const float*)d_in[5];
  const float* aw3 = (const float*)d_in[6];
  const float* ab3 = (const float*)d_in[7];
  const float* nw1 = (const float*)d_in[8];
  const float* nb1 = (const float*)d_in[9];
  const float* nw2 = (const float*)d_in[10];
  const float* nb2 = (const float*)d_in[11];
  const float* nw3 = (const float*)d_in[12];
  const float* nb3 = (const float*)d_in[13];
  const float* thw = (const float*)d_in[14];
  const float* gw1 = (const float*)d_in[15];
  const float* gb1 = (const float*)d_in[16];
  const float* gw2 = (const float*)d_in[17];
  const float* gb2 = (const float*)d_in[18];
  const float* gw3 = (const float*)d_in[19];
  const float* gb3 = (const float*)d_in[20];
  const int* edge_idx = (const int*)d_in[21];

  char* ws = (char*)d_ws;
  ushortT* WF1 = (ushortT*)(ws + 0);        // 131072 B
  ushortT* WF2 = (ushortT*)(ws + 131072);   // 65536 B
  ushortT* WF3 = (ushortT*)(ws + 196608);   // 32768 B
  float* bias1 = (float*)(ws + 229376);     // 1024 B
  float* bias2 = (float*)(ws + 230400);     // 1024 B
  float* bias3 = (float*)(ws + 231424);     // 512 B
  float* p2    = (float*)(ws + 231936);     // 131072 B
  float* gout  = (float*)(ws + 363008);     // 512 B
  float* hh    = (float*)d_out;

  pack_kernel<<<59, 256, 0, stream>>>(aw1, nw1, aw2, nw2, nw3,
                                      ab1, nb1, ab2, nb2, nb3,
                                      WF1, WF2, WF3, bias1, bias2, bias3);

  // U = h @ aw1[0:128,:] into the output buffer (consumed in-place by edge_kernel)
  ub_kernel<<<NN/16, 256, 0, stream>>>(h, aw1, hh);

  const int SMEM = 17024;
  hipFuncSetAttribute((const void*)edge_kernel,
                      hipFuncAttributeMaxDynamicSharedMemorySize, SMEM);
  edge_kernel<<<NN, 256, SMEM, stream>>>(h, e, edge_idx, WF1, WF2, WF3,
                                         bias1, bias2, bias3, aw3, ab3, hh);

  reduce1_kernel<<<256, 256, 0, stream>>>(hh, p2);
  gate_kernel<<<1, 256, 0, stream>>>(p2, thw, gw1, gb1, gw2, gb2, gw3, gb3, gout);
  toh_scale_kernel<<<NN/16, 256, 0, stream>>>(hh, thw, gout);
}

// Round 4
// 436.333 us; speedup vs baseline: 1.3682x; 1.2291x over previous
//
#include <hip/hip_runtime.h>
#include <math.h>

#define NN 16384
#define KNB 30
#define NE (NN*KNB)   // 491520

typedef __attribute__((ext_vector_type(8))) __bf16 bf16x8;
typedef __attribute__((ext_vector_type(4))) float f32x4;
typedef unsigned short ushortT;
typedef __attribute__((ext_vector_type(8))) unsigned short ushort8v;

#define SWZ(r) (((r)&7)<<4)

__device__ __forceinline__ ushortT f2bf(float x){
  __bf16 b = (__bf16)x;
  union { __bf16 b; ushortT u; } v; v.b = b; return v.u;
}
__device__ __forceinline__ float bf2f(ushortT u){
  union { unsigned int u32; float f; } v; v.u32 = ((unsigned int)u) << 16;
  return v.f;
}
// A&S 7.1.26 erf (|err| <= 1.5e-7), exact-GELU compatible at bf16 tolerance
__device__ __forceinline__ float gelu_f(float x){
  float ax = fabsf(x) * 0.7071067811865476f;
  float t = 1.0f / (1.0f + 0.3275911f * ax);
  float poly = t*(0.254829592f + t*(-0.284496736f + t*(1.421413741f +
               t*(-1.453152027f + t*1.061405429f))));
  float er = 1.0f - poly * __expf(-ax*ax);
  er = copysignf(er, x);
  return 0.5f * x * (1.0f + er);
}

// ---------------- prep: weights -> bf16 in MFMA-fragment order ----------------
// Fragment unit = 64 lanes x 8 bf16 (one B-operand wave-load = 1KB contiguous).
// WF1: 128 tiles = ((half*8+nt)*8+kt), k over [e|hj] (att: aw1 rows 128..383)
// WF2: 64 tiles  = ((half*8+nt)*4+kt)
// WF3: 32 tiles  = (nt*4+kt), nw3^T
__global__ void pack_kernel(const float* __restrict__ aw1, const float* __restrict__ nw1,
                            const float* __restrict__ aw2, const float* __restrict__ nw2,
                            const float* __restrict__ nw3,
                            const float* __restrict__ ab1, const float* __restrict__ nb1,
                            const float* __restrict__ ab2, const float* __restrict__ nb2,
                            const float* __restrict__ nb3,
                            ushortT* __restrict__ WF1, ushortT* __restrict__ WF2,
                            ushortT* __restrict__ WF3,
                            float* __restrict__ bias1, float* __restrict__ bias2,
                            float* __restrict__ bias3)
{
  int u = blockIdx.x * blockDim.x + threadIdx.x;
  if (u < 8192) {
    int lane = u & 63, tile = u >> 6;
    int half = tile >> 6, nt = (tile >> 3) & 7, kt = tile & 7;
    int mrow = lane & 15, krow = lane >> 4;
    int n = half*128 + nt*16 + mrow, k0 = kt*32 + krow*8;
    ushort8v o;
    #pragma unroll
    for (int j = 0; j < 8; ++j) {
      int k = k0 + j;
      float v = (half == 0) ? aw1[(128 + k)*128 + n] : nw1[k*128 + (n - 128)];
      o[j] = f2bf(v);
    }
    *(ushort8v*)(WF1 + (size_t)u*8) = o;
    return;
  }
  u -= 8192;
  if (u < 4096) {
    int lane = u & 63, tile = u >> 6;
    int half = tile >> 5, nt = (tile >> 2) & 7, kt = tile & 3;
    int mrow = lane & 15, krow = lane >> 4;
    int n = half*128 + nt*16 + mrow, k0 = kt*32 + krow*8;
    ushort8v o;
    #pragma unroll
    for (int j = 0; j < 8; ++j) {
      int k = k0 + j;
      float v = (half == 0) ? aw2[k*128 + n] : nw2[k*128 + (n - 128)];
      o[j] = f2bf(v);
    }
    *(ushort8v*)(WF2 + (size_t)u*8) = o;
    return;
  }
  u -= 4096;
  if (u < 2048) {
    int lane = u & 63, tile = u >> 6;
    int nt = tile >> 2, kt = tile & 3;
    int mrow = lane & 15, krow = lane >> 4;
    int n = nt*16 + mrow, k0 = kt*32 + krow*8;
    ushort8v o;
    #pragma unroll
    for (int j = 0; j < 8; ++j) o[j] = f2bf(nw3[(k0 + j)*128 + n]);
    *(ushort8v*)(WF3 + (size_t)u*8) = o;
    return;
  }
  u -= 2048;
  if (u < 256) { bias1[u] = (u < 128) ? ab1[u] : nb1[u - 128]; return; }
  u -= 256;
  if (u < 256) { bias2[u] = (u < 128) ? ab2[u] : nb2[u - 128]; return; }
  u -= 128 + 128;
  if (u >= 0 && u < 128) { bias3[u] = nb3[u]; return; }
}

// ---------------- U = h @ aw1[0:128,:]  (per-node att first-layer part) -------
// Written into the hh/output buffer; edge_kernel consumes its own row before
// overwriting it with hh0. 16 nodes/block, 256 threads, 8 rows/thread.
__global__ void ub_kernel(const float* __restrict__ h, const float* __restrict__ aw1,
                          float* __restrict__ U)
{
  __shared__ float hs[16][128];
  int tid = threadIdx.x;
  size_t n0 = (size_t)blockIdx.x * 16;
  {
    int r = tid >> 4, c = (tid & 15) * 8;
    const float* src = h + (n0 + r)*128 + c;
    *(float4*)&hs[r][c]     = *(const float4*)src;
    *(float4*)&hs[r][c + 4] = *(const float4*)(src + 4);
  }
  __syncthreads();
  int d = tid & 127, gq = tid >> 7;
  float s[8] = {0.f,0.f,0.f,0.f,0.f,0.f,0.f,0.f};
  for (int c = 0; c < 128; ++c) {
    float w = aw1[c*128 + d];
    #pragma unroll
    for (int r = 0; r < 8; ++r) s[r] += hs[gq*8 + r][c] * w;
  }
  #pragma unroll
  for (int r = 0; r < 8; ++r) U[(n0 + gq*8 + r)*128 + d] = s[r];
}

// ---------------- fused edge pipeline: 1 node (30 edges), 512 threads ---------
// 8 waves: wr = wid>>2 (16-row strip), wq = wid&3 (64-col quarter).
// acc = 4 x f32x4 = 16 AGPRs -> target 64 total regs -> 8 waves/SIMD.
// LDS: Xb [32][512B] XOR-swizzled bf16 (16 KiB); V3f [30][132] f32 overlay;
// lgp[2][32] logits partials; Ubs[128]. Total 17152 B -> 4 blocks/CU (32 waves).
__global__ __launch_bounds__(512, 8) void edge_kernel(
    const float* __restrict__ h, const float* __restrict__ e,
    const int* __restrict__ edge_idx,
    const ushortT* __restrict__ WF1, const ushortT* __restrict__ WF2,
    const ushortT* __restrict__ WF3,
    const float* __restrict__ bias1, const float* __restrict__ bias2,
    const float* __restrict__ bias3,
    const float* __restrict__ aw3, const float* __restrict__ ab3,
    float* __restrict__ hh)
{
  extern __shared__ char smem[];
  char*  Xb   = smem;                       // [32][512B] swizzled bf16 (16384 B)
  float* V3f  = (float*)smem;               // [30][132] f32 overlay (15840 B)
  float* lgp  = (float*)(smem + 16384);     // [2][32] logits partials
  float* Ubs  = (float*)(smem + 16640);     // [128]

  const int tid  = threadIdx.x;
  const int lane = tid & 63;
  const int wid  = tid >> 6;
  const int node = blockIdx.x;
  const long e0 = (long)node * KNB;

  // U for this block's node (precomputed by ub_kernel into hh row)
  float uval = 0.f;
  if (tid < 128) uval = hh[(size_t)node*128 + tid];

  // ---- Phase 0: stage X = [e | hj] bf16, swizzled; rows 30..31 zeroed ----
  #pragma unroll
  for (int it = 0; it < 2; ++it) {
    int idx = it*512 + tid;
    int r = idx >> 5, c8 = idx & 31;
    ushort8v u = {0,0,0,0,0,0,0,0};
    if (r < KNB) {
      long edge = e0 + r;
      const float* src;
      if (c8 < 16) src = e + (size_t)edge*128 + c8*8;
      else {
        int dst = edge_idx[NE + edge];
        src = h + (size_t)dst*128 + (c8 - 16)*8;
      }
      float4 v0 = *(const float4*)src;
      float4 v1 = *(const float4*)(src + 4);
      u[0]=f2bf(v0.x); u[1]=f2bf(v0.y); u[2]=f2bf(v0.z); u[3]=f2bf(v0.w);
      u[4]=f2bf(v1.x); u[5]=f2bf(v1.y); u[6]=f2bf(v1.z); u[7]=f2bf(v1.w);
    }
    *(ushort8v*)(Xb + r*512 + ((c8*16) ^ SWZ(r))) = u;
  }
  if (tid < 128) Ubs[tid] = uval;
  __syncthreads();

  const int mrow = lane & 15, krow = lane >> 4;
  const int wr = wid >> 2;   // row strip (16 rows)
  const int wq = wid & 3;    // col quarter (64 cols)
  const int row = wr*16 + mrow;

  f32x4 acc[4];
  #pragma unroll
  for (int nt = 0; nt < 4; ++nt) acc[nt] = (f32x4){0.f,0.f,0.f,0.f};

  // ---- GEMM1: X[32x256] @ WF1 -> (W1|V1)[32x256], wave = 16r x 64c ----
  for (int kt = 0; kt < 8; ++kt) {
    bf16x8 a = *(const bf16x8*)(Xb + row*512 + ((kt*64 + krow*16) ^ SWZ(row)));
    const ushortT* Bp = WF1 + ((size_t)((wq>>1)*8 + (wq&1)*4)*8 + kt)*512 + lane*8;
    #pragma unroll
    for (int nt = 0; nt < 4; ++nt) {
      bf16x8 b = *(const bf16x8*)(Bp + (size_t)nt*8*512);
      acc[nt] = __builtin_amdgcn_mfma_f32_16x16x32_bf16(a, b, acc[nt], 0, 0, 0);
    }
  }
  __syncthreads();
  // epilogue 1: +bias (+Ub on att half), relu/gelu, store bf16 in place
  {
    #pragma unroll
    for (int rr = 0; rr < 4; ++rr) {
      int orow = wr*16 + krow*4 + rr;
      #pragma unroll
      for (int nt = 0; nt < 4; ++nt) {
        int col = wq*64 + nt*16 + mrow;
        float x = acc[nt][rr] + bias1[col];
        x = (wq < 2) ? fmaxf(x + Ubs[col], 0.f) : gelu_f(x);
        *(ushortT*)(Xb + orow*512 + ((2*col) ^ SWZ(orow))) = f2bf(x);
      }
    }
  }
  __syncthreads();

  // ---- GEMM2: W2 = relu(W1@aw2), V2 = gelu(V1@nw2) ----
  #pragma unroll
  for (int nt = 0; nt < 4; ++nt) acc[nt] = (f32x4){0.f,0.f,0.f,0.f};
  for (int kt = 0; kt < 4; ++kt) {
    bf16x8 a = *(const bf16x8*)(Xb + row*512 + (((wq>>1)*256 + kt*64 + krow*16) ^ SWZ(row)));
    const ushortT* Bp = WF2 + ((size_t)((wq>>1)*8 + (wq&1)*4)*4 + kt)*512 + lane*8;
    #pragma unroll
    for (int nt = 0; nt < 4; ++nt) {
      bf16x8 b = *(const bf16x8*)(Bp + (size_t)nt*4*512);
      acc[nt] = __builtin_amdgcn_mfma_f32_16x16x32_bf16(a, b, acc[nt], 0, 0, 0);
    }
  }
  __syncthreads();
  // epilogue 2: V2 (gelu) -> Xb left half; W2 (relu) stays in regs and is
  // consumed here by the fused logits dot (its only use) -> no W2 LDS store.
  {
    if (wq < 2) {
      float aw3c[4];
      #pragma unroll
      for (int nt = 0; nt < 4; ++nt) aw3c[nt] = aw3[wq*64 + nt*16 + mrow];
      #pragma unroll
      for (int rr = 0; rr < 4; ++rr) {
        int orow = wr*16 + krow*4 + rr;
        float lsum = 0.f;
        #pragma unroll
        for (int nt = 0; nt < 4; ++nt) {
          int col = wq*64 + nt*16 + mrow;
          float x = fmaxf(acc[nt][rr] + bias2[col], 0.f);
          lsum += x * aw3c[nt];
        }
        lsum += __shfl_xor(lsum, 1);
        lsum += __shfl_xor(lsum, 2);
        lsum += __shfl_xor(lsum, 4);
        lsum += __shfl_xor(lsum, 8);
        if (mrow == 0) lgp[wq*32 + orow] = lsum;
      }
    } else {
      #pragma unroll
      for (int rr = 0; rr < 4; ++rr) {
        int orow = wr*16 + krow*4 + rr;
        #pragma unroll
        for (int nt = 0; nt < 4; ++nt) {
          int col = wq*64 + nt*16 + mrow;
          float x = gelu_f(acc[nt][rr] + bias2[col]);
          *(ushortT*)(Xb + orow*512 + ((2*(col ^ 128)) ^ SWZ(orow))) = f2bf(x);
        }
      }
    }
  }
  __syncthreads();

  // ---- GEMM3: V3 = V2 @ nw3 (A = Xb left half), wave = 16r x 32c ----
  f32x4 acc3[2];
  #pragma unroll
  for (int nt = 0; nt < 2; ++nt) acc3[nt] = (f32x4){0.f,0.f,0.f,0.f};
  for (int kt = 0; kt < 4; ++kt) {
    bf16x8 a = *(const bf16x8*)(Xb + row*512 + ((kt*64 + krow*16) ^ SWZ(row)));
    const ushortT* Bp = WF3 + ((size_t)(wq*2)*4*512 + (size_t)kt*512) + lane*8;
    #pragma unroll
    for (int nt = 0; nt < 2; ++nt) {
      bf16x8 b = *(const bf16x8*)(Bp + (size_t)nt*4*512);
      acc3[nt] = __builtin_amdgcn_mfma_f32_16x16x32_bf16(a, b, acc3[nt], 0, 0, 0);
    }
  }
  __syncthreads();   // all Xb reads complete before f32 overlay
  // V3 dump f32 over Xb region (rows < 30 only)
  {
    #pragma unroll
    for (int nt = 0; nt < 2; ++nt)
      #pragma unroll
      for (int rr = 0; rr < 4; ++rr) {
        int orow = wr*16 + krow*4 + rr;
        int col = wq*32 + nt*16 + mrow;
        if (orow < KNB) V3f[orow*132 + col] = acc3[nt][rr] + bias3[col];
      }
  }
  __syncthreads();

  // ---- softmax over 30 neighbors + PV (waves 0..3, 32 cols each) ----
  if (wid < 4) {
    int dh = wid * 32;
    int cl = lane & 31;
    float x = -INFINITY;
    if (lane < KNB)
      x = (lgp[lane] + lgp[32 + lane] + ab3[0]) * 0.08838834764831845f;
    float m = x;
    #pragma unroll
    for (int off = 32; off >= 1; off >>= 1) m = fmaxf(m, __shfl_xor(m, off));
    float p = (lane < KNB) ? __expf(x - m) : 0.f;
    float ssum = p;
    #pragma unroll
    for (int off = 32; off >= 1; off >>= 1) ssum += __shfl_xor(ssum, off);
    float attv = p / ssum;
    float s = 0.f;
    #pragma unroll
    for (int k2 = 0; k2 < KNB; ++k2) {
      float a = __shfl(attv, k2);
      s += a * V3f[(size_t)k2*132 + dh + cl];
    }
    if (lane < 32) hh[(size_t)node*128 + dh + cl] = s;
  }
}

// ---------------- deterministic column reduction over nodes (on hh0) ----------
__global__ void reduce1_kernel(const float* __restrict__ hh, float* __restrict__ p2) {
  int b = blockIdx.x, tid = threadIdx.x;
  int d = tid & 127, half = tid >> 7;
  float s = 0.f;
  const float* base = hh + (size_t)(b*64 + half*32)*128 + d;
  #pragma unroll 4
  for (int i = 0; i < 32; ++i) s += base[(size_t)i*128];
  __shared__ float ps[256];
  ps[tid] = s; __syncthreads();
  if (tid < 128) p2[b*128 + tid] = ps[tid] + ps[tid + 128];
}

// gate: c0 = mean(hh0); c = c0 @ thw; g = sigmoid(MLP(c))
__global__ void gate_kernel(const float* __restrict__ p2, const float* __restrict__ thw,
                            const float* __restrict__ gw1, const float* __restrict__ gb1,
                            const float* __restrict__ gw2, const float* __restrict__ gb2,
                            const float* __restrict__ gw3, const float* __restrict__ gb3,
                            float* __restrict__ gout) {
  int tid = threadIdx.x;
  int d = tid & 127, half = tid >> 7;
  float s = 0.f;
  for (int i = 0; i < 128; ++i) s += p2[(half*128 + i)*128 + d];
  __shared__ float ps[256];
  __shared__ float cv[128], cv2[128], y1[128], y2[128];
  ps[tid] = s; __syncthreads();
  if (tid < 128) cv[tid] = (ps[tid] + ps[tid+128]) * (1.f / (float)NN);
  __syncthreads();
  if (tid < 128) {
    float a = 0.f;
    for (int c = 0; c < 128; ++c) a += cv[c] * thw[c*128 + tid];
    cv2[tid] = a;
  }
  __syncthreads();
  if (tid < 128) {
    float a = gb1[tid];
    for (int c = 0; c < 128; ++c) a += cv2[c] * gw1[c*128 + tid];
    y1[tid] = fmaxf(a, 0.f);
  }
  __syncthreads();
  if (tid < 128) {
    float a = gb2[tid];
    for (int c = 0; c < 128; ++c) a += y1[c] * gw2[c*128 + tid];
    y2[tid] = fmaxf(a, 0.f);
  }
  __syncthreads();
  if (tid < 128) {
    float a = gb3[tid];
    for (int c = 0; c < 128; ++c) a += y2[c] * gw3[c*128 + tid];
    gout[tid] = 1.f / (1.f + __expf(-a));
  }
}

// ---------------- fused to_h + gate scale: out = (hh0 @ thw) * g, in place ----
__global__ void toh_scale_kernel(float* __restrict__ hh, const float* __restrict__ thw,
                                 const float* __restrict__ gv)
{
  __shared__ float hs[16][128];
  int tid = threadIdx.x;
  size_t n0 = (size_t)blockIdx.x * 16;
  {
    int r = tid >> 4, c = (tid & 15) * 8;
    const float* src = hh + (n0 + r)*128 + c;
    *(float4*)&hs[r][c]     = *(const float4*)src;
    *(float4*)&hs[r][c + 4] = *(const float4*)(src + 4);
  }
  __syncthreads();
  int d = tid & 127, gq = tid >> 7;
  float s[8] = {0.f,0.f,0.f,0.f,0.f,0.f,0.f,0.f};
  for (int c = 0; c < 128; ++c) {
    float w = thw[c*128 + d];
    #pragma unroll
    for (int r = 0; r < 8; ++r) s[r] += hs[gq*8 + r][c] * w;
  }
  float gd = gv[d];
  #pragma unroll
  for (int r = 0; r < 8; ++r) hh[(n0 + gq*8 + r)*128 + d] = s[r] * gd;
}

extern "C" void kernel_launch(void* const* d_in, const int* in_sizes, int n_in,
                              void* d_out, int out_size, void* d_ws, size_t ws_size,
                              hipStream_t stream) {
  const float* h   = (const float*)d_in[0];
  const float* e   = (const float*)d_in[1];
  const float* aw1 = (const float*)d_in[2];
  const float* ab1 = (const float*)d_in[3];
  const float* aw2 = (const float*)d_in[4];
  const float* ab2 = (const float*)d_in[5];
  const float* aw3 = (const float*)d_in[6];
  const float* ab3 = (const float*)d_in[7];
  const float* nw1 = (const float*)d_in[8];
  const float* nb1 = (const float*)d_in[9];
  const float* nw2 = (const float*)d_in[10];
  const float* nb2 = (const float*)d_in[11];
  const float* nw3 = (const float*)d_in[12];
  const float* nb3 = (const float*)d_in[13];
  const float* thw = (const float*)d_in[14];
  const float* gw1 = (const float*)d_in[15];
  const float* gb1 = (const float*)d_in[16];
  const float* gw2 = (const float*)d_in[17];
  const float* gb2 = (const float*)d_in[18];
  const float* gw3 = (const float*)d_in[19];
  const float* gb3 = (const float*)d_in[20];
  const int* edge_idx = (const int*)d_in[21];

  char* ws = (char*)d_ws;
  ushortT* WF1 = (ushortT*)(ws + 0);        // 131072 B
  ushortT* WF2 = (ushortT*)(ws + 131072);   // 65536 B
  ushortT* WF3 = (ushortT*)(ws + 196608);   // 32768 B
  float* bias1 = (float*)(ws + 229376);     // 1024 B
  float* bias2 = (float*)(ws + 230400);     // 1024 B
  float* bias3 = (float*)(ws + 231424);     // 512 B
  float* p2    = (float*)(ws + 231936);     // 131072 B
  float* gout  = (float*)(ws + 363008);     // 512 B
  float* hh    = (float*)d_out;

  pack_kernel<<<59, 256, 0, stream>>>(aw1, nw1, aw2, nw2, nw3,
                                      ab1, nb1, ab2, nb2, nb3,
                                      WF1, WF2, WF3, bias1, bias2, bias3);

  // U = h @ aw1[0:128,:] into the output buffer (consumed in-place by edge_kernel)
  ub_kernel<<<NN/16, 256, 0, stream>>>(h, aw1, hh);

  const int SMEM = 17152;
  hipFuncSetAttribute((const void*)edge_kernel,
                      hipFuncAttributeMaxDynamicSharedMemorySize, SMEM);
  edge_kernel<<<NN, 512, SMEM, stream>>>(h, e, edge_idx, WF1, WF2, WF3,
                                         bias1, bias2, bias3, aw3, ab3, hh);

  reduce1_kernel<<<256, 256, 0, stream>>>(hh, p2);
  gate_kernel<<<1, 256, 0, stream>>>(p2, thw, gw1, gb1, gw2, gb2, gw3, gb3, gout);
  toh_scale_kernel<<<NN/16, 256, 0, stream>>>(hh, thw, gout);
}

// Round 5
// 429.585 us; speedup vs baseline: 1.3897x; 1.0157x over previous
//
#include <hip/hip_runtime.h>
#include <math.h>

#define NN 16384
#define KNB 30
#define NE (NN*KNB)   // 491520

typedef __attribute__((ext_vector_type(8))) __bf16 bf16x8;
typedef __attribute__((ext_vector_type(4))) float f32x4;
typedef unsigned short ushortT;
typedef __attribute__((ext_vector_type(8))) unsigned short ushort8v;

#define SWZ(r) (((r)&7)<<4)

__device__ __forceinline__ ushortT f2bf(float x){
  __bf16 b = (__bf16)x;
  union { __bf16 b; ushortT u; } v; v.b = b; return v.u;
}
__device__ __forceinline__ float bf2f(ushortT u){
  union { unsigned int u32; float f; } v; v.u32 = ((unsigned int)u) << 16;
  return v.f;
}
// A&S 7.1.26 erf (|err| <= 1.5e-7), exact-GELU compatible at bf16 tolerance
__device__ __forceinline__ float gelu_f(float x){
  float ax = fabsf(x) * 0.7071067811865476f;
  float t = 1.0f / (1.0f + 0.3275911f * ax);
  float poly = t*(0.254829592f + t*(-0.284496736f + t*(1.421413741f +
               t*(-1.453152027f + t*1.061405429f))));
  float er = 1.0f - poly * __expf(-ax*ax);
  er = copysignf(er, x);
  return 0.5f * x * (1.0f + er);
}

// ---------------- prep: weights -> bf16 in MFMA-fragment order ----------------
// Fragment unit = 64 lanes x 8 bf16 (one B-operand wave-load = 1KB contiguous).
// WF1: 128 tiles = ((half*8+nt)*8+kt), k over [e|hj] (att: aw1 rows 128..383)
//      NOTE: kt 0..3 is exactly the e-part (k 0..127) -> reused by the hoisted
//      (K=128) GEMM1 path with tile stride 8.
// WF2: 64 tiles  = ((half*8+nt)*4+kt)
// WF3: 32 tiles  = (nt*4+kt), nw3^T
__global__ void pack_kernel(const float* __restrict__ aw1, const float* __restrict__ nw1,
                            const float* __restrict__ aw2, const float* __restrict__ nw2,
                            const float* __restrict__ nw3,
                            const float* __restrict__ ab1, const float* __restrict__ nb1,
                            const float* __restrict__ ab2, const float* __restrict__ nb2,
                            const float* __restrict__ nb3,
                            ushortT* __restrict__ WF1, ushortT* __restrict__ WF2,
                            ushortT* __restrict__ WF3,
                            float* __restrict__ bias1, float* __restrict__ bias2,
                            float* __restrict__ bias3)
{
  int u = blockIdx.x * blockDim.x + threadIdx.x;
  if (u < 8192) {
    int lane = u & 63, tile = u >> 6;
    int half = tile >> 6, nt = (tile >> 3) & 7, kt = tile & 7;
    int mrow = lane & 15, krow = lane >> 4;
    int n = half*128 + nt*16 + mrow, k0 = kt*32 + krow*8;
    ushort8v o;
    #pragma unroll
    for (int j = 0; j < 8; ++j) {
      int k = k0 + j;
      float v = (half == 0) ? aw1[(128 + k)*128 + n] : nw1[k*128 + (n - 128)];
      o[j] = f2bf(v);
    }
    *(ushort8v*)(WF1 + (size_t)u*8) = o;
    return;
  }
  u -= 8192;
  if (u < 4096) {
    int lane = u & 63, tile = u >> 6;
    int half = tile >> 5, nt = (tile >> 2) & 7, kt = tile & 3;
    int mrow = lane & 15, krow = lane >> 4;
    int n = half*128 + nt*16 + mrow, k0 = kt*32 + krow*8;
    ushort8v o;
    #pragma unroll
    for (int j = 0; j < 8; ++j) {
      int k = k0 + j;
      float v = (half == 0) ? aw2[k*128 + n] : nw2[k*128 + (n - 128)];
      o[j] = f2bf(v);
    }
    *(ushort8v*)(WF2 + (size_t)u*8) = o;
    return;
  }
  u -= 4096;
  if (u < 2048) {
    int lane = u & 63, tile = u >> 6;
    int nt = tile >> 2, kt = tile & 3;
    int mrow = lane & 15, krow = lane >> 4;
    int n = nt*16 + mrow, k0 = kt*32 + krow*8;
    ushort8v o;
    #pragma unroll
    for (int j = 0; j < 8; ++j) o[j] = f2bf(nw3[(k0 + j)*128 + n]);
    *(ushort8v*)(WF3 + (size_t)u*8) = o;
    return;
  }
  u -= 2048;
  if (u < 256) { bias1[u] = (u < 128) ? ab1[u] : nb1[u - 128]; return; }
  u -= 256;
  if (u < 256) { bias2[u] = (u < 128) ? ab2[u] : nb2[u - 128]; return; }
  u -= 128 + 128;
  if (u >= 0 && u < 128) { bias3[u] = nb3[u]; return; }
}

// ---------------- U = h @ aw1[0:128,:]  (per-node att src contribution) -------
// Written into the hh/output buffer; edge_kernel consumes its own row before
// overwriting it with hh0. 16 nodes/block, 256 threads, 8 rows/thread.
__global__ void ub_kernel(const float* __restrict__ h, const float* __restrict__ aw1,
                          float* __restrict__ U)
{
  __shared__ float hs[16][128];
  int tid = threadIdx.x;
  size_t n0 = (size_t)blockIdx.x * 16;
  {
    int r = tid >> 4, c = (tid & 15) * 8;
    const float* src = h + (n0 + r)*128 + c;
    *(float4*)&hs[r][c]     = *(const float4*)src;
    *(float4*)&hs[r][c + 4] = *(const float4*)(src + 4);
  }
  __syncthreads();
  int d = tid & 127, gq = tid >> 7;
  float s[8] = {0.f,0.f,0.f,0.f,0.f,0.f,0.f,0.f};
  for (int c = 0; c < 128; ++c) {
    float w = aw1[c*128 + d];
    #pragma unroll
    for (int r = 0; r < 8; ++r) s[r] += hs[gq*8 + r][c] * w;
  }
  #pragma unroll
  for (int r = 0; r < 8; ++r) U[(n0 + gq*8 + r)*128 + d] = s[r];
}

// ---------------- WVh = [h @ aw1[256:384] | h @ nw1[128:256]] as bf16 ---------
// Per-node dst contributions to both first-layer MLPs. 8 nodes/block, 256 thr,
// one output column per thread, 8 rows.
__global__ void wvh_kernel(const float* __restrict__ h,
                           const float* __restrict__ aw1, const float* __restrict__ nw1,
                           ushortT* __restrict__ WVh)
{
  __shared__ float hs[8][128];
  int tid = threadIdx.x;
  size_t n0 = (size_t)blockIdx.x * 8;
  {
    int r = tid >> 5, c = (tid & 31) * 4;
    *(float4*)&hs[r][c] = *(const float4*)(h + (n0 + r)*128 + c);
  }
  __syncthreads();
  int d = tid;   // 0..255; wave-uniform branch (64-lane waves align with halves)
  float s[8] = {0.f,0.f,0.f,0.f,0.f,0.f,0.f,0.f};
  for (int k = 0; k < 128; ++k) {
    float w = (d < 128) ? aw1[(256 + k)*128 + d] : nw1[(128 + k)*128 + (d - 128)];
    #pragma unroll
    for (int r = 0; r < 8; ++r) s[r] += hs[r][k] * w;
  }
  #pragma unroll
  for (int r = 0; r < 8; ++r) WVh[(n0 + r)*256 + d] = f2bf(s[r]);
}

// ---------------- fused edge pipeline (hoisted hj): 1 node, 512 threads -------
// GEMM1 K=128 (e only); hj contributions gathered as WVh[dst] and added in ep1.
// LDS: Xb [32][512B] swizzled bf16 (16K, V3f f32 overlay after G3);
//      WVhS [32][512B] swizzled bf16 (16K, rows 30/31 zero);
//      lgp[2][32]; Ubs[128]. Total 33536 B -> 4 blocks/CU (wave cap).
__global__ __launch_bounds__(512, 8) void edge_kernel(
    const float* __restrict__ e,
    const int* __restrict__ edge_idx,
    const ushortT* __restrict__ WVh,
    const ushortT* __restrict__ WF1, const ushortT* __restrict__ WF2,
    const ushortT* __restrict__ WF3,
    const float* __restrict__ bias1, const float* __restrict__ bias2,
    const float* __restrict__ bias3,
    const float* __restrict__ aw3, const float* __restrict__ ab3,
    float* __restrict__ hh)
{
  extern __shared__ char smem[];
  char*  Xb   = smem;                       // [32][512B] swizzled bf16 (16384 B)
  float* V3f  = (float*)smem;               // [30][132] f32 overlay (15840 B)
  char*  WVhS = smem + 16384;               // [32][512B] swizzled bf16 (16384 B)
  float* lgp  = (float*)(smem + 32768);     // [2][32] logits partials
  float* Ubs  = (float*)(smem + 33024);     // [128]

  const int tid  = threadIdx.x;
  const int lane = tid & 63;
  const int wid  = tid >> 6;
  const int node = blockIdx.x;
  const long e0 = (long)node * KNB;

  // U for this block's node (precomputed by ub_kernel into hh row)
  float uval = 0.f;
  if (tid < 128) uval = hh[(size_t)node*128 + tid];

  // ---- Phase 0a: stage e -> bf16 Xb cols 0..127; rows 30/31 zeroed ----
  {
    int r = tid >> 4, c8 = tid & 15;       // 32 rows x 16 groups = 512
    ushort8v u = {0,0,0,0,0,0,0,0};
    if (r < KNB) {
      const float* src = e + ((size_t)(e0 + r))*128 + c8*8;
      float4 v0 = *(const float4*)src;
      float4 v1 = *(const float4*)(src + 4);
      u[0]=f2bf(v0.x); u[1]=f2bf(v0.y); u[2]=f2bf(v0.z); u[3]=f2bf(v0.w);
      u[4]=f2bf(v1.x); u[5]=f2bf(v1.y); u[6]=f2bf(v1.z); u[7]=f2bf(v1.w);
    }
    *(ushort8v*)(Xb + r*512 + ((c8*16) ^ SWZ(r))) = u;
  }
  // ---- Phase 0b: stage WVh[dst] rows (raw bf16 copy); rows 30/31 zeroed ----
  #pragma unroll
  for (int it = 0; it < 2; ++it) {
    int idx = it*512 + tid;                // 32 rows x 32 groups = 1024
    int r = idx >> 5, c8 = idx & 31;
    ushort8v u = {0,0,0,0,0,0,0,0};
    if (r < KNB) {
      int dst = edge_idx[NE + e0 + r];
      u = *(const ushort8v*)(WVh + (size_t)dst*256 + c8*8);
    }
    *(ushort8v*)(WVhS + r*512 + ((c8*16) ^ SWZ(r))) = u;
  }
  if (tid < 128) Ubs[tid] = uval;
  __syncthreads();

  const int mrow = lane & 15, krow = lane >> 4;
  const int wr = wid >> 2;   // row strip (16 rows)
  const int wq = wid & 3;    // col quarter (64 cols)
  const int row = wr*16 + mrow;

  f32x4 acc[4];
  #pragma unroll
  for (int nt = 0; nt < 4; ++nt) acc[nt] = (f32x4){0.f,0.f,0.f,0.f};

  // ---- GEMM1: e[32x128] @ WF1(e-part) -> partial (W1|V1)[32x256] ----
  #pragma unroll
  for (int kt = 0; kt < 4; ++kt) {
    bf16x8 a = *(const bf16x8*)(Xb + row*512 + ((kt*64 + krow*16) ^ SWZ(row)));
    const ushortT* Bp = WF1 + ((size_t)((wq>>1)*8 + (wq&1)*4)*8 + kt)*512 + lane*8;
    #pragma unroll
    for (int nt = 0; nt < 4; ++nt) {
      bf16x8 b = *(const bf16x8*)(Bp + (size_t)nt*8*512);
      acc[nt] = __builtin_amdgcn_mfma_f32_16x16x32_bf16(a, b, acc[nt], 0, 0, 0);
    }
  }
  __syncthreads();
  // epilogue 1: + bias + WVh[dst] (+U on att half), relu/gelu, store bf16
  {
    #pragma unroll
    for (int rr = 0; rr < 4; ++rr) {
      int orow = wr*16 + krow*4 + rr;
      const char* wrow = WVhS + orow*512;
      #pragma unroll
      for (int nt = 0; nt < 4; ++nt) {
        int col = wq*64 + nt*16 + mrow;
        float wv = bf2f(*(const ushortT*)(wrow + ((2*col) ^ SWZ(orow))));
        float x = acc[nt][rr] + bias1[col] + wv;
        x = (wq < 2) ? fmaxf(x + Ubs[col], 0.f) : gelu_f(x);
        *(ushortT*)(Xb + orow*512 + ((2*col) ^ SWZ(orow))) = f2bf(x);
      }
    }
  }
  __syncthreads();

  // ---- GEMM2: W2 = relu(W1@aw2), V2 = gelu(V1@nw2) ----
  #pragma unroll
  for (int nt = 0; nt < 4; ++nt) acc[nt] = (f32x4){0.f,0.f,0.f,0.f};
  #pragma unroll
  for (int kt = 0; kt < 4; ++kt) {
    bf16x8 a = *(const bf16x8*)(Xb + row*512 + (((wq>>1)*256 + kt*64 + krow*16) ^ SWZ(row)));
    const ushortT* Bp = WF2 + ((size_t)((wq>>1)*8 + (wq&1)*4)*4 + kt)*512 + lane*8;
    #pragma unroll
    for (int nt = 0; nt < 4; ++nt) {
      bf16x8 b = *(const bf16x8*)(Bp + (size_t)nt*4*512);
      acc[nt] = __builtin_amdgcn_mfma_f32_16x16x32_bf16(a, b, acc[nt], 0, 0, 0);
    }
  }
  __syncthreads();
  // epilogue 2: V2 (gelu) -> Xb left half; W2 (relu) consumed in-reg by logits.
  {
    if (wq < 2) {
      float aw3c[4];
      #pragma unroll
      for (int nt = 0; nt < 4; ++nt) aw3c[nt] = aw3[wq*64 + nt*16 + mrow];
      #pragma unroll
      for (int rr = 0; rr < 4; ++rr) {
        int orow = wr*16 + krow*4 + rr;
        float lsum = 0.f;
        #pragma unroll
        for (int nt = 0; nt < 4; ++nt) {
          int col = wq*64 + nt*16 + mrow;
          float x = fmaxf(acc[nt][rr] + bias2[col], 0.f);
          lsum += x * aw3c[nt];
        }
        lsum += __shfl_xor(lsum, 1);
        lsum += __shfl_xor(lsum, 2);
        lsum += __shfl_xor(lsum, 4);
        lsum += __shfl_xor(lsum, 8);
        if (mrow == 0) lgp[wq*32 + orow] = lsum;
      }
    } else {
      #pragma unroll
      for (int rr = 0; rr < 4; ++rr) {
        int orow = wr*16 + krow*4 + rr;
        #pragma unroll
        for (int nt = 0; nt < 4; ++nt) {
          int col = wq*64 + nt*16 + mrow;
          float x = gelu_f(acc[nt][rr] + bias2[col]);
          *(ushortT*)(Xb + orow*512 + ((2*(col ^ 128)) ^ SWZ(orow))) = f2bf(x);
        }
      }
    }
  }
  __syncthreads();

  // ---- GEMM3: V3 = V2 @ nw3 (A = Xb left half), wave = 16r x 32c ----
  f32x4 acc3[2];
  #pragma unroll
  for (int nt = 0; nt < 2; ++nt) acc3[nt] = (f32x4){0.f,0.f,0.f,0.f};
  #pragma unroll
  for (int kt = 0; kt < 4; ++kt) {
    bf16x8 a = *(const bf16x8*)(Xb + row*512 + ((kt*64 + krow*16) ^ SWZ(row)));
    const ushortT* Bp = WF3 + ((size_t)(wq*2)*4*512 + (size_t)kt*512) + lane*8;
    #pragma unroll
    for (int nt = 0; nt < 2; ++nt) {
      bf16x8 b = *(const bf16x8*)(Bp + (size_t)nt*4*512);
      acc3[nt] = __builtin_amdgcn_mfma_f32_16x16x32_bf16(a, b, acc3[nt], 0, 0, 0);
    }
  }
  __syncthreads();   // all Xb reads complete before f32 overlay
  // V3 dump f32 over Xb region (rows < 30 only)
  {
    #pragma unroll
    for (int nt = 0; nt < 2; ++nt)
      #pragma unroll
      for (int rr = 0; rr < 4; ++rr) {
        int orow = wr*16 + krow*4 + rr;
        int col = wq*32 + nt*16 + mrow;
        if (orow < KNB) V3f[orow*132 + col] = acc3[nt][rr] + bias3[col];
      }
  }
  __syncthreads();

  // ---- softmax over 30 neighbors + PV (waves 0..3, 32 cols each) ----
  if (wid < 4) {
    int dh = wid * 32;
    int cl = lane & 31;
    float x = -INFINITY;
    if (lane < KNB)
      x = (lgp[lane] + lgp[32 + lane] + ab3[0]) * 0.08838834764831845f;
    float m = x;
    #pragma unroll
    for (int off = 32; off >= 1; off >>= 1) m = fmaxf(m, __shfl_xor(m, off));
    float p = (lane < KNB) ? __expf(x - m) : 0.f;
    float ssum = p;
    #pragma unroll
    for (int off = 32; off >= 1; off >>= 1) ssum += __shfl_xor(ssum, off);
    float attv = p / ssum;
    float s = 0.f;
    #pragma unroll
    for (int k2 = 0; k2 < KNB; ++k2) {
      float a = __shfl(attv, k2);
      s += a * V3f[(size_t)k2*132 + dh + cl];
    }
    if (lane < 32) hh[(size_t)node*128 + dh + cl] = s;
  }
}

// ---------------- fallback (round-4 kernel, no WVh workspace needed) ----------
__global__ __launch_bounds__(512, 8) void edge_kernel_old(
    const float* __restrict__ h, const float* __restrict__ e,
    const int* __restrict__ edge_idx,
    const ushortT* __restrict__ WF1, const ushortT* __restrict__ WF2,
    const ushortT* __restrict__ WF3,
    const float* __restrict__ bias1, const float* __restrict__ bias2,
    const float* __restrict__ bias3,
    const float* __restrict__ aw3, const float* __restrict__ ab3,
    float* __restrict__ hh)
{
  extern __shared__ char smem[];
  char*  Xb   = smem;
  float* V3f  = (float*)smem;
  float* lgp  = (float*)(smem + 16384);
  float* Ubs  = (float*)(smem + 16640);

  const int tid  = threadIdx.x;
  const int lane = tid & 63;
  const int wid  = tid >> 6;
  const int node = blockIdx.x;
  const long e0 = (long)node * KNB;

  float uval = 0.f;
  if (tid < 128) uval = hh[(size_t)node*128 + tid];

  #pragma unroll
  for (int it = 0; it < 2; ++it) {
    int idx = it*512 + tid;
    int r = idx >> 5, c8 = idx & 31;
    ushort8v u = {0,0,0,0,0,0,0,0};
    if (r < KNB) {
      long edge = e0 + r;
      const float* src;
      if (c8 < 16) src = e + (size_t)edge*128 + c8*8;
      else {
        int dst = edge_idx[NE + edge];
        src = h + (size_t)dst*128 + (c8 - 16)*8;
      }
      float4 v0 = *(const float4*)src;
      float4 v1 = *(const float4*)(src + 4);
      u[0]=f2bf(v0.x); u[1]=f2bf(v0.y); u[2]=f2bf(v0.z); u[3]=f2bf(v0.w);
      u[4]=f2bf(v1.x); u[5]=f2bf(v1.y); u[6]=f2bf(v1.z); u[7]=f2bf(v1.w);
    }
    *(ushort8v*)(Xb + r*512 + ((c8*16) ^ SWZ(r))) = u;
  }
  if (tid < 128) Ubs[tid] = uval;
  __syncthreads();

  const int mrow = lane & 15, krow = lane >> 4;
  const int wr = wid >> 2;
  const int wq = wid & 3;
  const int row = wr*16 + mrow;

  f32x4 acc[4];
  #pragma unroll
  for (int nt = 0; nt < 4; ++nt) acc[nt] = (f32x4){0.f,0.f,0.f,0.f};

  for (int kt = 0; kt < 8; ++kt) {
    bf16x8 a = *(const bf16x8*)(Xb + row*512 + ((kt*64 + krow*16) ^ SWZ(row)));
    const ushortT* Bp = WF1 + ((size_t)((wq>>1)*8 + (wq&1)*4)*8 + kt)*512 + lane*8;
    #pragma unroll
    for (int nt = 0; nt < 4; ++nt) {
      bf16x8 b = *(const bf16x8*)(Bp + (size_t)nt*8*512);
      acc[nt] = __builtin_amdgcn_mfma_f32_16x16x32_bf16(a, b, acc[nt], 0, 0, 0);
    }
  }
  __syncthreads();
  {
    #pragma unroll
    for (int rr = 0; rr < 4; ++rr) {
      int orow = wr*16 + krow*4 + rr;
      #pragma unroll
      for (int nt = 0; nt < 4; ++nt) {
        int col = wq*64 + nt*16 + mrow;
        float x = acc[nt][rr] + bias1[col];
        x = (wq < 2) ? fmaxf(x + Ubs[col], 0.f) : gelu_f(x);
        *(ushortT*)(Xb + orow*512 + ((2*col) ^ SWZ(orow))) = f2bf(x);
      }
    }
  }
  __syncthreads();

  #pragma unroll
  for (int nt = 0; nt < 4; ++nt) acc[nt] = (f32x4){0.f,0.f,0.f,0.f};
  for (int kt = 0; kt < 4; ++kt) {
    bf16x8 a = *(const bf16x8*)(Xb + row*512 + (((wq>>1)*256 + kt*64 + krow*16) ^ SWZ(row)));
    const ushortT* Bp = WF2 + ((size_t)((wq>>1)*8 + (wq&1)*4)*4 + kt)*512 + lane*8;
    #pragma unroll
    for (int nt = 0; nt < 4; ++nt) {
      bf16x8 b = *(const bf16x8*)(Bp + (size_t)nt*4*512);
      acc[nt] = __builtin_amdgcn_mfma_f32_16x16x32_bf16(a, b, acc[nt], 0, 0, 0);
    }
  }
  __syncthreads();
  {
    if (wq < 2) {
      float aw3c[4];
      #pragma unroll
      for (int nt = 0; nt < 4; ++nt) aw3c[nt] = aw3[wq*64 + nt*16 + mrow];
      #pragma unroll
      for (int rr = 0; rr < 4; ++rr) {
        int orow = wr*16 + krow*4 + rr;
        float lsum = 0.f;
        #pragma unroll
        for (int nt = 0; nt < 4; ++nt) {
          int col = wq*64 + nt*16 + mrow;
          float x = fmaxf(acc[nt][rr] + bias2[col], 0.f);
          lsum += x * aw3c[nt];
        }
        lsum += __shfl_xor(lsum, 1);
        lsum += __shfl_xor(lsum, 2);
        lsum += __shfl_xor(lsum, 4);
        lsum += __shfl_xor(lsum, 8);
        if (mrow == 0) lgp[wq*32 + orow] = lsum;
      }
    } else {
      #pragma unroll
      for (int rr = 0; rr < 4; ++rr) {
        int orow = wr*16 + krow*4 + rr;
        #pragma unroll
        for (int nt = 0; nt < 4; ++nt) {
          int col = wq*64 + nt*16 + mrow;
          float x = gelu_f(acc[nt][rr] + bias2[col]);
          *(ushortT*)(Xb + orow*512 + ((2*(col ^ 128)) ^ SWZ(orow))) = f2bf(x);
        }
      }
    }
  }
  __syncthreads();

  f32x4 acc3[2];
  #pragma unroll
  for (int nt = 0; nt < 2; ++nt) acc3[nt] = (f32x4){0.f,0.f,0.f,0.f};
  for (int kt = 0; kt < 4; ++kt) {
    bf16x8 a = *(const bf16x8*)(Xb + row*512 + ((kt*64 + krow*16) ^ SWZ(row)));
    const ushortT* Bp = WF3 + ((size_t)(wq*2)*4*512 + (size_t)kt*512) + lane*8;
    #pragma unroll
    for (int nt = 0; nt < 2; ++nt) {
      bf16x8 b = *(const bf16x8*)(Bp + (size_t)nt*4*512);
      acc3[nt] = __builtin_amdgcn_mfma_f32_16x16x32_bf16(a, b, acc3[nt], 0, 0, 0);
    }
  }
  __syncthreads();
  {
    #pragma unroll
    for (int nt = 0; nt < 2; ++nt)
      #pragma unroll
      for (int rr = 0; rr < 4; ++rr) {
        int orow = wr*16 + krow*4 + rr;
        int col = wq*32 + nt*16 + mrow;
        if (orow < KNB) V3f[orow*132 + col] = acc3[nt][rr] + bias3[col];
      }
  }
  __syncthreads();

  if (wid < 4) {
    int dh = wid * 32;
    int cl = lane & 31;
    float x = -INFINITY;
    if (lane < KNB)
      x = (lgp[lane] + lgp[32 + lane] + ab3[0]) * 0.08838834764831845f;
    float m = x;
    #pragma unroll
    for (int off = 32; off >= 1; off >>= 1) m = fmaxf(m, __shfl_xor(m, off));
    float p = (lane < KNB) ? __expf(x - m) : 0.f;
    float ssum = p;
    #pragma unroll
    for (int off = 32; off >= 1; off >>= 1) ssum += __shfl_xor(ssum, off);
    float attv = p / ssum;
    float s = 0.f;
    #pragma unroll
    for (int k2 = 0; k2 < KNB; ++k2) {
      float a = __shfl(attv, k2);
      s += a * V3f[(size_t)k2*132 + dh + cl];
    }
    if (lane < 32) hh[(size_t)node*128 + dh + cl] = s;
  }
}

// ---------------- deterministic column reduction over nodes (on hh0) ----------
__global__ void reduce1_kernel(const float* __restrict__ hh, float* __restrict__ p2) {
  int b = blockIdx.x, tid = threadIdx.x;
  int d = tid & 127, half = tid >> 7;
  float s = 0.f;
  const float* base = hh + (size_t)(b*64 + half*32)*128 + d;
  #pragma unroll 4
  for (int i = 0; i < 32; ++i) s += base[(size_t)i*128];
  __shared__ float ps[256];
  ps[tid] = s; __syncthreads();
  if (tid < 128) p2[b*128 + tid] = ps[tid] + ps[tid + 128];
}

// gate: c0 = mean(hh0); c = c0 @ thw; g = sigmoid(MLP(c))
__global__ void gate_kernel(const float* __restrict__ p2, const float* __restrict__ thw,
                            const float* __restrict__ gw1, const float* __restrict__ gb1,
                            const float* __restrict__ gw2, const float* __restrict__ gb2,
                            const float* __restrict__ gw3, const float* __restrict__ gb3,
                            float* __restrict__ gout) {
  int tid = threadIdx.x;
  int d = tid & 127, half = tid >> 7;
  float s = 0.f;
  for (int i = 0; i < 128; ++i) s += p2[(half*128 + i)*128 + d];
  __shared__ float ps[256];
  __shared__ float cv[128], cv2[128], y1[128], y2[128];
  ps[tid] = s; __syncthreads();
  if (tid < 128) cv[tid] = (ps[tid] + ps[tid+128]) * (1.f / (float)NN);
  __syncthreads();
  if (tid < 128) {
    float a = 0.f;
    for (int c = 0; c < 128; ++c) a += cv[c] * thw[c*128 + tid];
    cv2[tid] = a;
  }
  __syncthreads();
  if (tid < 128) {
    float a = gb1[tid];
    for (int c = 0; c < 128; ++c) a += cv2[c] * gw1[c*128 + tid];
    y1[tid] = fmaxf(a, 0.f);
  }
  __syncthreads();
  if (tid < 128) {
    float a = gb2[tid];
    for (int c = 0; c < 128; ++c) a += y1[c] * gw2[c*128 + tid];
    y2[tid] = fmaxf(a, 0.f);
  }
  __syncthreads();
  if (tid < 128) {
    float a = gb3[tid];
    for (int c = 0; c < 128; ++c) a += y2[c] * gw3[c*128 + tid];
    gout[tid] = 1.f / (1.f + __expf(-a));
  }
}

// ---------------- fused to_h + gate scale: out = (hh0 @ thw) * g, in place ----
__global__ void toh_scale_kernel(float* __restrict__ hh, const float* __restrict__ thw,
                                 const float* __restrict__ gv)
{
  __shared__ float hs[16][128];
  int tid = threadIdx.x;
  size_t n0 = (size_t)blockIdx.x * 16;
  {
    int r = tid >> 4, c = (tid & 15) * 8;
    const float* src = hh + (n0 + r)*128 + c;
    *(float4*)&hs[r][c]     = *(const float4*)src;
    *(float4*)&hs[r][c + 4] = *(const float4*)(src + 4);
  }
  __syncthreads();
  int d = tid & 127, gq = tid >> 7;
  float s[8] = {0.f,0.f,0.f,0.f,0.f,0.f,0.f,0.f};
  for (int c = 0; c < 128; ++c) {
    float w = thw[c*128 + d];
    #pragma unroll
    for (int r = 0; r < 8; ++r) s[r] += hs[gq*8 + r][c] * w;
  }
  float gd = gv[d];
  #pragma unroll
  for (int r = 0; r < 8; ++r) hh[(n0 + gq*8 + r)*128 + d] = s[r] * gd;
}

extern "C" void kernel_launch(void* const* d_in, const int* in_sizes, int n_in,
                              void* d_out, int out_size, void* d_ws, size_t ws_size,
                              hipStream_t stream) {
  const float* h   = (const float*)d_in[0];
  const float* e   = (const float*)d_in[1];
  const float* aw1 = (const float*)d_in[2];
  const float* ab1 = (const float*)d_in[3];
  const float* aw2 = (const float*)d_in[4];
  const float* ab2 = (const float*)d_in[5];
  const float* aw3 = (const float*)d_in[6];
  const float* ab3 = (const float*)d_in[7];
  const float* nw1 = (const float*)d_in[8];
  const float* nb1 = (const float*)d_in[9];
  const float* nw2 = (const float*)d_in[10];
  const float* nb2 = (const float*)d_in[11];
  const float* nw3 = (const float*)d_in[12];
  const float* nb3 = (const float*)d_in[13];
  const float* thw = (const float*)d_in[14];
  const float* gw1 = (const float*)d_in[15];
  const float* gb1 = (const float*)d_in[16];
  const float* gw2 = (const float*)d_in[17];
  const float* gb2 = (const float*)d_in[18];
  const float* gw3 = (const float*)d_in[19];
  const float* gb3 = (const float*)d_in[20];
  const int* edge_idx = (const int*)d_in[21];

  char* ws = (char*)d_ws;
  ushortT* WF1 = (ushortT*)(ws + 0);        // 131072 B
  ushortT* WF2 = (ushortT*)(ws + 131072);   // 65536 B
  ushortT* WF3 = (ushortT*)(ws + 196608);   // 32768 B
  float* bias1 = (float*)(ws + 229376);     // 1024 B
  float* bias2 = (float*)(ws + 230400);     // 1024 B
  float* bias3 = (float*)(ws + 231424);     // 512 B
  float* p2    = (float*)(ws + 231936);     // 131072 B
  float* gout  = (float*)(ws + 363008);     // 512 B
  ushortT* WVh = (ushortT*)(ws + 363520);   // 8388608 B (guarded by ws_size)
  float* hh    = (float*)d_out;

  const size_t WVH_NEED = 363520ull + (size_t)NN*256*2;
  const bool hoist = (ws_size >= WVH_NEED);

  pack_kernel<<<59, 256, 0, stream>>>(aw1, nw1, aw2, nw2, nw3,
                                      ab1, nb1, ab2, nb2, nb3,
                                      WF1, WF2, WF3, bias1, bias2, bias3);

  // U = h @ aw1[0:128,:] into the output buffer (consumed in-place by edge_kernel)
  ub_kernel<<<NN/16, 256, 0, stream>>>(h, aw1, hh);

  if (hoist) {
    wvh_kernel<<<NN/8, 256, 0, stream>>>(h, aw1, nw1, WVh);
    const int SMEM = 33536;
    hipFuncSetAttribute((const void*)edge_kernel,
                        hipFuncAttributeMaxDynamicSharedMemorySize, SMEM);
    edge_kernel<<<NN, 512, SMEM, stream>>>(e, edge_idx, WVh, WF1, WF2, WF3,
                                           bias1, bias2, bias3, aw3, ab3, hh);
  } else {
    const int SMEM = 17152;
    hipFuncSetAttribute((const void*)edge_kernel_old,
                        hipFuncAttributeMaxDynamicSharedMemorySize, SMEM);
    edge_kernel_old<<<NN, 512, SMEM, stream>>>(h, e, edge_idx, WF1, WF2, WF3,
                                               bias1, bias2, bias3, aw3, ab3, hh);
  }

  reduce1_kernel<<<256, 256, 0, stream>>>(hh, p2);
  gate_kernel<<<1, 256, 0, stream>>>(p2, thw, gw1, gb1, gw2, gb2, gw3, gb3, gout);
  toh_scale_kernel<<<NN/16, 256, 0, stream>>>(hh, thw, gout);
}

// Round 6
// 374.587 us; speedup vs baseline: 1.5938x; 1.1468x over previous
//
#include <hip/hip_runtime.h>
#include <math.h>

#define NN 16384
#define KNB 30
#define NE (NN*KNB)   // 491520

typedef __attribute__((ext_vector_type(8))) __bf16 bf16x8;
typedef __attribute__((ext_vector_type(4))) float f32x4;
typedef unsigned short ushortT;
typedef __attribute__((ext_vector_type(8))) unsigned short ushort8v;

#define SWZ(r) (((r)&7)<<4)

__device__ __forceinline__ ushortT f2bf(float x){
  __bf16 b = (__bf16)x;
  union { __bf16 b; ushortT u; } v; v.b = b; return v.u;
}
__device__ __forceinline__ float bf2f(ushortT u){
  union { unsigned int u32; float f; } v; v.u32 = ((unsigned int)u) << 16;
  return v.f;
}
// A&S 7.1.26 erf (|err| <= 1.5e-7), exact-GELU compatible at bf16 tolerance
__device__ __forceinline__ float gelu_f(float x){
  float ax = fabsf(x) * 0.7071067811865476f;
  float t = 1.0f / (1.0f + 0.3275911f * ax);
  float poly = t*(0.254829592f + t*(-0.284496736f + t*(1.421413741f +
               t*(-1.453152027f + t*1.061405429f))));
  float er = 1.0f - poly * __expf(-ax*ax);
  er = copysignf(er, x);
  return 0.5f * x * (1.0f + er);
}

// ---------------- prep: weights -> bf16 in MFMA-fragment order ----------------
// (unchanged from round 5; WF3/bias3 now unused but kept to preserve offsets)
__global__ void pack_kernel(const float* __restrict__ aw1, const float* __restrict__ nw1,
                            const float* __restrict__ aw2, const float* __restrict__ nw2,
                            const float* __restrict__ nw3,
                            const float* __restrict__ ab1, const float* __restrict__ nb1,
                            const float* __restrict__ ab2, const float* __restrict__ nb2,
                            const float* __restrict__ nb3,
                            ushortT* __restrict__ WF1, ushortT* __restrict__ WF2,
                            ushortT* __restrict__ WF3,
                            float* __restrict__ bias1, float* __restrict__ bias2,
                            float* __restrict__ bias3)
{
  int u = blockIdx.x * blockDim.x + threadIdx.x;
  if (u < 8192) {
    int lane = u & 63, tile = u >> 6;
    int half = tile >> 6, nt = (tile >> 3) & 7, kt = tile & 7;
    int mrow = lane & 15, krow = lane >> 4;
    int n = half*128 + nt*16 + mrow, k0 = kt*32 + krow*8;
    ushort8v o;
    #pragma unroll
    for (int j = 0; j < 8; ++j) {
      int k = k0 + j;
      float v = (half == 0) ? aw1[(128 + k)*128 + n] : nw1[k*128 + (n - 128)];
      o[j] = f2bf(v);
    }
    *(ushort8v*)(WF1 + (size_t)u*8) = o;
    return;
  }
  u -= 8192;
  if (u < 4096) {
    int lane = u & 63, tile = u >> 6;
    int half = tile >> 5, nt = (tile >> 2) & 7, kt = tile & 3;
    int mrow = lane & 15, krow = lane >> 4;
    int n = half*128 + nt*16 + mrow, k0 = kt*32 + krow*8;
    ushort8v o;
    #pragma unroll
    for (int j = 0; j < 8; ++j) {
      int k = k0 + j;
      float v = (half == 0) ? aw2[k*128 + n] : nw2[k*128 + (n - 128)];
      o[j] = f2bf(v);
    }
    *(ushort8v*)(WF2 + (size_t)u*8) = o;
    return;
  }
  u -= 4096;
  if (u < 2048) {
    int lane = u & 63, tile = u >> 6;
    int nt = tile >> 2, kt = tile & 3;
    int mrow = lane & 15, krow = lane >> 4;
    int n = nt*16 + mrow, k0 = kt*32 + krow*8;
    ushort8v o;
    #pragma unroll
    for (int j = 0; j < 8; ++j) o[j] = f2bf(nw3[(k0 + j)*128 + n]);
    *(ushort8v*)(WF3 + (size_t)u*8) = o;
    return;
  }
  u -= 2048;
  if (u < 256) { bias1[u] = (u < 128) ? ab1[u] : nb1[u - 128]; return; }
  u -= 256;
  if (u < 256) { bias2[u] = (u < 128) ? ab2[u] : nb2[u - 128]; return; }
  u -= 128 + 128;
  if (u >= 0 && u < 128) { bias3[u] = nb3[u]; return; }
}

// ---------------- M = nw3 @ thw (f32), c3 = nb3 @ thw --------------------------
// block b<128: M row b; block 128: c3. 128 threads each.
__global__ void m_kernel(const float* __restrict__ nw3, const float* __restrict__ nb3,
                         const float* __restrict__ thw,
                         float* __restrict__ M, float* __restrict__ c3)
{
  __shared__ float rowv[128];
  int d = threadIdx.x;
  int b = blockIdx.x;
  rowv[d] = (b < 128) ? nw3[b*128 + d] : nb3[d];
  __syncthreads();
  float s = 0.f;
  for (int n = 0; n < 128; ++n) s += rowv[n] * thw[n*128 + d];
  if (b < 128) M[b*128 + d] = s;
  else c3[d] = s;
}

// ---------------- fused per-node precompute: U (f32) + WVh (bf16) -------------
// U   = h @ aw1[0:128,:]              (att source contribution, f32 -> hh buf)
// WVh = [h @ aw1[256:384] | h @ nw1[128:256]]  (dst contributions, bf16)
// 8 nodes/block, 384 threads (seg = tid>>7 wave-uniform).
__global__ void uwvh_kernel(const float* __restrict__ h,
                            const float* __restrict__ aw1, const float* __restrict__ nw1,
                            float* __restrict__ U, ushortT* __restrict__ WVh)
{
  __shared__ float hs[8][128];
  int tid = threadIdx.x;
  size_t n0 = (size_t)blockIdx.x * 8;
  if (tid < 256) {
    int r = tid >> 5, c = (tid & 31) * 4;
    *(float4*)&hs[r][c] = *(const float4*)(h + (n0 + r)*128 + c);
  }
  __syncthreads();
  int d = tid & 127, seg = tid >> 7;   // 0: U, 1: WVh[0:128], 2: WVh[128:256]
  const float* wbase = (seg == 0) ? (aw1 + d)
                     : (seg == 1) ? (aw1 + 256*128 + d)
                                  : (nw1 + 128*128 + d);
  float s[8] = {0.f,0.f,0.f,0.f,0.f,0.f,0.f,0.f};
  for (int c = 0; c < 128; ++c) {
    float w = wbase[(size_t)c*128];
    #pragma unroll
    for (int r = 0; r < 8; ++r) s[r] += hs[r][c] * w;
  }
  if (seg == 0) {
    #pragma unroll
    for (int r = 0; r < 8; ++r) U[(n0 + r)*128 + d] = s[r];
  } else {
    int off = (seg - 1) * 128;
    #pragma unroll
    for (int r = 0; r < 8; ++r) WVh[(n0 + r)*256 + off + d] = f2bf(s[r]);
  }
}

// ---------------- fused edge pipeline: 1 node, 512 threads, NO GEMM3 ----------
// q = att @ V2 written to hh; V3/to_h folded into M downstream.
// LDS: Xb [32][512B] swizzled bf16 (16K); WVhS [32][512B] (16K);
//      lgp[2][32]; Ubs[128]. Total 33536 B -> 4 blocks/CU (wave cap).
__global__ __launch_bounds__(512, 8) void edge_kernel(
    const float* __restrict__ e,
    const int* __restrict__ edge_idx,
    const ushortT* __restrict__ WVh,
    const ushortT* __restrict__ WF1, const ushortT* __restrict__ WF2,
    const float* __restrict__ bias1, const float* __restrict__ bias2,
    const float* __restrict__ aw3, const float* __restrict__ ab3,
    float* __restrict__ hh)
{
  extern __shared__ char smem[];
  char*  Xb   = smem;                       // [32][512B] swizzled bf16 (16384 B)
  char*  WVhS = smem + 16384;               // [32][512B] swizzled bf16 (16384 B)
  float* lgp  = (float*)(smem + 32768);     // [2][32] logits partials
  float* Ubs  = (float*)(smem + 33024);     // [128]

  const int tid  = threadIdx.x;
  const int lane = tid & 63;
  const int wid  = tid >> 6;
  const int node = blockIdx.x;
  const long e0 = (long)node * KNB;

  // U for this block's node (precomputed by uwvh_kernel into hh row)
  float uval = 0.f;
  if (tid < 128) uval = hh[(size_t)node*128 + tid];

  // ---- Phase 0a: stage e -> bf16 Xb cols 0..127; rows 30/31 zeroed ----
  {
    int r = tid >> 4, c8 = tid & 15;       // 32 rows x 16 groups = 512
    ushort8v u = {0,0,0,0,0,0,0,0};
    if (r < KNB) {
      const float* src = e + ((size_t)(e0 + r))*128 + c8*8;
      float4 v0 = *(const float4*)src;
      float4 v1 = *(const float4*)(src + 4);
      u[0]=f2bf(v0.x); u[1]=f2bf(v0.y); u[2]=f2bf(v0.z); u[3]=f2bf(v0.w);
      u[4]=f2bf(v1.x); u[5]=f2bf(v1.y); u[6]=f2bf(v1.z); u[7]=f2bf(v1.w);
    }
    *(ushort8v*)(Xb + r*512 + ((c8*16) ^ SWZ(r))) = u;
  }
  // ---- Phase 0b: stage WVh[dst] rows (raw bf16 copy); rows 30/31 zeroed ----
  #pragma unroll
  for (int it = 0; it < 2; ++it) {
    int idx = it*512 + tid;                // 32 rows x 32 groups = 1024
    int r = idx >> 5, c8 = idx & 31;
    ushort8v u = {0,0,0,0,0,0,0,0};
    if (r < KNB) {
      int dst = edge_idx[NE + e0 + r];
      u = *(const ushort8v*)(WVh + (size_t)dst*256 + c8*8);
    }
    *(ushort8v*)(WVhS + r*512 + ((c8*16) ^ SWZ(r))) = u;
  }
  if (tid < 128) Ubs[tid] = uval;
  __syncthreads();

  const int mrow = lane & 15, krow = lane >> 4;
  const int wr = wid >> 2;   // row strip (16 rows)
  const int wq = wid & 3;    // col quarter (64 cols)
  const int row = wr*16 + mrow;

  f32x4 acc[4];
  #pragma unroll
  for (int nt = 0; nt < 4; ++nt) acc[nt] = (f32x4){0.f,0.f,0.f,0.f};

  // ---- GEMM1: e[32x128] @ WF1(e-part) -> partial (W1|V1)[32x256] ----
  #pragma unroll
  for (int kt = 0; kt < 4; ++kt) {
    bf16x8 a = *(const bf16x8*)(Xb + row*512 + ((kt*64 + krow*16) ^ SWZ(row)));
    const ushortT* Bp = WF1 + ((size_t)((wq>>1)*8 + (wq&1)*4)*8 + kt)*512 + lane*8;
    #pragma unroll
    for (int nt = 0; nt < 4; ++nt) {
      bf16x8 b = *(const bf16x8*)(Bp + (size_t)nt*8*512);
      acc[nt] = __builtin_amdgcn_mfma_f32_16x16x32_bf16(a, b, acc[nt], 0, 0, 0);
    }
  }
  __syncthreads();
  // epilogue 1: + bias + WVh[dst] (+U on att half), relu/gelu, store bf16
  {
    #pragma unroll
    for (int rr = 0; rr < 4; ++rr) {
      int orow = wr*16 + krow*4 + rr;
      const char* wrow = WVhS + orow*512;
      #pragma unroll
      for (int nt = 0; nt < 4; ++nt) {
        int col = wq*64 + nt*16 + mrow;
        float wv = bf2f(*(const ushortT*)(wrow + ((2*col) ^ SWZ(orow))));
        float x = acc[nt][rr] + bias1[col] + wv;
        x = (wq < 2) ? fmaxf(x + Ubs[col], 0.f) : gelu_f(x);
        *(ushortT*)(Xb + orow*512 + ((2*col) ^ SWZ(orow))) = f2bf(x);
      }
    }
  }
  __syncthreads();

  // ---- GEMM2: W2 = relu(W1@aw2), V2 = gelu(V1@nw2) ----
  #pragma unroll
  for (int nt = 0; nt < 4; ++nt) acc[nt] = (f32x4){0.f,0.f,0.f,0.f};
  #pragma unroll
  for (int kt = 0; kt < 4; ++kt) {
    bf16x8 a = *(const bf16x8*)(Xb + row*512 + (((wq>>1)*256 + kt*64 + krow*16) ^ SWZ(row)));
    const ushortT* Bp = WF2 + ((size_t)((wq>>1)*8 + (wq&1)*4)*4 + kt)*512 + lane*8;
    #pragma unroll
    for (int nt = 0; nt < 4; ++nt) {
      bf16x8 b = *(const bf16x8*)(Bp + (size_t)nt*4*512);
      acc[nt] = __builtin_amdgcn_mfma_f32_16x16x32_bf16(a, b, acc[nt], 0, 0, 0);
    }
  }
  __syncthreads();
  // epilogue 2: V2 (gelu) -> Xb bytes (2*c)^swz, c in [0,128); W2 (relu)
  // consumed in-register by the fused logits dot (its only use).
  {
    if (wq < 2) {
      float aw3c[4];
      #pragma unroll
      for (int nt = 0; nt < 4; ++nt) aw3c[nt] = aw3[wq*64 + nt*16 + mrow];
      #pragma unroll
      for (int rr = 0; rr < 4; ++rr) {
        int orow = wr*16 + krow*4 + rr;
        float lsum = 0.f;
        #pragma unroll
        for (int nt = 0; nt < 4; ++nt) {
          int col = wq*64 + nt*16 + mrow;
          float x = fmaxf(acc[nt][rr] + bias2[col], 0.f);
          lsum += x * aw3c[nt];
        }
        lsum += __shfl_xor(lsum, 1);
        lsum += __shfl_xor(lsum, 2);
        lsum += __shfl_xor(lsum, 4);
        lsum += __shfl_xor(lsum, 8);
        if (mrow == 0) lgp[wq*32 + orow] = lsum;
      }
    } else {
      #pragma unroll
      for (int rr = 0; rr < 4; ++rr) {
        int orow = wr*16 + krow*4 + rr;
        #pragma unroll
        for (int nt = 0; nt < 4; ++nt) {
          int col = wq*64 + nt*16 + mrow;
          float x = gelu_f(acc[nt][rr] + bias2[col]);
          *(ushortT*)(Xb + orow*512 + ((2*(col ^ 128)) ^ SWZ(orow))) = f2bf(x);
        }
      }
    }
  }
  __syncthreads();

  // ---- softmax over 30 neighbors + q = att@V2 (8 waves x 16 cols) ----
  {
    int cl = lane & 15, ks = lane >> 4;
    float x = -INFINITY;
    if (lane < KNB)
      x = (lgp[lane] + lgp[32 + lane] + ab3[0]) * 0.08838834764831845f;
    float m = x;
    #pragma unroll
    for (int off = 32; off >= 1; off >>= 1) m = fmaxf(m, __shfl_xor(m, off));
    float p = (lane < KNB) ? __expf(x - m) : 0.f;
    float ssum = p;
    #pragma unroll
    for (int off = 32; off >= 1; off >>= 1) ssum += __shfl_xor(ssum, off);
    float attv = p / ssum;
    float s = 0.f;
    int col = wid*16 + cl;
    #pragma unroll
    for (int j = 0; j < 8; ++j) {
      int k2 = ks + 4*j;
      float a = __shfl(attv, k2 & 31);
      float v = 0.f;
      if (k2 < KNB)
        v = bf2f(*(const ushortT*)(Xb + k2*512 + ((2*col) ^ SWZ(k2))));
      s += a * v;
    }
    s += __shfl_xor(s, 16);
    s += __shfl_xor(s, 32);
    if (lane < 16) hh[(size_t)node*128 + col] = s;
  }
}

// ---------------- deterministic column reduction over nodes (on q) ------------
__global__ void reduce1_kernel(const float* __restrict__ hh, float* __restrict__ p2) {
  int b = blockIdx.x, tid = threadIdx.x;
  int d = tid & 127, half = tid >> 7;
  float s = 0.f;
  const float* base = hh + (size_t)(b*64 + half*32)*128 + d;
  #pragma unroll 4
  for (int i = 0; i < 32; ++i) s += base[(size_t)i*128];
  __shared__ float ps[256];
  ps[tid] = s; __syncthreads();
  if (tid < 128) p2[b*128 + tid] = ps[tid] + ps[tid + 128];
}

// gate: c = (mean q)@M + c3; g = sigmoid(MLP(c))
__global__ void gate_kernel(const float* __restrict__ p2,
                            const float* __restrict__ M, const float* __restrict__ c3,
                            const float* __restrict__ gw1, const float* __restrict__ gb1,
                            const float* __restrict__ gw2, const float* __restrict__ gb2,
                            const float* __restrict__ gw3, const float* __restrict__ gb3,
                            float* __restrict__ gout) {
  int tid = threadIdx.x;
  int d = tid & 127, half = tid >> 7;
  float s = 0.f;
  for (int i = 0; i < 128; ++i) s += p2[(half*128 + i)*128 + d];
  __shared__ float ps[256];
  __shared__ float cv[128], cv2[128], y1[128], y2[128];
  ps[tid] = s; __syncthreads();
  if (tid < 128) cv[tid] = (ps[tid] + ps[tid+128]) * (1.f / (float)NN);
  __syncthreads();
  if (tid < 128) {
    float a = c3[tid];
    for (int c = 0; c < 128; ++c) a += cv[c] * M[c*128 + tid];
    cv2[tid] = a;
  }
  __syncthreads();
  if (tid < 128) {
    float a = gb1[tid];
    for (int c = 0; c < 128; ++c) a += cv2[c] * gw1[c*128 + tid];
    y1[tid] = fmaxf(a, 0.f);
  }
  __syncthreads();
  if (tid < 128) {
    float a = gb2[tid];
    for (int c = 0; c < 128; ++c) a += y1[c] * gw2[c*128 + tid];
    y2[tid] = fmaxf(a, 0.f);
  }
  __syncthreads();
  if (tid < 128) {
    float a = gb3[tid];
    for (int c = 0; c < 128; ++c) a += y2[c] * gw3[c*128 + tid];
    gout[tid] = 1.f / (1.f + __expf(-a));
  }
}

// ---------------- fused (V3 + to_h + gate): out = (q@M + c3)*g, in place ------
__global__ void toh_scale_kernel(float* __restrict__ hh, const float* __restrict__ M,
                                 const float* __restrict__ c3,
                                 const float* __restrict__ gv)
{
  __shared__ float hs[16][128];
  int tid = threadIdx.x;
  size_t n0 = (size_t)blockIdx.x * 16;
  {
    int r = tid >> 4, c = (tid & 15) * 8;
    const float* src = hh + (n0 + r)*128 + c;
    *(float4*)&hs[r][c]     = *(const float4*)src;
    *(float4*)&hs[r][c + 4] = *(const float4*)(src + 4);
  }
  __syncthreads();
  int d = tid & 127, gq = tid >> 7;
  float s[8] = {0.f,0.f,0.f,0.f,0.f,0.f,0.f,0.f};
  for (int c = 0; c < 128; ++c) {
    float w = M[c*128 + d];
    #pragma unroll
    for (int r = 0; r < 8; ++r) s[r] += hs[gq*8 + r][c] * w;
  }
  float gd = gv[d];
  float cd = c3[d];
  #pragma unroll
  for (int r = 0; r < 8; ++r) hh[(n0 + gq*8 + r)*128 + d] = (s[r] + cd) * gd;
}

extern "C" void kernel_launch(void* const* d_in, const int* in_sizes, int n_in,
                              void* d_out, int out_size, void* d_ws, size_t ws_size,
                              hipStream_t stream) {
  const float* h   = (const float*)d_in[0];
  const float* e   = (const float*)d_in[1];
  const float* aw1 = (const float*)d_in[2];
  const float* ab1 = (const float*)d_in[3];
  const float* aw2 = (const float*)d_in[4];
  const float* ab2 = (const float*)d_in[5];
  const float* aw3 = (const float*)d_in[6];
  const float* ab3 = (const float*)d_in[7];
  const float* nw1 = (const float*)d_in[8];
  const float* nb1 = (const float*)d_in[9];
  const float* nw2 = (const float*)d_in[10];
  const float* nb2 = (const float*)d_in[11];
  const float* nw3 = (const float*)d_in[12];
  const float* nb3 = (const float*)d_in[13];
  const float* thw = (const float*)d_in[14];
  const float* gw1 = (const float*)d_in[15];
  const float* gb1 = (const float*)d_in[16];
  const float* gw2 = (const float*)d_in[17];
  const float* gb2 = (const float*)d_in[18];
  const float* gw3 = (const float*)d_in[19];
  const float* gb3 = (const float*)d_in[20];
  const int* edge_idx = (const int*)d_in[21];

  char* ws = (char*)d_ws;
  ushortT* WF1 = (ushortT*)(ws + 0);        // 131072 B
  ushortT* WF2 = (ushortT*)(ws + 131072);   // 65536 B
  ushortT* WF3 = (ushortT*)(ws + 196608);   // 32768 B (packed, unused)
  float* bias1 = (float*)(ws + 229376);     // 1024 B
  float* bias2 = (float*)(ws + 230400);     // 1024 B
  float* bias3 = (float*)(ws + 231424);     // 512 B (packed, unused)
  float* p2    = (float*)(ws + 231936);     // 131072 B
  float* gout  = (float*)(ws + 363008);     // 512 B
  float* Mw    = (float*)(ws + 363520);     // 65536 B
  float* c3w   = (float*)(ws + 429056);     // 512 B
  ushortT* WVh = (ushortT*)(ws + 429568);   // 8388608 B
  float* hh    = (float*)d_out;

  pack_kernel<<<59, 256, 0, stream>>>(aw1, nw1, aw2, nw2, nw3,
                                      ab1, nb1, ab2, nb2, nb3,
                                      WF1, WF2, WF3, bias1, bias2, bias3);

  m_kernel<<<129, 128, 0, stream>>>(nw3, nb3, thw, Mw, c3w);

  // U = h@aw1[0:128] (into hh, consumed in-place) + WVh bf16
  uwvh_kernel<<<NN/8, 384, 0, stream>>>(h, aw1, nw1, hh, WVh);

  const int SMEM = 33536;
  hipFuncSetAttribute((const void*)edge_kernel,
                      hipFuncAttributeMaxDynamicSharedMemorySize, SMEM);
  edge_kernel<<<NN, 512, SMEM, stream>>>(e, edge_idx, WVh, WF1, WF2,
                                         bias1, bias2, aw3, ab3, hh);

  reduce1_kernel<<<256, 256, 0, stream>>>(hh, p2);
  gate_kernel<<<1, 256, 0, stream>>>(p2, Mw, c3w, gw1, gb1, gw2, gb2, gw3, gb3, gout);
  toh_scale_kernel<<<NN/16, 256, 0, stream>>>(hh, Mw, c3w, gout);
}

// Round 7
// 355.211 us; speedup vs baseline: 1.6807x; 1.0545x over previous
//
#include <hip/hip_runtime.h>
#include <math.h>

#define NN 16384
#define KNB 30
#define NE (NN*KNB)   // 491520

typedef __attribute__((ext_vector_type(8))) __bf16 bf16x8;
typedef __attribute__((ext_vector_type(4))) float f32x4;
typedef unsigned short ushortT;
typedef __attribute__((ext_vector_type(8))) unsigned short ushort8v;

#define SWZ(r) (((r)&7)<<4)

__device__ __forceinline__ ushortT f2bf(float x){
  __bf16 b = (__bf16)x;
  union { __bf16 b; ushortT u; } v; v.b = b; return v.u;
}
__device__ __forceinline__ float bf2f(ushortT u){
  union { unsigned int u32; float f; } v; v.u32 = ((unsigned int)u) << 16;
  return v.f;
}
// A&S 7.1.26 erf (|err| <= 1.5e-7), exact-GELU compatible at bf16 tolerance
__device__ __forceinline__ float gelu_f(float x){
  float ax = fabsf(x) * 0.7071067811865476f;
  float t = 1.0f / (1.0f + 0.3275911f * ax);
  float poly = t*(0.254829592f + t*(-0.284496736f + t*(1.421413741f +
               t*(-1.453152027f + t*1.061405429f))));
  float er = 1.0f - poly * __expf(-ax*ax);
  er = copysignf(er, x);
  return 0.5f * x * (1.0f + er);
}

// ---------------- prep: weights -> bf16 in MFMA-fragment order ----------------
// (unchanged; WF3/bias3 packed but unused, kept to preserve offsets)
__global__ void pack_kernel(const float* __restrict__ aw1, const float* __restrict__ nw1,
                            const float* __restrict__ aw2, const float* __restrict__ nw2,
                            const float* __restrict__ nw3,
                            const float* __restrict__ ab1, const float* __restrict__ nb1,
                            const float* __restrict__ ab2, const float* __restrict__ nb2,
                            const float* __restrict__ nb3,
                            ushortT* __restrict__ WF1, ushortT* __restrict__ WF2,
                            ushortT* __restrict__ WF3,
                            float* __restrict__ bias1, float* __restrict__ bias2,
                            float* __restrict__ bias3)
{
  int u = blockIdx.x * blockDim.x + threadIdx.x;
  if (u < 8192) {
    int lane = u & 63, tile = u >> 6;
    int half = tile >> 6, nt = (tile >> 3) & 7, kt = tile & 7;
    int mrow = lane & 15, krow = lane >> 4;
    int n = half*128 + nt*16 + mrow, k0 = kt*32 + krow*8;
    ushort8v o;
    #pragma unroll
    for (int j = 0; j < 8; ++j) {
      int k = k0 + j;
      float v = (half == 0) ? aw1[(128 + k)*128 + n] : nw1[k*128 + (n - 128)];
      o[j] = f2bf(v);
    }
    *(ushort8v*)(WF1 + (size_t)u*8) = o;
    return;
  }
  u -= 8192;
  if (u < 4096) {
    int lane = u & 63, tile = u >> 6;
    int half = tile >> 5, nt = (tile >> 2) & 7, kt = tile & 3;
    int mrow = lane & 15, krow = lane >> 4;
    int n = half*128 + nt*16 + mrow, k0 = kt*32 + krow*8;
    ushort8v o;
    #pragma unroll
    for (int j = 0; j < 8; ++j) {
      int k = k0 + j;
      float v = (half == 0) ? aw2[k*128 + n] : nw2[k*128 + (n - 128)];
      o[j] = f2bf(v);
    }
    *(ushort8v*)(WF2 + (size_t)u*8) = o;
    return;
  }
  u -= 4096;
  if (u < 2048) {
    int lane = u & 63, tile = u >> 6;
    int nt = tile >> 2, kt = tile & 3;
    int mrow = lane & 15, krow = lane >> 4;
    int n = nt*16 + mrow, k0 = kt*32 + krow*8;
    ushort8v o;
    #pragma unroll
    for (int j = 0; j < 8; ++j) o[j] = f2bf(nw3[(k0 + j)*128 + n]);
    *(ushort8v*)(WF3 + (size_t)u*8) = o;
    return;
  }
  u -= 2048;
  if (u < 256) { bias1[u] = (u < 128) ? ab1[u] : nb1[u - 128]; return; }
  u -= 256;
  if (u < 256) { bias2[u] = (u < 128) ? ab2[u] : nb2[u - 128]; return; }
  u -= 128 + 128;
  if (u >= 0 && u < 128) { bias3[u] = nb3[u]; return; }
}

// ---------------- M = nw3 @ thw (f32), c3 = nb3 @ thw --------------------------
__global__ void m_kernel(const float* __restrict__ nw3, const float* __restrict__ nb3,
                         const float* __restrict__ thw,
                         float* __restrict__ M, float* __restrict__ c3)
{
  __shared__ float rowv[128];
  int d = threadIdx.x;
  int b = blockIdx.x;
  rowv[d] = (b < 128) ? nw3[b*128 + d] : nb3[d];
  __syncthreads();
  float s = 0.f;
  for (int n = 0; n < 128; ++n) s += rowv[n] * thw[n*128 + d];
  if (b < 128) M[b*128 + d] = s;
  else c3[d] = s;
}

// ---------------- fused per-node precompute: U (f32) + WVh (bf16) -------------
__global__ void uwvh_kernel(const float* __restrict__ h,
                            const float* __restrict__ aw1, const float* __restrict__ nw1,
                            float* __restrict__ U, ushortT* __restrict__ WVh)
{
  __shared__ float hs[8][128];
  int tid = threadIdx.x;
  size_t n0 = (size_t)blockIdx.x * 8;
  if (tid < 256) {
    int r = tid >> 5, c = (tid & 31) * 4;
    *(float4*)&hs[r][c] = *(const float4*)(h + (n0 + r)*128 + c);
  }
  __syncthreads();
  int d = tid & 127, seg = tid >> 7;   // 0: U, 1: WVh[0:128], 2: WVh[128:256]
  const float* wbase = (seg == 0) ? (aw1 + d)
                     : (seg == 1) ? (aw1 + 256*128 + d)
                                  : (nw1 + 128*128 + d);
  float s[8] = {0.f,0.f,0.f,0.f,0.f,0.f,0.f,0.f};
  for (int c = 0; c < 128; ++c) {
    float w = wbase[(size_t)c*128];
    #pragma unroll
    for (int r = 0; r < 8; ++r) s[r] += hs[r][c] * w;
  }
  if (seg == 0) {
    #pragma unroll
    for (int r = 0; r < 8; ++r) U[(n0 + r)*128 + d] = s[r];
  } else {
    int off = (seg - 1) * 128;
    #pragma unroll
    for (int r = 0; r < 8; ++r) WVh[(n0 + r)*256 + off + d] = f2bf(s[r]);
  }
}

// ---------------- fused edge pipeline: 1 node, 512 threads --------------------
// Balanced waves: each wave owns 32 att cols (nt 0,1) + 32 node cols (nt 2,3)
// in both GEMMs and epilogues -> gelu spread over all 8 waves.
// T14: WVh gather issued pre-barrier-1 (raw s_barrier, lgkm-only), LDS-written
// after GEMM1 (latency hidden under MFMA).
// LDS: Xb[32][512B] swz bf16; WVhS[32][512B]; lgp[4][32]; Ubs[128]. 33792 B.
__global__ __launch_bounds__(512, 8) void edge_kernel(
    const float* __restrict__ e,
    const int* __restrict__ edge_idx,
    const ushortT* __restrict__ WVh,
    const ushortT* __restrict__ WF1, const ushortT* __restrict__ WF2,
    const float* __restrict__ bias1, const float* __restrict__ bias2,
    const float* __restrict__ aw3, const float* __restrict__ ab3,
    float* __restrict__ hh)
{
  extern __shared__ char smem[];
  char*  Xb   = smem;                       // [32][512B] swizzled bf16 (16384 B)
  char*  WVhS = smem + 16384;               // [32][512B] swizzled bf16 (16384 B)
  float* lgp  = (float*)(smem + 32768);     // [4][32] logits partials
  float* Ubs  = (float*)(smem + 33280);     // [128]

  const int tid  = threadIdx.x;
  const int lane = tid & 63;
  const int wid  = tid >> 6;
  const int node = blockIdx.x;
  const long e0 = (long)node * KNB;

  // U row (precomputed into hh) — issued first, in flight during staging
  float uval = 0.f;
  if (tid < 128) uval = hh[(size_t)node*128 + tid];

  // ---- Phase 0a: stage e -> bf16 Xb cols 0..127; rows 30/31 zeroed ----
  {
    int r = tid >> 4, c8 = tid & 15;       // 32 rows x 16 groups = 512
    ushort8v u = {0,0,0,0,0,0,0,0};
    if (r < KNB) {
      const float* src = e + ((size_t)(e0 + r))*128 + c8*8;
      float4 v0 = *(const float4*)src;
      float4 v1 = *(const float4*)(src + 4);
      u[0]=f2bf(v0.x); u[1]=f2bf(v0.y); u[2]=f2bf(v0.z); u[3]=f2bf(v0.w);
      u[4]=f2bf(v1.x); u[5]=f2bf(v1.y); u[6]=f2bf(v1.z); u[7]=f2bf(v1.w);
    }
    *(ushort8v*)(Xb + r*512 + ((c8*16) ^ SWZ(r))) = u;
  }
  // ---- Phase 0b: ISSUE WVh[dst] gathers into registers (write-late) ----
  const int r0 = tid >> 5, c80 = tid & 31;       // idx = tid
  const int r1 = 16 + (tid >> 5);                // idx = 512+tid
  ushort8v wv0 = {0,0,0,0,0,0,0,0}, wv1 = {0,0,0,0,0,0,0,0};
  if (r0 < KNB) {
    int dst = edge_idx[NE + e0 + r0];
    wv0 = *(const ushort8v*)(WVh + (size_t)dst*256 + c80*8);
  }
  if (r1 < KNB) {
    int dst = edge_idx[NE + e0 + r1];
    wv1 = *(const ushort8v*)(WVh + (size_t)dst*256 + c80*8);
  }
  if (tid < 128) Ubs[tid] = uval;
  // barrier 1: LDS (Xb/Ubs) drained; global loads stay in flight
  asm volatile("s_waitcnt lgkmcnt(0)" ::: "memory");
  __builtin_amdgcn_s_barrier();

  const int mrow = lane & 15, krow = lane >> 4;
  const int wr = wid >> 2;   // row strip (16 rows)
  const int wq = wid & 3;    // 32-col group (att + node)
  const int row = wr*16 + mrow;

  f32x4 acc[4];
  #pragma unroll
  for (int nt = 0; nt < 4; ++nt) acc[nt] = (f32x4){0.f,0.f,0.f,0.f};

  // ---- GEMM1: e[32x128] @ WF1 -> acc: nt 0,1 att cols, nt 2,3 node cols ----
  #pragma unroll
  for (int kt = 0; kt < 4; ++kt) {
    bf16x8 a = *(const bf16x8*)(Xb + row*512 + ((kt*64 + krow*16) ^ SWZ(row)));
    const ushortT* Ba = WF1 + ((size_t)(wq*2)*8 + kt)*512 + lane*8;       // att half
    const ushortT* Bn = WF1 + ((size_t)(8 + wq*2)*8 + kt)*512 + lane*8;   // node half
    acc[0] = __builtin_amdgcn_mfma_f32_16x16x32_bf16(a, *(const bf16x8*)Ba, acc[0], 0, 0, 0);
    acc[1] = __builtin_amdgcn_mfma_f32_16x16x32_bf16(a, *(const bf16x8*)(Ba + 8*512), acc[1], 0, 0, 0);
    acc[2] = __builtin_amdgcn_mfma_f32_16x16x32_bf16(a, *(const bf16x8*)Bn, acc[2], 0, 0, 0);
    acc[3] = __builtin_amdgcn_mfma_f32_16x16x32_bf16(a, *(const bf16x8*)(Bn + 8*512), acc[3], 0, 0, 0);
  }
  // write-late: WVh fragments -> LDS (vmcnt waited here, hidden under GEMM1)
  *(ushort8v*)(WVhS + r0*512 + ((c80*16) ^ SWZ(r0))) = wv0;
  *(ushort8v*)(WVhS + r1*512 + ((c80*16) ^ SWZ(r1))) = wv1;
  __syncthreads();

  // epilogue 1: + bias + WVh[dst] (+U on att), relu / gelu, store bf16 in place
  {
    #pragma unroll
    for (int rr = 0; rr < 4; ++rr) {
      int orow = wr*16 + krow*4 + rr;
      const char* wrow = WVhS + orow*512;
      char* xrow = Xb + orow*512;
      #pragma unroll
      for (int nt = 0; nt < 2; ++nt) {
        int col = wq*32 + nt*16 + mrow;
        float wv = bf2f(*(const ushortT*)(wrow + ((2*col) ^ SWZ(orow))));
        float x = fmaxf(acc[nt][rr] + bias1[col] + wv + Ubs[col], 0.f);
        *(ushortT*)(xrow + ((2*col) ^ SWZ(orow))) = f2bf(x);
      }
      #pragma unroll
      for (int nt = 0; nt < 2; ++nt) {
        int cg = 128 + wq*32 + nt*16 + mrow;
        float wv = bf2f(*(const ushortT*)(wrow + ((2*cg) ^ SWZ(orow))));
        float x = gelu_f(acc[2+nt][rr] + bias1[cg] + wv);
        *(ushortT*)(xrow + ((2*cg) ^ SWZ(orow))) = f2bf(x);
      }
    }
  }
  __syncthreads();

  // ---- GEMM2: W2 = W1@aw2 (nt 0,1), V2pre = V1@nw2 (nt 2,3) ----
  #pragma unroll
  for (int nt = 0; nt < 4; ++nt) acc[nt] = (f32x4){0.f,0.f,0.f,0.f};
  #pragma unroll
  for (int kt = 0; kt < 4; ++kt) {
    bf16x8 a0 = *(const bf16x8*)(Xb + row*512 + ((kt*64 + krow*16) ^ SWZ(row)));
    bf16x8 a1 = *(const bf16x8*)(Xb + row*512 + ((256 + kt*64 + krow*16) ^ SWZ(row)));
    const ushortT* Ba = WF2 + ((size_t)(wq*2)*4 + kt)*512 + lane*8;
    const ushortT* Bn = WF2 + ((size_t)(8 + wq*2)*4 + kt)*512 + lane*8;
    acc[0] = __builtin_amdgcn_mfma_f32_16x16x32_bf16(a0, *(const bf16x8*)Ba, acc[0], 0, 0, 0);
    acc[1] = __builtin_amdgcn_mfma_f32_16x16x32_bf16(a0, *(const bf16x8*)(Ba + 4*512), acc[1], 0, 0, 0);
    acc[2] = __builtin_amdgcn_mfma_f32_16x16x32_bf16(a1, *(const bf16x8*)Bn, acc[2], 0, 0, 0);
    acc[3] = __builtin_amdgcn_mfma_f32_16x16x32_bf16(a1, *(const bf16x8*)(Bn + 4*512), acc[3], 0, 0, 0);
  }
  __syncthreads();
  // epilogue 2: logits partial from W2 (in-reg), V2 (gelu) -> Xb left half
  {
    float aw3c[2];
    aw3c[0] = aw3[wq*32 + mrow];
    aw3c[1] = aw3[wq*32 + 16 + mrow];
    #pragma unroll
    for (int rr = 0; rr < 4; ++rr) {
      int orow = wr*16 + krow*4 + rr;
      float lsum = fmaxf(acc[0][rr] + bias2[wq*32 + mrow], 0.f) * aw3c[0]
                 + fmaxf(acc[1][rr] + bias2[wq*32 + 16 + mrow], 0.f) * aw3c[1];
      lsum += __shfl_xor(lsum, 1);
      lsum += __shfl_xor(lsum, 2);
      lsum += __shfl_xor(lsum, 4);
      lsum += __shfl_xor(lsum, 8);
      if (mrow == 0) lgp[wq*32 + orow] = lsum;
      char* xrow = Xb + orow*512;
      #pragma unroll
      for (int nt = 0; nt < 2; ++nt) {
        int cn = wq*32 + nt*16 + mrow;
        float x = gelu_f(acc[2+nt][rr] + bias2[128 + cn]);
        *(ushortT*)(xrow + ((2*cn) ^ SWZ(orow))) = f2bf(x);
      }
    }
  }
  __syncthreads();

  // ---- softmax over 30 neighbors + q = att@V2 (8 waves x 16 cols) ----
  {
    int cl = lane & 15, ks = lane >> 4;
    float x = -INFINITY;
    if (lane < KNB)
      x = (lgp[lane] + lgp[32 + lane] + lgp[64 + lane] + lgp[96 + lane] + ab3[0])
          * 0.08838834764831845f;
    float m = x;
    #pragma unroll
    for (int off = 32; off >= 1; off >>= 1) m = fmaxf(m, __shfl_xor(m, off));
    float p = (lane < KNB) ? __expf(x - m) : 0.f;
    float ssum = p;
    #pragma unroll
    for (int off = 32; off >= 1; off >>= 1) ssum += __shfl_xor(ssum, off);
    float attv = p / ssum;
    float s = 0.f;
    int col = wid*16 + cl;
    #pragma unroll
    for (int j = 0; j < 8; ++j) {
      int k2 = ks + 4*j;
      float a = __shfl(attv, k2 & 31);
      float v = 0.f;
      if (k2 < KNB)
        v = bf2f(*(const ushortT*)(Xb + k2*512 + ((2*col) ^ SWZ(k2))));
      s += a * v;
    }
    s += __shfl_xor(s, 16);
    s += __shfl_xor(s, 32);
    if (lane < 16) hh[(size_t)node*128 + col] = s;
  }
}

// ---------------- deterministic column reduction over nodes (on q) ------------
__global__ void reduce1_kernel(const float* __restrict__ hh, float* __restrict__ p2) {
  int b = blockIdx.x, tid = threadIdx.x;
  int d = tid & 127, half = tid >> 7;
  float s = 0.f;
  const float* base = hh + (size_t)(b*64 + half*32)*128 + d;
  #pragma unroll 4
  for (int i = 0; i < 32; ++i) s += base[(size_t)i*128];
  __shared__ float ps[256];
  ps[tid] = s; __syncthreads();
  if (tid < 128) p2[b*128 + tid] = ps[tid] + ps[tid + 128];
}

// gate: c = (mean q)@M + c3; g = sigmoid(MLP(c))
__global__ void gate_kernel(const float* __restrict__ p2,
                            const float* __restrict__ M, const float* __restrict__ c3,
                            const float* __restrict__ gw1, const float* __restrict__ gb1,
                            const float* __restrict__ gw2, const float* __restrict__ gb2,
                            const float* __restrict__ gw3, const float* __restrict__ gb3,
                            float* __restrict__ gout) {
  int tid = threadIdx.x;
  int d = tid & 127, half = tid >> 7;
  float s = 0.f;
  for (int i = 0; i < 128; ++i) s += p2[(half*128 + i)*128 + d];
  __shared__ float ps[256];
  __shared__ float cv[128], cv2[128], y1[128], y2[128];
  ps[tid] = s; __syncthreads();
  if (tid < 128) cv[tid] = (ps[tid] + ps[tid+128]) * (1.f / (float)NN);
  __syncthreads();
  if (tid < 128) {
    float a = c3[tid];
    for (int c = 0; c < 128; ++c) a += cv[c] * M[c*128 + tid];
    cv2[tid] = a;
  }
  __syncthreads();
  if (tid < 128) {
    float a = gb1[tid];
    for (int c = 0; c < 128; ++c) a += cv2[c] * gw1[c*128 + tid];
    y1[tid] = fmaxf(a, 0.f);
  }
  __syncthreads();
  if (tid < 128) {
    float a = gb2[tid];
    for (int c = 0; c < 128; ++c) a += y1[c] * gw2[c*128 + tid];
    y2[tid] = fmaxf(a, 0.f);
  }
  __syncthreads();
  if (tid < 128) {
    float a = gb3[tid];
    for (int c = 0; c < 128; ++c) a += y2[c] * gw3[c*128 + tid];
    gout[tid] = 1.f / (1.f + __expf(-a));
  }
}

// ---------------- fused (V3 + to_h + gate): out = (q@M + c3)*g, in place ------
__global__ void toh_scale_kernel(float* __restrict__ hh, const float* __restrict__ M,
                                 const float* __restrict__ c3,
                                 const float* __restrict__ gv)
{
  __shared__ float hs[16][128];
  int tid = threadIdx.x;
  size_t n0 = (size_t)blockIdx.x * 16;
  {
    int r = tid >> 4, c = (tid & 15) * 8;
    const float* src = hh + (n0 + r)*128 + c;
    *(float4*)&hs[r][c]     = *(const float4*)src;
    *(float4*)&hs[r][c + 4] = *(const float4*)(src + 4);
  }
  __syncthreads();
  int d = tid & 127, gq = tid >> 7;
  float s[8] = {0.f,0.f,0.f,0.f,0.f,0.f,0.f,0.f};
  for (int c = 0; c < 128; ++c) {
    float w = M[c*128 + d];
    #pragma unroll
    for (int r = 0; r < 8; ++r) s[r] += hs[gq*8 + r][c] * w;
  }
  float gd = gv[d];
  float cd = c3[d];
  #pragma unroll
  for (int r = 0; r < 8; ++r) hh[(n0 + gq*8 + r)*128 + d] = (s[r] + cd) * gd;
}

extern "C" void kernel_launch(void* const* d_in, const int* in_sizes, int n_in,
                              void* d_out, int out_size, void* d_ws, size_t ws_size,
                              hipStream_t stream) {
  const float* h   = (const float*)d_in[0];
  const float* e   = (const float*)d_in[1];
  const float* aw1 = (const float*)d_in[2];
  const float* ab1 = (const float*)d_in[3];
  const float* aw2 = (const float*)d_in[4];
  const float* ab2 = (const float*)d_in[5];
  const float* aw3 = (const float*)d_in[6];
  const float* ab3 = (const float*)d_in[7];
  const float* nw1 = (const float*)d_in[8];
  const float* nb1 = (const float*)d_in[9];
  const float* nw2 = (const float*)d_in[10];
  const float* nb2 = (const float*)d_in[11];
  const float* nw3 = (const float*)d_in[12];
  const float* nb3 = (const float*)d_in[13];
  const float* thw = (const float*)d_in[14];
  const float* gw1 = (const float*)d_in[15];
  const float* gb1 = (const float*)d_in[16];
  const float* gw2 = (const float*)d_in[17];
  const float* gb2 = (const float*)d_in[18];
  const float* gw3 = (const float*)d_in[19];
  const float* gb3 = (const float*)d_in[20];
  const int* edge_idx = (const int*)d_in[21];

  char* ws = (char*)d_ws;
  ushortT* WF1 = (ushortT*)(ws + 0);        // 131072 B
  ushortT* WF2 = (ushortT*)(ws + 131072);   // 65536 B
  ushortT* WF3 = (ushortT*)(ws + 196608);   // 32768 B (packed, unused)
  float* bias1 = (float*)(ws + 229376);     // 1024 B
  float* bias2 = (float*)(ws + 230400);     // 1024 B
  float* bias3 = (float*)(ws + 231424);     // 512 B (packed, unused)
  float* p2    = (float*)(ws + 231936);     // 131072 B
  float* gout  = (float*)(ws + 363008);     // 512 B
  float* Mw    = (float*)(ws + 363520);     // 65536 B
  float* c3w   = (float*)(ws + 429056);     // 512 B
  ushortT* WVh = (ushortT*)(ws + 429568);   // 8388608 B
  float* hh    = (float*)d_out;

  pack_kernel<<<59, 256, 0, stream>>>(aw1, nw1, aw2, nw2, nw3,
                                      ab1, nb1, ab2, nb2, nb3,
                                      WF1, WF2, WF3, bias1, bias2, bias3);

  m_kernel<<<129, 128, 0, stream>>>(nw3, nb3, thw, Mw, c3w);

  // U = h@aw1[0:128] (into hh, consumed in-place) + WVh bf16
  uwvh_kernel<<<NN/8, 384, 0, stream>>>(h, aw1, nw1, hh, WVh);

  const int SMEM = 33792;
  hipFuncSetAttribute((const void*)edge_kernel,
                      hipFuncAttributeMaxDynamicSharedMemorySize, SMEM);
  edge_kernel<<<NN, 512, SMEM, stream>>>(e, edge_idx, WVh, WF1, WF2,
                                         bias1, bias2, aw3, ab3, hh);

  reduce1_kernel<<<256, 256, 0, stream>>>(hh, p2);
  gate_kernel<<<1, 256, 0, stream>>>(p2, Mw, c3w, gw1, gb1, gw2, gb2, gw3, gb3, gout);
  toh_scale_kernel<<<NN/16, 256, 0, stream>>>(hh, Mw, c3w, gout);
}

// Round 8
// 333.912 us; speedup vs baseline: 1.7879x; 1.0638x over previous
//
#include <hip/hip_runtime.h>
#include <math.h>

#define NN 16384
#define KNB 30
#define NE (NN*KNB)   // 491520

typedef __attribute__((ext_vector_type(8))) __bf16 bf16x8;
typedef __attribute__((ext_vector_type(4))) float f32x4;
typedef unsigned short ushortT;
typedef __attribute__((ext_vector_type(8))) unsigned short ushort8v;

#define SWZ(r) (((r)&7)<<4)

__device__ __forceinline__ ushortT f2bf(float x){
  __bf16 b = (__bf16)x;
  union { __bf16 b; ushortT u; } v; v.b = b; return v.u;
}
__device__ __forceinline__ float bf2f(ushortT u){
  union { unsigned int u32; float f; } v; v.u32 = ((unsigned int)u) << 16;
  return v.f;
}
__device__ __forceinline__ float bf2f_lo(unsigned int w){
  union { unsigned int u32; float f; } v; v.u32 = w << 16; return v.f;
}
__device__ __forceinline__ float bf2f_hi(unsigned int w){
  union { unsigned int u32; float f; } v; v.u32 = w & 0xffff0000u; return v.f;
}
// A&S 7.1.26 erf (|err| <= 1.5e-7), exact-GELU compatible at bf16 tolerance
__device__ __forceinline__ float gelu_f(float x){
  float ax = fabsf(x) * 0.7071067811865476f;
  float t = 1.0f / (1.0f + 0.3275911f * ax);
  float poly = t*(0.254829592f + t*(-0.284496736f + t*(1.421413741f +
               t*(-1.453152027f + t*1.061405429f))));
  float er = 1.0f - poly * __expf(-ax*ax);
  er = copysignf(er, x);
  return 0.5f * x * (1.0f + er);
}

// ---------------- merged prep kernel ------------------------------------------
// blocks 0..2047      : uwvh  (U = h@aw1[0:128] -> hh; WVhP paired bf16)
// blocks 2048..2106   : pack  (WF1/WF2 fragments + bias1/2)
// blocks 2107..2235   : M = nw3@thw, c3 = nb3@thw
// WVhP pairing: value (g, c) with c=0..127, g=0 att / 1 node:
//   wq=c>>5, m=c&15, hi=(c>>4)&1 -> ushort idx = ((g*4+wq)*16+m)*2 + hi
// so consumer dword at ((g*4+wq)*16+m) holds cols (g*128+wq*32+m, +16).
__global__ void prep_kernel(const float* __restrict__ h,
                            const float* __restrict__ aw1, const float* __restrict__ nw1,
                            const float* __restrict__ aw2, const float* __restrict__ nw2,
                            const float* __restrict__ nw3, const float* __restrict__ nb3,
                            const float* __restrict__ thw,
                            const float* __restrict__ ab1, const float* __restrict__ nb1,
                            const float* __restrict__ ab2, const float* __restrict__ nb2,
                            ushortT* __restrict__ WF1, ushortT* __restrict__ WF2,
                            float* __restrict__ bias1, float* __restrict__ bias2,
                            float* __restrict__ U, ushortT* __restrict__ WVhP,
                            float* __restrict__ M, float* __restrict__ c3)
{
  __shared__ float sbuf[8*128];
  int tid = threadIdx.x;
  int b = blockIdx.x;

  if (b < 2048) {
    // ---- uwvh: 8 nodes, 384 threads ----
    size_t n0 = (size_t)b * 8;
    if (tid < 256) {
      int r = tid >> 5, c = (tid & 31) * 4;
      *(float4*)&sbuf[r*128 + c] = *(const float4*)(h + (n0 + r)*128 + c);
    }
    __syncthreads();
    int d = tid & 127, seg = tid >> 7;   // 0: U, 1: WVh att, 2: WVh node
    const float* wbase = (seg == 0) ? (aw1 + d)
                       : (seg == 1) ? (aw1 + 256*128 + d)
                                    : (nw1 + 128*128 + d);
    float s[8] = {0.f,0.f,0.f,0.f,0.f,0.f,0.f,0.f};
    for (int c = 0; c < 128; ++c) {
      float w = wbase[(size_t)c*128];
      #pragma unroll
      for (int r = 0; r < 8; ++r) s[r] += sbuf[r*128 + c] * w;
    }
    if (seg == 0) {
      #pragma unroll
      for (int r = 0; r < 8; ++r) U[(n0 + r)*128 + d] = s[r];
    } else {
      int g = seg - 1;
      int idx = ((g*4 + (d >> 5))*16 + (d & 15))*2 + ((d >> 4) & 1);
      #pragma unroll
      for (int r = 0; r < 8; ++r) WVhP[(n0 + r)*256 + idx] = f2bf(s[r]);
    }
    return;
  }
  if (b < 2107) {
    // ---- pack: u in [0, 59*256) over 256-thread slices ----
    if (tid >= 256) return;
    int u = (b - 2048) * 256 + tid;
    if (u < 8192) {
      int lane = u & 63, tile = u >> 6;
      int half = tile >> 6, nt = (tile >> 3) & 7, kt = tile & 7;
      int mrow = lane & 15, krow = lane >> 4;
      int n = half*128 + nt*16 + mrow, k0 = kt*32 + krow*8;
      ushort8v o;
      #pragma unroll
      for (int j = 0; j < 8; ++j) {
        int k = k0 + j;
        float v = (half == 0) ? aw1[(128 + k)*128 + n] : nw1[k*128 + (n - 128)];
        o[j] = f2bf(v);
      }
      *(ushort8v*)(WF1 + (size_t)u*8) = o;
      return;
    }
    u -= 8192;
    if (u < 4096) {
      int lane = u & 63, tile = u >> 6;
      int half = tile >> 5, nt = (tile >> 2) & 7, kt = tile & 3;
      int mrow = lane & 15, krow = lane >> 4;
      int n = half*128 + nt*16 + mrow, k0 = kt*32 + krow*8;
      ushort8v o;
      #pragma unroll
      for (int j = 0; j < 8; ++j) {
        int k = k0 + j;
        float v = (half == 0) ? aw2[k*128 + n] : nw2[k*128 + (n - 128)];
        o[j] = f2bf(v);
      }
      *(ushort8v*)(WF2 + (size_t)u*8) = o;
      return;
    }
    u -= 4096;
    if (u < 256) { bias1[u] = (u < 128) ? ab1[u] : nb1[u - 128]; return; }
    u -= 256;
    if (u < 256) { bias2[u] = (u < 128) ? ab2[u] : nb2[u - 128]; return; }
    return;
  }
  {
    // ---- M / c3: 129 blocks, 128 threads ----
    if (tid >= 128) return;
    int bb = b - 2107;
    int d = tid;
    sbuf[d] = (bb < 128) ? nw3[bb*128 + d] : nb3[d];
    __syncthreads();
    float s = 0.f;
    for (int n = 0; n < 128; ++n) s += sbuf[n] * thw[n*128 + d];
    if (bb < 128) M[bb*128 + d] = s;
    else c3[d] = s;
  }
}

// ---------------- fused edge pipeline: 1 node, 512 threads --------------------
// Direct WVh gather: each thread loads the exact 8 paired dwords its ep1 tile
// needs (issued pre-GEMM1, consumed from registers — no WVhS LDS round-trip).
// LDS: Xb[32][512B] swz bf16 (16K); lgp[4][32]; Ubs[128]. 17408 B.
__global__ __launch_bounds__(512, 8) void edge_kernel(
    const float* __restrict__ e,
    const int* __restrict__ edge_idx,
    const ushortT* __restrict__ WVhP,
    const ushortT* __restrict__ WF1, const ushortT* __restrict__ WF2,
    const float* __restrict__ bias1, const float* __restrict__ bias2,
    const float* __restrict__ aw3, const float* __restrict__ ab3,
    float* __restrict__ hh)
{
  extern __shared__ char smem[];
  char*  Xb   = smem;                       // [32][512B] swizzled bf16 (16384 B)
  float* lgp  = (float*)(smem + 16384);     // [4][32] logits partials
  float* Ubs  = (float*)(smem + 16896);     // [128]

  const int tid  = threadIdx.x;
  const int lane = tid & 63;
  const int wid  = tid >> 6;
  const int node = blockIdx.x;
  const long e0 = (long)node * KNB;

  const int mrow = lane & 15, krow = lane >> 4;
  const int wr = wid >> 2;   // row strip (16 rows)
  const int wq = wid & 3;    // 32-col group (att + node)
  const int row = wr*16 + mrow;

  // U row (precomputed into hh) — issued first, in flight during staging
  float uval = 0.f;
  if (tid < 128) uval = hh[(size_t)node*128 + tid];

  // dst indices for this thread's 4 output rows (guard rows >= 30)
  int dstr[4];
  #pragma unroll
  for (int rr = 0; rr < 4; ++rr) {
    int orow = wr*16 + krow*4 + rr;
    dstr[rr] = (orow < KNB) ? edge_idx[NE + e0 + orow] : -1;
  }

  // ---- Phase 0a: stage e -> bf16 Xb cols 0..127; rows 30/31 zeroed ----
  {
    int r = tid >> 4, c8 = tid & 15;       // 32 rows x 16 groups = 512
    ushort8v u = {0,0,0,0,0,0,0,0};
    if (r < KNB) {
      const float* src = e + ((size_t)(e0 + r))*128 + c8*8;
      float4 v0 = *(const float4*)src;
      float4 v1 = *(const float4*)(src + 4);
      u[0]=f2bf(v0.x); u[1]=f2bf(v0.y); u[2]=f2bf(v0.z); u[3]=f2bf(v0.w);
      u[4]=f2bf(v1.x); u[5]=f2bf(v1.y); u[6]=f2bf(v1.z); u[7]=f2bf(v1.w);
    }
    *(ushort8v*)(Xb + r*512 + ((c8*16) ^ SWZ(r))) = u;
  }

  // ---- Phase 0b: issue direct WVh gathers (att + node pair dwords) ----
  unsigned int wva[4], wvn[4];
  #pragma unroll
  for (int rr = 0; rr < 4; ++rr) {
    wva[rr] = 0u; wvn[rr] = 0u;
    if (dstr[rr] >= 0) {
      const unsigned int* base = (const unsigned int*)(WVhP + (size_t)dstr[rr]*256);
      wva[rr] = base[wq*16 + mrow];        // cols (wq*32+mrow, +16)
      wvn[rr] = base[64 + wq*16 + mrow];   // cols (128+wq*32+mrow, +16)
    }
  }
  if (tid < 128) Ubs[tid] = uval;
  // barrier: LDS drained; WVh gathers stay in flight through GEMM1
  asm volatile("s_waitcnt lgkmcnt(0)" ::: "memory");
  __builtin_amdgcn_s_barrier();

  // hoisted per-column constants (L1-resident)
  const float b1a0 = bias1[wq*32 + mrow],        b1a1 = bias1[wq*32 + 16 + mrow];
  const float b1n0 = bias1[128 + wq*32 + mrow],  b1n1 = bias1[128 + wq*32 + 16 + mrow];
  const float b2a0 = bias2[wq*32 + mrow],        b2a1 = bias2[wq*32 + 16 + mrow];
  const float b2n0 = bias2[128 + wq*32 + mrow],  b2n1 = bias2[128 + wq*32 + 16 + mrow];
  const float aw3c0 = aw3[wq*32 + mrow],         aw3c1 = aw3[wq*32 + 16 + mrow];

  f32x4 acc[4];
  #pragma unroll
  for (int nt = 0; nt < 4; ++nt) acc[nt] = (f32x4){0.f,0.f,0.f,0.f};

  // ---- GEMM1: e[32x128] @ WF1 -> acc: nt 0,1 att cols, nt 2,3 node cols ----
  #pragma unroll
  for (int kt = 0; kt < 4; ++kt) {
    bf16x8 a = *(const bf16x8*)(Xb + row*512 + ((kt*64 + krow*16) ^ SWZ(row)));
    const ushortT* Ba = WF1 + ((size_t)(wq*2)*8 + kt)*512 + lane*8;       // att half
    const ushortT* Bn = WF1 + ((size_t)(8 + wq*2)*8 + kt)*512 + lane*8;   // node half
    acc[0] = __builtin_amdgcn_mfma_f32_16x16x32_bf16(a, *(const bf16x8*)Ba, acc[0], 0, 0, 0);
    acc[1] = __builtin_amdgcn_mfma_f32_16x16x32_bf16(a, *(const bf16x8*)(Ba + 8*512), acc[1], 0, 0, 0);
    acc[2] = __builtin_amdgcn_mfma_f32_16x16x32_bf16(a, *(const bf16x8*)Bn, acc[2], 0, 0, 0);
    acc[3] = __builtin_amdgcn_mfma_f32_16x16x32_bf16(a, *(const bf16x8*)(Bn + 8*512), acc[3], 0, 0, 0);
  }
  __syncthreads();

  // epilogue 1: + bias + WVh[dst] (+U on att), relu / gelu, store bf16 in place
  {
    const float ub0 = Ubs[wq*32 + mrow], ub1 = Ubs[wq*32 + 16 + mrow];
    #pragma unroll
    for (int rr = 0; rr < 4; ++rr) {
      int orow = wr*16 + krow*4 + rr;
      char* xrow = Xb + orow*512;
      int sw = SWZ(orow);
      int ca0 = 2*(wq*32 + mrow),        ca1 = 2*(wq*32 + 16 + mrow);
      float x0 = fmaxf(acc[0][rr] + b1a0 + bf2f_lo(wva[rr]) + ub0, 0.f);
      float x1 = fmaxf(acc[1][rr] + b1a1 + bf2f_hi(wva[rr]) + ub1, 0.f);
      *(ushortT*)(xrow + (ca0 ^ sw)) = f2bf(x0);
      *(ushortT*)(xrow + (ca1 ^ sw)) = f2bf(x1);
      float y0 = gelu_f(acc[2][rr] + b1n0 + bf2f_lo(wvn[rr]));
      float y1 = gelu_f(acc[3][rr] + b1n1 + bf2f_hi(wvn[rr]));
      *(ushortT*)(xrow + ((256 + ca0) ^ sw)) = f2bf(y0);
      *(ushortT*)(xrow + ((256 + ca1) ^ sw)) = f2bf(y1);
    }
  }
  __syncthreads();

  // ---- GEMM2: W2 = W1@aw2 (nt 0,1), V2pre = V1@nw2 (nt 2,3) ----
  #pragma unroll
  for (int nt = 0; nt < 4; ++nt) acc[nt] = (f32x4){0.f,0.f,0.f,0.f};
  #pragma unroll
  for (int kt = 0; kt < 4; ++kt) {
    bf16x8 a0 = *(const bf16x8*)(Xb + row*512 + ((kt*64 + krow*16) ^ SWZ(row)));
    bf16x8 a1 = *(const bf16x8*)(Xb + row*512 + ((256 + kt*64 + krow*16) ^ SWZ(row)));
    const ushortT* Ba = WF2 + ((size_t)(wq*2)*4 + kt)*512 + lane*8;
    const ushortT* Bn = WF2 + ((size_t)(8 + wq*2)*4 + kt)*512 + lane*8;
    acc[0] = __builtin_amdgcn_mfma_f32_16x16x32_bf16(a0, *(const bf16x8*)Ba, acc[0], 0, 0, 0);
    acc[1] = __builtin_amdgcn_mfma_f32_16x16x32_bf16(a0, *(const bf16x8*)(Ba + 4*512), acc[1], 0, 0, 0);
    acc[2] = __builtin_amdgcn_mfma_f32_16x16x32_bf16(a1, *(const bf16x8*)Bn, acc[2], 0, 0, 0);
    acc[3] = __builtin_amdgcn_mfma_f32_16x16x32_bf16(a1, *(const bf16x8*)(Bn + 4*512), acc[3], 0, 0, 0);
  }
  __syncthreads();
  // epilogue 2: logits partial from W2 (in-reg), V2 (gelu) -> Xb left half
  {
    #pragma unroll
    for (int rr = 0; rr < 4; ++rr) {
      int orow = wr*16 + krow*4 + rr;
      int sw = SWZ(orow);
      float lsum = fmaxf(acc[0][rr] + b2a0, 0.f) * aw3c0
                 + fmaxf(acc[1][rr] + b2a1, 0.f) * aw3c1;
      lsum += __shfl_xor(lsum, 1);
      lsum += __shfl_xor(lsum, 2);
      lsum += __shfl_xor(lsum, 4);
      lsum += __shfl_xor(lsum, 8);
      if (mrow == 0) lgp[wq*32 + orow] = lsum;
      char* xrow = Xb + orow*512;
      float y0 = gelu_f(acc[2][rr] + b2n0);
      float y1 = gelu_f(acc[3][rr] + b2n1);
      *(ushortT*)(xrow + ((2*(wq*32 + mrow)) ^ sw)) = f2bf(y0);
      *(ushortT*)(xrow + ((2*(wq*32 + 16 + mrow)) ^ sw)) = f2bf(y1);
    }
  }
  __syncthreads();

  // ---- softmax over 30 neighbors + q = att@V2 (8 waves x 16 cols) ----
  {
    int cl = lane & 15, ks = lane >> 4;
    float x = -INFINITY;
    if (lane < KNB)
      x = (lgp[lane] + lgp[32 + lane] + lgp[64 + lane] + lgp[96 + lane] + ab3[0])
          * 0.08838834764831845f;
    float m = x;
    #pragma unroll
    for (int off = 32; off >= 1; off >>= 1) m = fmaxf(m, __shfl_xor(m, off));
    float p = (lane < KNB) ? __expf(x - m) : 0.f;
    float ssum = p;
    #pragma unroll
    for (int off = 32; off >= 1; off >>= 1) ssum += __shfl_xor(ssum, off);
    float attv = p / ssum;   // lanes 30,31 -> 0 (rows 30/31 finite, weight 0)
    float s = 0.f;
    int col = wid*16 + cl;
    #pragma unroll
    for (int j = 0; j < 8; ++j) {
      int k2 = ks + 4*j;
      float a = __shfl(attv, k2);
      float v = bf2f(*(const ushortT*)(Xb + k2*512 + ((2*col) ^ SWZ(k2))));
      s += a * v;
    }
    s += __shfl_xor(s, 16);
    s += __shfl_xor(s, 32);
    if (lane < 16) hh[(size_t)node*128 + col] = s;
  }
}

// ---------------- deterministic column reduction over nodes (on q) ------------
__global__ void reduce1_kernel(const float* __restrict__ hh, float* __restrict__ p2) {
  int b = blockIdx.x, tid = threadIdx.x;
  int d = tid & 127, half = tid >> 7;
  float s = 0.f;
  const float* base = hh + (size_t)(b*64 + half*32)*128 + d;
  #pragma unroll 4
  for (int i = 0; i < 32; ++i) s += base[(size_t)i*128];
  __shared__ float ps[256];
  ps[tid] = s; __syncthreads();
  if (tid < 128) p2[b*128 + tid] = ps[tid] + ps[tid + 128];
}

// gate: c = (mean q)@M + c3; g = sigmoid(MLP(c))
__global__ void gate_kernel(const float* __restrict__ p2,
                            const float* __restrict__ M, const float* __restrict__ c3,
                            const float* __restrict__ gw1, const float* __restrict__ gb1,
                            const float* __restrict__ gw2, const float* __restrict__ gb2,
                            const float* __restrict__ gw3, const float* __restrict__ gb3,
                            float* __restrict__ gout) {
  int tid = threadIdx.x;
  int d = tid & 127, half = tid >> 7;
  float s = 0.f;
  for (int i = 0; i < 128; ++i) s += p2[(half*128 + i)*128 + d];
  __shared__ float ps[256];
  __shared__ float cv[128], cv2[128], y1[128], y2[128];
  ps[tid] = s; __syncthreads();
  if (tid < 128) cv[tid] = (ps[tid] + ps[tid+128]) * (1.f / (float)NN);
  __syncthreads();
  if (tid < 128) {
    float a = c3[tid];
    for (int c = 0; c < 128; ++c) a += cv[c] * M[c*128 + tid];
    cv2[tid] = a;
  }
  __syncthreads();
  if (tid < 128) {
    float a = gb1[tid];
    for (int c = 0; c < 128; ++c) a += cv2[c] * gw1[c*128 + tid];
    y1[tid] = fmaxf(a, 0.f);
  }
  __syncthreads();
  if (tid < 128) {
    float a = gb2[tid];
    for (int c = 0; c < 128; ++c) a += y1[c] * gw2[c*128 + tid];
    y2[tid] = fmaxf(a, 0.f);
  }
  __syncthreads();
  if (tid < 128) {
    float a = gb3[tid];
    for (int c = 0; c < 128; ++c) a += y2[c] * gw3[c*128 + tid];
    gout[tid] = 1.f / (1.f + __expf(-a));
  }
}

// ---------------- fused (V3 + to_h + gate): out = (q@M + c3)*g, in place ------
__global__ void toh_scale_kernel(float* __restrict__ hh, const float* __restrict__ M,
                                 const float* __restrict__ c3,
                                 const float* __restrict__ gv)
{
  __shared__ float hs[16][128];
  int tid = threadIdx.x;
  size_t n0 = (size_t)blockIdx.x * 16;
  {
    int r = tid >> 4, c = (tid & 15) * 8;
    const float* src = hh + (n0 + r)*128 + c;
    *(float4*)&hs[r][c]     = *(const float4*)src;
    *(float4*)&hs[r][c + 4] = *(const float4*)(src + 4);
  }
  __syncthreads();
  int d = tid & 127, gq = tid >> 7;
  float s[8] = {0.f,0.f,0.f,0.f,0.f,0.f,0.f,0.f};
  for (int c = 0; c < 128; ++c) {
    float w = M[c*128 + d];
    #pragma unroll
    for (int r = 0; r < 8; ++r) s[r] += hs[gq*8 + r][c] * w;
  }
  float gd = gv[d];
  float cd = c3[d];
  #pragma unroll
  for (int r = 0; r < 8; ++r) hh[(n0 + gq*8 + r)*128 + d] = (s[r] + cd) * gd;
}

extern "C" void kernel_launch(void* const* d_in, const int* in_sizes, int n_in,
                              void* d_out, int out_size, void* d_ws, size_t ws_size,
                              hipStream_t stream) {
  const float* h   = (const float*)d_in[0];
  const float* e   = (const float*)d_in[1];
  const float* aw1 = (const float*)d_in[2];
  const float* ab1 = (const float*)d_in[3];
  const float* aw2 = (const float*)d_in[4];
  const float* ab2 = (const float*)d_in[5];
  const float* aw3 = (const float*)d_in[6];
  const float* ab3 = (const float*)d_in[7];
  const float* nw1 = (const float*)d_in[8];
  const float* nb1 = (const float*)d_in[9];
  const float* nw2 = (const float*)d_in[10];
  const float* nb2 = (const float*)d_in[11];
  const float* nw3 = (const float*)d_in[12];
  const float* nb3 = (const float*)d_in[13];
  const float* thw = (const float*)d_in[14];
  const float* gw1 = (const float*)d_in[15];
  const float* gb1 = (const float*)d_in[16];
  const float* gw2 = (const float*)d_in[17];
  const float* gb2 = (const float*)d_in[18];
  const float* gw3 = (const float*)d_in[19];
  const float* gb3 = (const float*)d_in[20];
  const int* edge_idx = (const int*)d_in[21];

  char* ws = (char*)d_ws;
  ushortT* WF1 = (ushortT*)(ws + 0);        // 131072 B
  ushortT* WF2 = (ushortT*)(ws + 131072);   // 65536 B
  float* bias1 = (float*)(ws + 196608);     // 1024 B
  float* bias2 = (float*)(ws + 197632);     // 1024 B
  float* p2    = (float*)(ws + 198656);     // 131072 B
  float* gout  = (float*)(ws + 329728);     // 512 B
  float* Mw    = (float*)(ws + 330240);     // 65536 B
  float* c3w   = (float*)(ws + 395776);     // 512 B
  ushortT* WVhP= (ushortT*)(ws + 396288);   // 8388608 B
  float* hh    = (float*)d_out;

  // merged prep: uwvh (2048) + pack (59) + M (129)
  prep_kernel<<<2236, 384, 0, stream>>>(h, aw1, nw1, aw2, nw2, nw3, nb3, thw,
                                        ab1, nb1, ab2, nb2,
                                        WF1, WF2, bias1, bias2,
                                        hh, WVhP, Mw, c3w);

  const int SMEM = 17408;
  hipFuncSetAttribute((const void*)edge_kernel,
                      hipFuncAttributeMaxDynamicSharedMemorySize, SMEM);
  edge_kernel<<<NN, 512, SMEM, stream>>>(e, edge_idx, WVhP, WF1, WF2,
                                         bias1, bias2, aw3, ab3, hh);

  reduce1_kernel<<<256, 256, 0, stream>>>(hh, p2);
  gate_kernel<<<1, 256, 0, stream>>>(p2, Mw, c3w, gw1, gb1, gw2, gb2, gw3, gb3, gout);
  toh_scale_kernel<<<NN/16, 256, 0, stream>>>(hh, Mw, c3w, gout);
}

// Round 9
// 326.983 us; speedup vs baseline: 1.8258x; 1.0212x over previous
//
#include <hip/hip_runtime.h>
#include <math.h>

#define NN 16384
#define KNB 30
#define NE (NN*KNB)   // 491520

typedef __attribute__((ext_vector_type(8))) __bf16 bf16x8;
typedef __attribute__((ext_vector_type(4))) float f32x4;
typedef unsigned short ushortT;
typedef __attribute__((ext_vector_type(8))) unsigned short ushort8v;

#define SWZ(r) (((r)&7)<<4)

__device__ __forceinline__ ushortT f2bf(float x){
  __bf16 b = (__bf16)x;
  union { __bf16 b; ushortT u; } v; v.b = b; return v.u;
}
__device__ __forceinline__ float bf2f(ushortT u){
  union { unsigned int u32; float f; } v; v.u32 = ((unsigned int)u) << 16;
  return v.f;
}
__device__ __forceinline__ float bf2f_lo(unsigned int w){
  union { unsigned int u32; float f; } v; v.u32 = w << 16; return v.f;
}
__device__ __forceinline__ float bf2f_hi(unsigned int w){
  union { unsigned int u32; float f; } v; v.u32 = w & 0xffff0000u; return v.f;
}
// A&S 7.1.25 erf (3-term, |err| <= 2.5e-5) — ~100x below bf16 quantization of
// the stored activation; exact-GELU compatible at harness tolerance.
__device__ __forceinline__ float gelu_f(float x){
  float ax = fabsf(x) * 0.7071067811865476f;
  float t = 1.0f / (1.0f + 0.47047f * ax);
  float poly = t*(0.3480242f + t*(-0.0958798f + t*0.7478556f));
  float er = 1.0f - poly * __expf(-ax*ax);
  er = copysignf(er, x);
  return 0.5f * x * (1.0f + er);
}

// ---------------- merged prep kernel ------------------------------------------
// blocks 0..2047      : uwvh  (U = h@aw1[0:128] -> hh; WVhP paired bf16)
// blocks 2048..2106   : pack  (WF1/WF2 fragments + bias1/2)
// blocks 2107..2235   : M = nw3@thw, c3 = nb3@thw
// WVhP pairing: value (g, c) with c=0..127, g=0 att / 1 node:
//   wq=c>>5, m=c&15, hi=(c>>4)&1 -> ushort idx = ((g*4+wq)*16+m)*2 + hi
// so consumer dword at ((g*4+wq)*16+m) holds cols (g*128+wq*32+m, +16).
__global__ void prep_kernel(const float* __restrict__ h,
                            const float* __restrict__ aw1, const float* __restrict__ nw1,
                            const float* __restrict__ aw2, const float* __restrict__ nw2,
                            const float* __restrict__ nw3, const float* __restrict__ nb3,
                            const float* __restrict__ thw,
                            const float* __restrict__ ab1, const float* __restrict__ nb1,
                            const float* __restrict__ ab2, const float* __restrict__ nb2,
                            ushortT* __restrict__ WF1, ushortT* __restrict__ WF2,
                            float* __restrict__ bias1, float* __restrict__ bias2,
                            float* __restrict__ U, ushortT* __restrict__ WVhP,
                            float* __restrict__ M, float* __restrict__ c3)
{
  __shared__ float sbuf[8*128];
  int tid = threadIdx.x;
  int b = blockIdx.x;

  if (b < 2048) {
    // ---- uwvh: 8 nodes, 384 threads ----
    size_t n0 = (size_t)b * 8;
    if (tid < 256) {
      int r = tid >> 5, c = (tid & 31) * 4;
      *(float4*)&sbuf[r*128 + c] = *(const float4*)(h + (n0 + r)*128 + c);
    }
    __syncthreads();
    int d = tid & 127, seg = tid >> 7;   // 0: U, 1: WVh att, 2: WVh node
    const float* wbase = (seg == 0) ? (aw1 + d)
                       : (seg == 1) ? (aw1 + 256*128 + d)
                                    : (nw1 + 128*128 + d);
    float s[8] = {0.f,0.f,0.f,0.f,0.f,0.f,0.f,0.f};
    for (int c = 0; c < 128; ++c) {
      float w = wbase[(size_t)c*128];
      #pragma unroll
      for (int r = 0; r < 8; ++r) s[r] += sbuf[r*128 + c] * w;
    }
    if (seg == 0) {
      #pragma unroll
      for (int r = 0; r < 8; ++r) U[(n0 + r)*128 + d] = s[r];
    } else {
      int g = seg - 1;
      int idx = ((g*4 + (d >> 5))*16 + (d & 15))*2 + ((d >> 4) & 1);
      #pragma unroll
      for (int r = 0; r < 8; ++r) WVhP[(n0 + r)*256 + idx] = f2bf(s[r]);
    }
    return;
  }
  if (b < 2107) {
    // ---- pack: u in [0, 59*256) over 256-thread slices ----
    if (tid >= 256) return;
    int u = (b - 2048) * 256 + tid;
    if (u < 8192) {
      int lane = u & 63, tile = u >> 6;
      int half = tile >> 6, nt = (tile >> 3) & 7, kt = tile & 7;
      int mrow = lane & 15, krow = lane >> 4;
      int n = half*128 + nt*16 + mrow, k0 = kt*32 + krow*8;
      ushort8v o;
      #pragma unroll
      for (int j = 0; j < 8; ++j) {
        int k = k0 + j;
        float v = (half == 0) ? aw1[(128 + k)*128 + n] : nw1[k*128 + (n - 128)];
        o[j] = f2bf(v);
      }
      *(ushort8v*)(WF1 + (size_t)u*8) = o;
      return;
    }
    u -= 8192;
    if (u < 4096) {
      int lane = u & 63, tile = u >> 6;
      int half = tile >> 5, nt = (tile >> 2) & 7, kt = tile & 3;
      int mrow = lane & 15, krow = lane >> 4;
      int n = half*128 + nt*16 + mrow, k0 = kt*32 + krow*8;
      ushort8v o;
      #pragma unroll
      for (int j = 0; j < 8; ++j) {
        int k = k0 + j;
        float v = (half == 0) ? aw2[k*128 + n] : nw2[k*128 + (n - 128)];
        o[j] = f2bf(v);
      }
      *(ushort8v*)(WF2 + (size_t)u*8) = o;
      return;
    }
    u -= 4096;
    if (u < 256) { bias1[u] = (u < 128) ? ab1[u] : nb1[u - 128]; return; }
    u -= 256;
    if (u < 256) { bias2[u] = (u < 128) ? ab2[u] : nb2[u - 128]; return; }
    return;
  }
  {
    // ---- M / c3: 129 blocks, 128 threads ----
    if (tid >= 128) return;
    int bb = b - 2107;
    int d = tid;
    sbuf[d] = (bb < 128) ? nw3[bb*128 + d] : nb3[d];
    __syncthreads();
    float s = 0.f;
    for (int n = 0; n < 128; ++n) s += sbuf[n] * thw[n*128 + d];
    if (bb < 128) M[bb*128 + d] = s;
    else c3[d] = s;
  }
}

// ---------------- fused edge pipeline: 1 node, 512 threads --------------------
// Direct WVh gather (registers across GEMM1); softmax shift-invariance drops
// ab3; aw3 pre-scaled by 1/sqrt(DH); PV reads paired columns via ds_read_b32.
// LDS: Xb[32][512B] swz bf16 (16K); lgp[4][32]; Ubs[128]. 17408 B.
__global__ __launch_bounds__(512, 8) void edge_kernel(
    const float* __restrict__ e,
    const int* __restrict__ edge_idx,
    const ushortT* __restrict__ WVhP,
    const ushortT* __restrict__ WF1, const ushortT* __restrict__ WF2,
    const float* __restrict__ bias1, const float* __restrict__ bias2,
    const float* __restrict__ aw3, const float* __restrict__ ab3,
    float* __restrict__ hh)
{
  extern __shared__ char smem[];
  char*  Xb   = smem;                       // [32][512B] swizzled bf16 (16384 B)
  float* lgp  = (float*)(smem + 16384);     // [4][32] logits partials
  float* Ubs  = (float*)(smem + 16896);     // [128]

  const int tid  = threadIdx.x;
  const int lane = tid & 63;
  const int wid  = tid >> 6;
  const int node = blockIdx.x;
  const long e0 = (long)node * KNB;

  const int mrow = lane & 15, krow = lane >> 4;
  const int wr = wid >> 2;   // row strip (16 rows)
  const int wq = wid & 3;    // 32-col group (att + node)
  const int row = wr*16 + mrow;

  // U row (precomputed into hh) — issued first, in flight during staging
  float uval = 0.f;
  if (tid < 128) uval = hh[(size_t)node*128 + tid];

  // dst indices for this thread's 4 output rows (guard rows >= 30)
  int dstr[4];
  #pragma unroll
  for (int rr = 0; rr < 4; ++rr) {
    int orow = wr*16 + krow*4 + rr;
    dstr[rr] = (orow < KNB) ? edge_idx[NE + e0 + orow] : -1;
  }

  // ---- Phase 0a: stage e -> bf16 Xb cols 0..127; rows 30/31 zeroed ----
  {
    int r = tid >> 4, c8 = tid & 15;       // 32 rows x 16 groups = 512
    ushort8v u = {0,0,0,0,0,0,0,0};
    if (r < KNB) {
      const float* src = e + ((size_t)(e0 + r))*128 + c8*8;
      float4 v0 = *(const float4*)src;
      float4 v1 = *(const float4*)(src + 4);
      u[0]=f2bf(v0.x); u[1]=f2bf(v0.y); u[2]=f2bf(v0.z); u[3]=f2bf(v0.w);
      u[4]=f2bf(v1.x); u[5]=f2bf(v1.y); u[6]=f2bf(v1.z); u[7]=f2bf(v1.w);
    }
    *(ushort8v*)(Xb + r*512 + ((c8*16) ^ SWZ(r))) = u;
  }

  // ---- Phase 0b: issue direct WVh gathers (att + node pair dwords) ----
  unsigned int wva[4], wvn[4];
  #pragma unroll
  for (int rr = 0; rr < 4; ++rr) {
    wva[rr] = 0u; wvn[rr] = 0u;
    if (dstr[rr] >= 0) {
      const unsigned int* base = (const unsigned int*)(WVhP + (size_t)dstr[rr]*256);
      wva[rr] = base[wq*16 + mrow];        // cols (wq*32+mrow, +16)
      wvn[rr] = base[64 + wq*16 + mrow];   // cols (128+wq*32+mrow, +16)
    }
  }
  if (tid < 128) Ubs[tid] = uval;
  // barrier: LDS drained; WVh gathers stay in flight through GEMM1
  asm volatile("s_waitcnt lgkmcnt(0)" ::: "memory");
  __builtin_amdgcn_s_barrier();

  // hoisted per-column constants (L1-resident); aw3 pre-scaled by 1/sqrt(DH)
  const float b1a0 = bias1[wq*32 + mrow],        b1a1 = bias1[wq*32 + 16 + mrow];
  const float b1n0 = bias1[128 + wq*32 + mrow],  b1n1 = bias1[128 + wq*32 + 16 + mrow];
  const float b2a0 = bias2[wq*32 + mrow],        b2a1 = bias2[wq*32 + 16 + mrow];
  const float b2n0 = bias2[128 + wq*32 + mrow],  b2n1 = bias2[128 + wq*32 + 16 + mrow];
  const float aw3c0 = aw3[wq*32 + mrow]      * 0.08838834764831845f;
  const float aw3c1 = aw3[wq*32 + 16 + mrow] * 0.08838834764831845f;

  f32x4 acc[4];
  #pragma unroll
  for (int nt = 0; nt < 4; ++nt) acc[nt] = (f32x4){0.f,0.f,0.f,0.f};

  // ---- GEMM1: e[32x128] @ WF1 -> acc: nt 0,1 att cols, nt 2,3 node cols ----
  #pragma unroll
  for (int kt = 0; kt < 4; ++kt) {
    bf16x8 a = *(const bf16x8*)(Xb + row*512 + ((kt*64 + krow*16) ^ SWZ(row)));
    const ushortT* Ba = WF1 + ((size_t)(wq*2)*8 + kt)*512 + lane*8;       // att half
    const ushortT* Bn = WF1 + ((size_t)(8 + wq*2)*8 + kt)*512 + lane*8;   // node half
    acc[0] = __builtin_amdgcn_mfma_f32_16x16x32_bf16(a, *(const bf16x8*)Ba, acc[0], 0, 0, 0);
    acc[1] = __builtin_amdgcn_mfma_f32_16x16x32_bf16(a, *(const bf16x8*)(Ba + 8*512), acc[1], 0, 0, 0);
    acc[2] = __builtin_amdgcn_mfma_f32_16x16x32_bf16(a, *(const bf16x8*)Bn, acc[2], 0, 0, 0);
    acc[3] = __builtin_amdgcn_mfma_f32_16x16x32_bf16(a, *(const bf16x8*)(Bn + 8*512), acc[3], 0, 0, 0);
  }
  __syncthreads();

  // epilogue 1: + (bias+U) + WVh[dst], relu / gelu, store bf16 in place
  {
    const float b1u0 = b1a0 + Ubs[wq*32 + mrow];
    const float b1u1 = b1a1 + Ubs[wq*32 + 16 + mrow];
    #pragma unroll
    for (int rr = 0; rr < 4; ++rr) {
      int orow = wr*16 + krow*4 + rr;
      char* xrow = Xb + orow*512;
      int sw = SWZ(orow);
      int ca0 = 2*(wq*32 + mrow),        ca1 = 2*(wq*32 + 16 + mrow);
      float x0 = fmaxf(acc[0][rr] + b1u0 + bf2f_lo(wva[rr]), 0.f);
      float x1 = fmaxf(acc[1][rr] + b1u1 + bf2f_hi(wva[rr]), 0.f);
      *(ushortT*)(xrow + (ca0 ^ sw)) = f2bf(x0);
      *(ushortT*)(xrow + (ca1 ^ sw)) = f2bf(x1);
      float y0 = gelu_f(acc[2][rr] + b1n0 + bf2f_lo(wvn[rr]));
      float y1 = gelu_f(acc[3][rr] + b1n1 + bf2f_hi(wvn[rr]));
      *(ushortT*)(xrow + ((256 + ca0) ^ sw)) = f2bf(y0);
      *(ushortT*)(xrow + ((256 + ca1) ^ sw)) = f2bf(y1);
    }
  }
  __syncthreads();

  // ---- GEMM2: W2 = W1@aw2 (nt 0,1), V2pre = V1@nw2 (nt 2,3) ----
  #pragma unroll
  for (int nt = 0; nt < 4; ++nt) acc[nt] = (f32x4){0.f,0.f,0.f,0.f};
  #pragma unroll
  for (int kt = 0; kt < 4; ++kt) {
    bf16x8 a0 = *(const bf16x8*)(Xb + row*512 + ((kt*64 + krow*16) ^ SWZ(row)));
    bf16x8 a1 = *(const bf16x8*)(Xb + row*512 + ((256 + kt*64 + krow*16) ^ SWZ(row)));
    const ushortT* Ba = WF2 + ((size_t)(wq*2)*4 + kt)*512 + lane*8;
    const ushortT* Bn = WF2 + ((size_t)(8 + wq*2)*4 + kt)*512 + lane*8;
    acc[0] = __builtin_amdgcn_mfma_f32_16x16x32_bf16(a0, *(const bf16x8*)Ba, acc[0], 0, 0, 0);
    acc[1] = __builtin_amdgcn_mfma_f32_16x16x32_bf16(a0, *(const bf16x8*)(Ba + 4*512), acc[1], 0, 0, 0);
    acc[2] = __builtin_amdgcn_mfma_f32_16x16x32_bf16(a1, *(const bf16x8*)Bn, acc[2], 0, 0, 0);
    acc[3] = __builtin_amdgcn_mfma_f32_16x16x32_bf16(a1, *(const bf16x8*)(Bn + 4*512), acc[3], 0, 0, 0);
  }
  __syncthreads();
  // epilogue 2: logits partial from W2 (in-reg, pre-scaled), V2 -> Xb left half
  {
    #pragma unroll
    for (int rr = 0; rr < 4; ++rr) {
      int orow = wr*16 + krow*4 + rr;
      int sw = SWZ(orow);
      float lsum = fmaxf(acc[0][rr] + b2a0, 0.f) * aw3c0
                 + fmaxf(acc[1][rr] + b2a1, 0.f) * aw3c1;
      lsum += __shfl_xor(lsum, 1);
      lsum += __shfl_xor(lsum, 2);
      lsum += __shfl_xor(lsum, 4);
      lsum += __shfl_xor(lsum, 8);
      if (mrow == 0) lgp[wq*32 + orow] = lsum;
      char* xrow = Xb + orow*512;
      float y0 = gelu_f(acc[2][rr] + b2n0);
      float y1 = gelu_f(acc[3][rr] + b2n1);
      *(ushortT*)(xrow + ((2*(wq*32 + mrow)) ^ sw)) = f2bf(y0);
      *(ushortT*)(xrow + ((2*(wq*32 + 16 + mrow)) ^ sw)) = f2bf(y1);
    }
  }
  __syncthreads();

  // ---- softmax (shift-invariant, 32-lane reduce) + q = att@V2 (paired) ----
  {
    float x = -INFINITY;
    if (lane < KNB)
      x = lgp[lane] + lgp[32 + lane] + lgp[64 + lane] + lgp[96 + lane];
    float m = x;
    #pragma unroll
    for (int off = 16; off >= 1; off >>= 1) m = fmaxf(m, __shfl_xor(m, off));
    float p = (lane < KNB) ? __expf(x - m) : 0.f;
    float ssum = p;
    #pragma unroll
    for (int off = 16; off >= 1; off >>= 1) ssum += __shfl_xor(ssum, off);
    float attv = p / ssum;   // lanes 30,31 -> 0 (rows 30/31 finite, weight 0)

    int pr = lane & 7, ks = lane >> 3;
    int col0 = wid*16 + pr*2;
    float s0 = 0.f, s1 = 0.f;
    #pragma unroll
    for (int j = 0; j < 4; ++j) {
      int k2 = ks + 8*j;                  // 0..31; attv[30],attv[31] == 0
      float a = __shfl(attv, k2);
      unsigned int w = *(const unsigned int*)(Xb + k2*512 + ((2*col0) ^ SWZ(k2)));
      s0 += a * bf2f_lo(w);
      s1 += a * bf2f_hi(w);
    }
    s0 += __shfl_xor(s0, 8);  s1 += __shfl_xor(s1, 8);
    s0 += __shfl_xor(s0, 16); s1 += __shfl_xor(s1, 16);
    s0 += __shfl_xor(s0, 32); s1 += __shfl_xor(s1, 32);
    if (lane < 8) {
      float2 o; o.x = s0; o.y = s1;
      *(float2*)(hh + (size_t)node*128 + col0) = o;
    }
  }
}

// ---------------- deterministic column reduction over nodes (on q) ------------
__global__ void reduce1_kernel(const float* __restrict__ hh, float* __restrict__ p2) {
  int b = blockIdx.x, tid = threadIdx.x;
  int d = tid & 127, half = tid >> 7;
  float s = 0.f;
  const float* base = hh + (size_t)(b*64 + half*32)*128 + d;
  #pragma unroll 4
  for (int i = 0; i < 32; ++i) s += base[(size_t)i*128];
  __shared__ float ps[256];
  ps[tid] = s; __syncthreads();
  if (tid < 128) p2[b*128 + tid] = ps[tid] + ps[tid + 128];
}

// gate: c = (mean q)@M + c3; g = sigmoid(MLP(c))
__global__ void gate_kernel(const float* __restrict__ p2,
                            const float* __restrict__ M, const float* __restrict__ c3,
                            const float* __restrict__ gw1, const float* __restrict__ gb1,
                            const float* __restrict__ gw2, const float* __restrict__ gb2,
                            const float* __restrict__ gw3, const float* __restrict__ gb3,
                            float* __restrict__ gout) {
  int tid = threadIdx.x;
  int d = tid & 127, half = tid >> 7;
  float s = 0.f;
  for (int i = 0; i < 128; ++i) s += p2[(half*128 + i)*128 + d];
  __shared__ float ps[256];
  __shared__ float cv[128], cv2[128], y1[128], y2[128];
  ps[tid] = s; __syncthreads();
  if (tid < 128) cv[tid] = (ps[tid] + ps[tid+128]) * (1.f / (float)NN);
  __syncthreads();
  if (tid < 128) {
    float a = c3[tid];
    for (int c = 0; c < 128; ++c) a += cv[c] * M[c*128 + tid];
    cv2[tid] = a;
  }
  __syncthreads();
  if (tid < 128) {
    float a = gb1[tid];
    for (int c = 0; c < 128; ++c) a += cv2[c] * gw1[c*128 + tid];
    y1[tid] = fmaxf(a, 0.f);
  }
  __syncthreads();
  if (tid < 128) {
    float a = gb2[tid];
    for (int c = 0; c < 128; ++c) a += y1[c] * gw2[c*128 + tid];
    y2[tid] = fmaxf(a, 0.f);
  }
  __syncthreads();
  if (tid < 128) {
    float a = gb3[tid];
    for (int c = 0; c < 128; ++c) a += y2[c] * gw3[c*128 + tid];
    gout[tid] = 1.f / (1.f + __expf(-a));
  }
}

// ---------------- fused (V3 + to_h + gate): out = (q@M + c3)*g, in place ------
__global__ void toh_scale_kernel(float* __restrict__ hh, const float* __restrict__ M,
                                 const float* __restrict__ c3,
                                 const float* __restrict__ gv)
{
  __shared__ float hs[16][128];
  int tid = threadIdx.x;
  size_t n0 = (size_t)blockIdx.x * 16;
  {
    int r = tid >> 4, c = (tid & 15) * 8;
    const float* src = hh + (n0 + r)*128 + c;
    *(float4*)&hs[r][c]     = *(const float4*)src;
    *(float4*)&hs[r][c + 4] = *(const float4*)(src + 4);
  }
  __syncthreads();
  int d = tid & 127, gq = tid >> 7;
  float s[8] = {0.f,0.f,0.f,0.f,0.f,0.f,0.f,0.f};
  for (int c = 0; c < 128; ++c) {
    float w = M[c*128 + d];
    #pragma unroll
    for (int r = 0; r < 8; ++r) s[r] += hs[gq*8 + r][c] * w;
  }
  float gd = gv[d];
  float cd = c3[d];
  #pragma unroll
  for (int r = 0; r < 8; ++r) hh[(n0 + gq*8 + r)*128 + d] = (s[r] + cd) * gd;
}

extern "C" void kernel_launch(void* const* d_in, const int* in_sizes, int n_in,
                              void* d_out, int out_size, void* d_ws, size_t ws_size,
                              hipStream_t stream) {
  const float* h   = (const float*)d_in[0];
  const float* e   = (const float*)d_in[1];
  const float* aw1 = (const float*)d_in[2];
  const float* ab1 = (const float*)d_in[3];
  const float* aw2 = (const float*)d_in[4];
  const float* ab2 = (const float*)d_in[5];
  const float* aw3 = (const float*)d_in[6];
  const float* ab3 = (const float*)d_in[7];
  const float* nw1 = (const float*)d_in[8];
  const float* nb1 = (const float*)d_in[9];
  const float* nw2 = (const float*)d_in[10];
  const float* nb2 = (const float*)d_in[11];
  const float* nw3 = (const float*)d_in[12];
  const float* nb3 = (const float*)d_in[13];
  const float* thw = (const float*)d_in[14];
  const float* gw1 = (const float*)d_in[15];
  const float* gb1 = (const float*)d_in[16];
  const float* gw2 = (const float*)d_in[17];
  const float* gb2 = (const float*)d_in[18];
  const float* gw3 = (const float*)d_in[19];
  const float* gb3 = (const float*)d_in[20];
  const int* edge_idx = (const int*)d_in[21];

  char* ws = (char*)d_ws;
  ushortT* WF1 = (ushortT*)(ws + 0);        // 131072 B
  ushortT* WF2 = (ushortT*)(ws + 131072);   // 65536 B
  float* bias1 = (float*)(ws + 196608);     // 1024 B
  float* bias2 = (float*)(ws + 197632);     // 1024 B
  float* p2    = (float*)(ws + 198656);     // 131072 B
  float* gout  = (float*)(ws + 329728);     // 512 B
  float* Mw    = (float*)(ws + 330240);     // 65536 B
  float* c3w   = (float*)(ws + 395776);     // 512 B
  ushortT* WVhP= (ushortT*)(ws + 396288);   // 8388608 B
  float* hh    = (float*)d_out;

  // merged prep: uwvh (2048) + pack (59) + M (129)
  prep_kernel<<<2236, 384, 0, stream>>>(h, aw1, nw1, aw2, nw2, nw3, nb3, thw,
                                        ab1, nb1, ab2, nb2,
                                        WF1, WF2, bias1, bias2,
                                        hh, WVhP, Mw, c3w);

  const int SMEM = 17408;
  hipFuncSetAttribute((const void*)edge_kernel,
                      hipFuncAttributeMaxDynamicSharedMemorySize, SMEM);
  edge_kernel<<<NN, 512, SMEM, stream>>>(e, edge_idx, WVhP, WF1, WF2,
                                         bias1, bias2, aw3, ab3, hh);

  reduce1_kernel<<<256, 256, 0, stream>>>(hh, p2);
  gate_kernel<<<1, 256, 0, stream>>>(p2, Mw, c3w, gw1, gb1, gw2, gb2, gw3, gb3, gout);
  toh_scale_kernel<<<NN/16, 256, 0, stream>>>(hh, Mw, c3w, gout);
}

// Round 10
// 319.387 us; speedup vs baseline: 1.8692x; 1.0238x over previous
//
#include <hip/hip_runtime.h>
#include <math.h>

#define NN 16384
#define KNB 30
#define NE (NN*KNB)   // 491520

typedef __attribute__((ext_vector_type(8))) __bf16 bf16x8;
typedef __attribute__((ext_vector_type(4))) float f32x4;
typedef unsigned short ushortT;
typedef __attribute__((ext_vector_type(8))) unsigned short ushort8v;

#define SWZ(r) (((r)&7)<<4)

__device__ __forceinline__ ushortT f2bf(float x){
  __bf16 b = (__bf16)x;
  union { __bf16 b; ushortT u; } v; v.b = b; return v.u;
}
__device__ __forceinline__ float bf2f(ushortT u){
  union { unsigned int u32; float f; } v; v.u32 = ((unsigned int)u) << 16;
  return v.f;
}
__device__ __forceinline__ float bf2f_lo(unsigned int w){
  union { unsigned int u32; float f; } v; v.u32 = w << 16; return v.f;
}
__device__ __forceinline__ float bf2f_hi(unsigned int w){
  union { unsigned int u32; float f; } v; v.u32 = w & 0xffff0000u; return v.f;
}
// A&S 7.1.25 erf (3-term, |err| <= 2.5e-5) — ~100x below bf16 quantization of
// the stored activation; exact-GELU compatible at harness tolerance.
__device__ __forceinline__ float gelu_f(float x){
  float ax = fabsf(x) * 0.7071067811865476f;
  float t = 1.0f / (1.0f + 0.47047f * ax);
  float poly = t*(0.3480242f + t*(-0.0958798f + t*0.7478556f));
  float er = 1.0f - poly * __expf(-ax*ax);
  er = copysignf(er, x);
  return 0.5f * x * (1.0f + er);
}

// ---------------- merged prep kernel ------------------------------------------
// blocks 0..2047      : uwvh  (U = h@aw1[0:128] -> hh; WVhP paired bf16)
// blocks 2048..2106   : pack  (WF1/WF2 fragments + bias1/2)
// blocks 2107..2235   : M = nw3@thw, c3 = nb3@thw
// WVhP pairing: value (g, c) with c=0..127, g=0 att / 1 node:
//   wq=c>>5, m=c&15, hi=(c>>4)&1 -> ushort idx = ((g*4+wq)*16+m)*2 + hi
// so consumer dword at ((g*4+wq)*16+m) holds cols (g*128+wq*32+m, +16).
__global__ void prep_kernel(const float* __restrict__ h,
                            const float* __restrict__ aw1, const float* __restrict__ nw1,
                            const float* __restrict__ aw2, const float* __restrict__ nw2,
                            const float* __restrict__ nw3, const float* __restrict__ nb3,
                            const float* __restrict__ thw,
                            const float* __restrict__ ab1, const float* __restrict__ nb1,
                            const float* __restrict__ ab2, const float* __restrict__ nb2,
                            ushortT* __restrict__ WF1, ushortT* __restrict__ WF2,
                            float* __restrict__ bias1, float* __restrict__ bias2,
                            float* __restrict__ U, ushortT* __restrict__ WVhP,
                            float* __restrict__ M, float* __restrict__ c3)
{
  __shared__ float sbuf[8*128];
  int tid = threadIdx.x;
  int b = blockIdx.x;

  if (b < 2048) {
    // ---- uwvh: 8 nodes, 384 threads ----
    size_t n0 = (size_t)b * 8;
    if (tid < 256) {
      int r = tid >> 5, c = (tid & 31) * 4;
      *(float4*)&sbuf[r*128 + c] = *(const float4*)(h + (n0 + r)*128 + c);
    }
    __syncthreads();
    int d = tid & 127, seg = tid >> 7;   // 0: U, 1: WVh att, 2: WVh node
    const float* wbase = (seg == 0) ? (aw1 + d)
                       : (seg == 1) ? (aw1 + 256*128 + d)
                                    : (nw1 + 128*128 + d);
    float s[8] = {0.f,0.f,0.f,0.f,0.f,0.f,0.f,0.f};
    for (int c = 0; c < 128; ++c) {
      float w = wbase[(size_t)c*128];
      #pragma unroll
      for (int r = 0; r < 8; ++r) s[r] += sbuf[r*128 + c] * w;
    }
    if (seg == 0) {
      #pragma unroll
      for (int r = 0; r < 8; ++r) U[(n0 + r)*128 + d] = s[r];
    } else {
      int g = seg - 1;
      int idx = ((g*4 + (d >> 5))*16 + (d & 15))*2 + ((d >> 4) & 1);
      #pragma unroll
      for (int r = 0; r < 8; ++r) WVhP[(n0 + r)*256 + idx] = f2bf(s[r]);
    }
    return;
  }
  if (b < 2107) {
    // ---- pack: u in [0, 59*256) over 256-thread slices ----
    if (tid >= 256) return;
    int u = (b - 2048) * 256 + tid;
    if (u < 8192) {
      int lane = u & 63, tile = u >> 6;
      int half = tile >> 6, nt = (tile >> 3) & 7, kt = tile & 7;
      int mrow = lane & 15, krow = lane >> 4;
      int n = half*128 + nt*16 + mrow, k0 = kt*32 + krow*8;
      ushort8v o;
      #pragma unroll
      for (int j = 0; j < 8; ++j) {
        int k = k0 + j;
        float v = (half == 0) ? aw1[(128 + k)*128 + n] : nw1[k*128 + (n - 128)];
        o[j] = f2bf(v);
      }
      *(ushort8v*)(WF1 + (size_t)u*8) = o;
      return;
    }
    u -= 8192;
    if (u < 4096) {
      int lane = u & 63, tile = u >> 6;
      int half = tile >> 5, nt = (tile >> 2) & 7, kt = tile & 3;
      int mrow = lane & 15, krow = lane >> 4;
      int n = half*128 + nt*16 + mrow, k0 = kt*32 + krow*8;
      ushort8v o;
      #pragma unroll
      for (int j = 0; j < 8; ++j) {
        int k = k0 + j;
        float v = (half == 0) ? aw2[k*128 + n] : nw2[k*128 + (n - 128)];
        o[j] = f2bf(v);
      }
      *(ushort8v*)(WF2 + (size_t)u*8) = o;
      return;
    }
    u -= 4096;
    if (u < 256) { bias1[u] = (u < 128) ? ab1[u] : nb1[u - 128]; return; }
    u -= 256;
    if (u < 256) { bias2[u] = (u < 128) ? ab2[u] : nb2[u - 128]; return; }
    return;
  }
  {
    // ---- M / c3: 129 blocks, 128 threads ----
    if (tid >= 128) return;
    int bb = b - 2107;
    int d = tid;
    sbuf[d] = (bb < 128) ? nw3[bb*128 + d] : nb3[d];
    __syncthreads();
    float s = 0.f;
    for (int n = 0; n < 128; ++n) s += sbuf[n] * thw[n*128 + d];
    if (bb < 128) M[bb*128 + d] = s;
    else c3[d] = s;
  }
}

// ---------------- fused edge pipeline: 1 node, 512 threads, 3 barriers --------
// Double-buffered LDS: stage->bar1->[G1 reads Xb | ep1 writes Yb]->bar2->
// [G2 reads Yb | ep2 writes Xb]->bar3->PV reads Xb. GEMM->epilogue barriers
// removed (epilogues touch only registers + the other buffer).
// LDS: Xb[32][512B] + Yb[32][512B] swz bf16; lgp[4][32]; Ubs[128]. 33792 B
// -> 4 blocks/CU (wave cap).
__global__ __launch_bounds__(512, 8) void edge_kernel(
    const float* __restrict__ e,
    const int* __restrict__ edge_idx,
    const ushortT* __restrict__ WVhP,
    const ushortT* __restrict__ WF1, const ushortT* __restrict__ WF2,
    const float* __restrict__ bias1, const float* __restrict__ bias2,
    const float* __restrict__ aw3, const float* __restrict__ ab3,
    float* __restrict__ hh)
{
  extern __shared__ char smem[];
  char*  Xb   = smem;                       // [32][512B] swizzled bf16 (16384 B)
  char*  Yb   = smem + 16384;               // [32][512B] swizzled bf16 (16384 B)
  float* lgp  = (float*)(smem + 32768);     // [4][32] logits partials
  float* Ubs  = (float*)(smem + 33280);     // [128]

  const int tid  = threadIdx.x;
  const int lane = tid & 63;
  const int wid  = tid >> 6;
  const int node = blockIdx.x;
  const long e0 = (long)node * KNB;

  const int mrow = lane & 15, krow = lane >> 4;
  const int wr = wid >> 2;   // row strip (16 rows)
  const int wq = wid & 3;    // 32-col group (att + node)
  const int row = wr*16 + mrow;

  // U row (precomputed into hh) — issued first, in flight during staging
  float uval = 0.f;
  if (tid < 128) uval = hh[(size_t)node*128 + tid];

  // dst indices for this thread's 4 output rows (guard rows >= 30)
  int dstr[4];
  #pragma unroll
  for (int rr = 0; rr < 4; ++rr) {
    int orow = wr*16 + krow*4 + rr;
    dstr[rr] = (orow < KNB) ? edge_idx[NE + e0 + orow] : -1;
  }

  // ---- Phase 0a: stage e -> bf16 Xb cols 0..127; rows 30/31 zeroed ----
  {
    int r = tid >> 4, c8 = tid & 15;       // 32 rows x 16 groups = 512
    ushort8v u = {0,0,0,0,0,0,0,0};
    if (r < KNB) {
      const float* src = e + ((size_t)(e0 + r))*128 + c8*8;
      float4 v0 = *(const float4*)src;
      float4 v1 = *(const float4*)(src + 4);
      u[0]=f2bf(v0.x); u[1]=f2bf(v0.y); u[2]=f2bf(v0.z); u[3]=f2bf(v0.w);
      u[4]=f2bf(v1.x); u[5]=f2bf(v1.y); u[6]=f2bf(v1.z); u[7]=f2bf(v1.w);
    }
    *(ushort8v*)(Xb + r*512 + ((c8*16) ^ SWZ(r))) = u;
  }

  // ---- Phase 0b: issue direct WVh gathers (att + node pair dwords) ----
  unsigned int wva[4], wvn[4];
  #pragma unroll
  for (int rr = 0; rr < 4; ++rr) {
    wva[rr] = 0u; wvn[rr] = 0u;
    if (dstr[rr] >= 0) {
      const unsigned int* base = (const unsigned int*)(WVhP + (size_t)dstr[rr]*256);
      wva[rr] = base[wq*16 + mrow];        // cols (wq*32+mrow, +16)
      wvn[rr] = base[64 + wq*16 + mrow];   // cols (128+wq*32+mrow, +16)
    }
  }
  if (tid < 128) Ubs[tid] = uval;
  // barrier 1: LDS drained; WVh gathers stay in flight through GEMM1
  asm volatile("s_waitcnt lgkmcnt(0)" ::: "memory");
  __builtin_amdgcn_s_barrier();

  // hoisted per-column constants (L1-resident); aw3 pre-scaled by 1/sqrt(DH)
  const float b1a0 = bias1[wq*32 + mrow],        b1a1 = bias1[wq*32 + 16 + mrow];
  const float b1n0 = bias1[128 + wq*32 + mrow],  b1n1 = bias1[128 + wq*32 + 16 + mrow];
  const float b2a0 = bias2[wq*32 + mrow],        b2a1 = bias2[wq*32 + 16 + mrow];
  const float b2n0 = bias2[128 + wq*32 + mrow],  b2n1 = bias2[128 + wq*32 + 16 + mrow];
  const float aw3c0 = aw3[wq*32 + mrow]      * 0.08838834764831845f;
  const float aw3c1 = aw3[wq*32 + 16 + mrow] * 0.08838834764831845f;

  f32x4 acc[4];
  #pragma unroll
  for (int nt = 0; nt < 4; ++nt) acc[nt] = (f32x4){0.f,0.f,0.f,0.f};

  // ---- GEMM1: e[32x128] @ WF1 -> acc: nt 0,1 att cols, nt 2,3 node cols ----
  #pragma unroll
  for (int kt = 0; kt < 4; ++kt) {
    bf16x8 a = *(const bf16x8*)(Xb + row*512 + ((kt*64 + krow*16) ^ SWZ(row)));
    const ushortT* Ba = WF1 + ((size_t)(wq*2)*8 + kt)*512 + lane*8;       // att half
    const ushortT* Bn = WF1 + ((size_t)(8 + wq*2)*8 + kt)*512 + lane*8;   // node half
    acc[0] = __builtin_amdgcn_mfma_f32_16x16x32_bf16(a, *(const bf16x8*)Ba, acc[0], 0, 0, 0);
    acc[1] = __builtin_amdgcn_mfma_f32_16x16x32_bf16(a, *(const bf16x8*)(Ba + 8*512), acc[1], 0, 0, 0);
    acc[2] = __builtin_amdgcn_mfma_f32_16x16x32_bf16(a, *(const bf16x8*)Bn, acc[2], 0, 0, 0);
    acc[3] = __builtin_amdgcn_mfma_f32_16x16x32_bf16(a, *(const bf16x8*)(Bn + 8*512), acc[3], 0, 0, 0);
  }

  // epilogue 1 (no barrier needed: acc is wave-private, output goes to Yb)
  {
    const float b1u0 = b1a0 + Ubs[wq*32 + mrow];
    const float b1u1 = b1a1 + Ubs[wq*32 + 16 + mrow];
    #pragma unroll
    for (int rr = 0; rr < 4; ++rr) {
      int orow = wr*16 + krow*4 + rr;
      char* yrow = Yb + orow*512;
      int sw = SWZ(orow);
      int ca0 = 2*(wq*32 + mrow),        ca1 = 2*(wq*32 + 16 + mrow);
      float x0 = fmaxf(acc[0][rr] + b1u0 + bf2f_lo(wva[rr]), 0.f);
      float x1 = fmaxf(acc[1][rr] + b1u1 + bf2f_hi(wva[rr]), 0.f);
      *(ushortT*)(yrow + (ca0 ^ sw)) = f2bf(x0);
      *(ushortT*)(yrow + (ca1 ^ sw)) = f2bf(x1);
      float y0 = gelu_f(acc[2][rr] + b1n0 + bf2f_lo(wvn[rr]));
      float y1 = gelu_f(acc[3][rr] + b1n1 + bf2f_hi(wvn[rr]));
      *(ushortT*)(yrow + ((256 + ca0) ^ sw)) = f2bf(y0);
      *(ushortT*)(yrow + ((256 + ca1) ^ sw)) = f2bf(y1);
    }
  }
  __syncthreads();   // barrier 2: Yb (W1|V1) visible to all waves

  // ---- GEMM2: W2 = W1@aw2 (nt 0,1), V2pre = V1@nw2 (nt 2,3), A from Yb ----
  #pragma unroll
  for (int nt = 0; nt < 4; ++nt) acc[nt] = (f32x4){0.f,0.f,0.f,0.f};
  #pragma unroll
  for (int kt = 0; kt < 4; ++kt) {
    bf16x8 a0 = *(const bf16x8*)(Yb + row*512 + ((kt*64 + krow*16) ^ SWZ(row)));
    bf16x8 a1 = *(const bf16x8*)(Yb + row*512 + ((256 + kt*64 + krow*16) ^ SWZ(row)));
    const ushortT* Ba = WF2 + ((size_t)(wq*2)*4 + kt)*512 + lane*8;
    const ushortT* Bn = WF2 + ((size_t)(8 + wq*2)*4 + kt)*512 + lane*8;
    acc[0] = __builtin_amdgcn_mfma_f32_16x16x32_bf16(a0, *(const bf16x8*)Ba, acc[0], 0, 0, 0);
    acc[1] = __builtin_amdgcn_mfma_f32_16x16x32_bf16(a0, *(const bf16x8*)(Ba + 4*512), acc[1], 0, 0, 0);
    acc[2] = __builtin_amdgcn_mfma_f32_16x16x32_bf16(a1, *(const bf16x8*)Bn, acc[2], 0, 0, 0);
    acc[3] = __builtin_amdgcn_mfma_f32_16x16x32_bf16(a1, *(const bf16x8*)(Bn + 4*512), acc[3], 0, 0, 0);
  }

  // epilogue 2 (no barrier: logits from in-reg W2, V2 -> Xb which G2 never reads)
  {
    #pragma unroll
    for (int rr = 0; rr < 4; ++rr) {
      int orow = wr*16 + krow*4 + rr;
      int sw = SWZ(orow);
      float lsum = fmaxf(acc[0][rr] + b2a0, 0.f) * aw3c0
                 + fmaxf(acc[1][rr] + b2a1, 0.f) * aw3c1;
      lsum += __shfl_xor(lsum, 1);
      lsum += __shfl_xor(lsum, 2);
      lsum += __shfl_xor(lsum, 4);
      lsum += __shfl_xor(lsum, 8);
      if (mrow == 0) lgp[wq*32 + orow] = lsum;
      char* xrow = Xb + orow*512;
      float y0 = gelu_f(acc[2][rr] + b2n0);
      float y1 = gelu_f(acc[3][rr] + b2n1);
      *(ushortT*)(xrow + ((2*(wq*32 + mrow)) ^ sw)) = f2bf(y0);
      *(ushortT*)(xrow + ((2*(wq*32 + 16 + mrow)) ^ sw)) = f2bf(y1);
    }
  }
  __syncthreads();   // barrier 3: V2 (Xb) + lgp visible

  // ---- softmax (shift-invariant, 32-lane reduce) + q = att@V2 (paired) ----
  {
    float x = -INFINITY;
    if (lane < KNB)
      x = lgp[lane] + lgp[32 + lane] + lgp[64 + lane] + lgp[96 + lane];
    float m = x;
    #pragma unroll
    for (int off = 16; off >= 1; off >>= 1) m = fmaxf(m, __shfl_xor(m, off));
    float p = (lane < KNB) ? __expf(x - m) : 0.f;
    float ssum = p;
    #pragma unroll
    for (int off = 16; off >= 1; off >>= 1) ssum += __shfl_xor(ssum, off);
    float attv = p / ssum;   // lanes 30,31 -> 0 (rows 30/31 finite, weight 0)

    int pr = lane & 7, ks = lane >> 3;
    int col0 = wid*16 + pr*2;
    float s0 = 0.f, s1 = 0.f;
    #pragma unroll
    for (int j = 0; j < 4; ++j) {
      int k2 = ks + 8*j;                  // 0..31; attv[30],attv[31] == 0
      float a = __shfl(attv, k2);
      unsigned int w = *(const unsigned int*)(Xb + k2*512 + ((2*col0) ^ SWZ(k2)));
      s0 += a * bf2f_lo(w);
      s1 += a * bf2f_hi(w);
    }
    s0 += __shfl_xor(s0, 8);  s1 += __shfl_xor(s1, 8);
    s0 += __shfl_xor(s0, 16); s1 += __shfl_xor(s1, 16);
    s0 += __shfl_xor(s0, 32); s1 += __shfl_xor(s1, 32);
    if (lane < 8) {
      float2 o; o.x = s0; o.y = s1;
      *(float2*)(hh + (size_t)node*128 + col0) = o;
    }
  }
}

// ---------------- deterministic column reduction over nodes (on q) ------------
__global__ void reduce1_kernel(const float* __restrict__ hh, float* __restrict__ p2) {
  int b = blockIdx.x, tid = threadIdx.x;
  int d = tid & 127, half = tid >> 7;
  float s = 0.f;
  const float* base = hh + (size_t)(b*64 + half*32)*128 + d;
  #pragma unroll 4
  for (int i = 0; i < 32; ++i) s += base[(size_t)i*128];
  __shared__ float ps[256];
  ps[tid] = s; __syncthreads();
  if (tid < 128) p2[b*128 + tid] = ps[tid] + ps[tid + 128];
}

// gate: c = (mean q)@M + c3; g = sigmoid(MLP(c))
__global__ void gate_kernel(const float* __restrict__ p2,
                            const float* __restrict__ M, const float* __restrict__ c3,
                            const float* __restrict__ gw1, const float* __restrict__ gb1,
                            const float* __restrict__ gw2, const float* __restrict__ gb2,
                            const float* __restrict__ gw3, const float* __restrict__ gb3,
                            float* __restrict__ gout) {
  int tid = threadIdx.x;
  int d = tid & 127, half = tid >> 7;
  float s = 0.f;
  for (int i = 0; i < 128; ++i) s += p2[(half*128 + i)*128 + d];
  __shared__ float ps[256];
  __shared__ float cv[128], cv2[128], y1[128], y2[128];
  ps[tid] = s; __syncthreads();
  if (tid < 128) cv[tid] = (ps[tid] + ps[tid+128]) * (1.f / (float)NN);
  __syncthreads();
  if (tid < 128) {
    float a = c3[tid];
    for (int c = 0; c < 128; ++c) a += cv[c] * M[c*128 + tid];
    cv2[tid] = a;
  }
  __syncthreads();
  if (tid < 128) {
    float a = gb1[tid];
    for (int c = 0; c < 128; ++c) a += cv2[c] * gw1[c*128 + tid];
    y1[tid] = fmaxf(a, 0.f);
  }
  __syncthreads();
  if (tid < 128) {
    float a = gb2[tid];
    for (int c = 0; c < 128; ++c) a += y1[c] * gw2[c*128 + tid];
    y2[tid] = fmaxf(a, 0.f);
  }
  __syncthreads();
  if (tid < 128) {
    float a = gb3[tid];
    for (int c = 0; c < 128; ++c) a += y2[c] * gw3[c*128 + tid];
    gout[tid] = 1.f / (1.f + __expf(-a));
  }
}

// ---------------- fused (V3 + to_h + gate): out = (q@M + c3)*g, in place ------
__global__ void toh_scale_kernel(float* __restrict__ hh, const float* __restrict__ M,
                                 const float* __restrict__ c3,
                                 const float* __restrict__ gv)
{
  __shared__ float hs[16][128];
  int tid = threadIdx.x;
  size_t n0 = (size_t)blockIdx.x * 16;
  {
    int r = tid >> 4, c = (tid & 15) * 8;
    const float* src = hh + (n0 + r)*128 + c;
    *(float4*)&hs[r][c]     = *(const float4*)src;
    *(float4*)&hs[r][c + 4] = *(const float4*)(src + 4);
  }
  __syncthreads();
  int d = tid & 127, gq = tid >> 7;
  float s[8] = {0.f,0.f,0.f,0.f,0.f,0.f,0.f,0.f};
  for (int c = 0; c < 128; ++c) {
    float w = M[c*128 + d];
    #pragma unroll
    for (int r = 0; r < 8; ++r) s[r] += hs[gq*8 + r][c] * w;
  }
  float gd = gv[d];
  float cd = c3[d];
  #pragma unroll
  for (int r = 0; r < 8; ++r) hh[(n0 + gq*8 + r)*128 + d] = (s[r] + cd) * gd;
}

extern "C" void kernel_launch(void* const* d_in, const int* in_sizes, int n_in,
                              void* d_out, int out_size, void* d_ws, size_t ws_size,
                              hipStream_t stream) {
  const float* h   = (const float*)d_in[0];
  const float* e   = (const float*)d_in[1];
  const float* aw1 = (const float*)d_in[2];
  const float* ab1 = (const float*)d_in[3];
  const float* aw2 = (const float*)d_in[4];
  const float* ab2 = (const float*)d_in[5];
  const float* aw3 = (const float*)d_in[6];
  const float* ab3 = (const float*)d_in[7];
  const float* nw1 = (const float*)d_in[8];
  const float* nb1 = (const float*)d_in[9];
  const float* nw2 = (const float*)d_in[10];
  const float* nb2 = (const float*)d_in[11];
  const float* nw3 = (const float*)d_in[12];
  const float* nb3 = (const float*)d_in[13];
  const float* thw = (const float*)d_in[14];
  const float* gw1 = (const float*)d_in[15];
  const float* gb1 = (const float*)d_in[16];
  const float* gw2 = (const float*)d_in[17];
  const float* gb2 = (const float*)d_in[18];
  const float* gw3 = (const float*)d_in[19];
  const float* gb3 = (const float*)d_in[20];
  const int* edge_idx = (const int*)d_in[21];

  char* ws = (char*)d_ws;
  ushortT* WF1 = (ushortT*)(ws + 0);        // 131072 B
  ushortT* WF2 = (ushortT*)(ws + 131072);   // 65536 B
  float* bias1 = (float*)(ws + 196608);     // 1024 B
  float* bias2 = (float*)(ws + 197632);     // 1024 B
  float* p2    = (float*)(ws + 198656);     // 131072 B
  float* gout  = (float*)(ws + 329728);     // 512 B
  float* Mw    = (float*)(ws + 330240);     // 65536 B
  float* c3w   = (float*)(ws + 395776);     // 512 B
  ushortT* WVhP= (ushortT*)(ws + 396288);   // 8388608 B
  float* hh    = (float*)d_out;

  // merged prep: uwvh (2048) + pack (59) + M (129)
  prep_kernel<<<2236, 384, 0, stream>>>(h, aw1, nw1, aw2, nw2, nw3, nb3, thw,
                                        ab1, nb1, ab2, nb2,
                                        WF1, WF2, bias1, bias2,
                                        hh, WVhP, Mw, c3w);

  const int SMEM = 33792;
  hipFuncSetAttribute((const void*)edge_kernel,
                      hipFuncAttributeMaxDynamicSharedMemorySize, SMEM);
  edge_kernel<<<NN, 512, SMEM, stream>>>(e, edge_idx, WVhP, WF1, WF2,
                                         bias1, bias2, aw3, ab3, hh);

  reduce1_kernel<<<256, 256, 0, stream>>>(hh, p2);
  gate_kernel<<<1, 256, 0, stream>>>(p2, Mw, c3w, gw1, gb1, gw2, gb2, gw3, gb3, gout);
  toh_scale_kernel<<<NN/16, 256, 0, stream>>>(hh, Mw, c3w, gout);
}